// Round 5
// baseline (966.779 us; speedup 1.0000x reference)
//
#include <hip/hip_runtime.h>
#include <math.h>

#define D_MODELC 256
#define N_LAYERSC 6
#define N_HEADSC 8
#define D_FFC 1024
#define HEAD_DIMC 32
#define B_SZ 4
#define T_SEQ 2048
#define M_ROWS 8192
#define QKV_N 768

typedef short bf16x8 __attribute__((ext_vector_type(8)));
typedef short bf16x4 __attribute__((ext_vector_type(4)));
typedef float f32x4  __attribute__((ext_vector_type(4)));
typedef unsigned u32x4 __attribute__((ext_vector_type(4)));
typedef unsigned short u16;

// scale(1/sqrt(32)) * log2(e) folded into wq at conversion time
#define QSCALE 0.25503488f

__device__ __forceinline__ u16 f2bf(float x) {
    unsigned u = __builtin_bit_cast(unsigned, x);
    u += 0x7FFF + ((u >> 16) & 1);          // round-to-nearest-even
    return (u16)(u >> 16);
}

__device__ __forceinline__ unsigned pack2bf(float a, float b) {  // truncating
    unsigned ua = __builtin_bit_cast(unsigned, a);
    unsigned ub = __builtin_bit_cast(unsigned, b);
    return (ua >> 16) | (ub & 0xFFFF0000u);
}

__device__ __forceinline__ void async_lds16(const void* g, void* l) {
    __builtin_amdgcn_global_load_lds(
        (const __attribute__((address_space(1))) unsigned int*)g,
        (__attribute__((address_space(3))) unsigned int*)l, 16, 0, 0);
}

// ---------------------------------------------------------------------------
// Weight transpose+convert: dst[n][k] = bf16(src[k][n] * scale), per layer z.
// ---------------------------------------------------------------------------
__global__ __launch_bounds__(256) void transpose_w(
    const float* __restrict__ src, u16* __restrict__ dst,
    int K, int N, int srcLS, int dstLS, float scale)
{
    __shared__ float t[32][33];
    src += (size_t)blockIdx.z * srcLS;
    dst += (size_t)blockIdx.z * dstLS;
    const int k0 = blockIdx.y * 32, n0 = blockIdx.x * 32;
    const int r = threadIdx.x >> 3, c4 = (threadIdx.x & 7) * 4;
    const float4 v = *(const float4*)(src + (size_t)(k0 + r) * N + n0 + c4);
    t[r][c4 + 0] = v.x; t[r][c4 + 1] = v.y;
    t[r][c4 + 2] = v.z; t[r][c4 + 3] = v.w;
    __syncthreads();
    bf16x4 o;
#pragma unroll
    for (int i = 0; i < 4; i++) o[i] = (short)f2bf(t[c4 + i][r] * scale);
    *(bf16x4*)(dst + (size_t)(n0 + r) * K + k0 + c4) = o;
}

// Fused QKV bias: [l][768] = [ bq*QSCALE | bk | bv ]
__global__ __launch_bounds__(256) void pack_bias(
    const float* __restrict__ bq, const float* __restrict__ bk,
    const float* __restrict__ bv, float* __restrict__ dst)
{
    int i = blockIdx.x * 256 + threadIdx.x;
    if (i >= N_LAYERSC * QKV_N) return;
    int l = i / QKV_N, j = i % QKV_N;
    float v;
    if (j < 256)      v = bq[l * 256 + j] * QSCALE;
    else if (j < 512) v = bk[l * 256 + j - 256];
    else              v = bv[l * 256 + j - 512];
    dst[i] = v;
}

// ---------------------------------------------------------------------------
// V transpose (per layer): VT[h*32+dim][token 0..8191] = V from qkv cols 512+.
// 64-token x 32-dim tiles via LDS; coalesced b128 both sides.
// ---------------------------------------------------------------------------
__global__ __launch_bounds__(256) void transpose_v(
    const u16* __restrict__ QKV, u16* __restrict__ VT)
{
    __shared__ u16 T[64][40];                     // 80B rows: b128-aligned
    const int h = blockIdx.y;
    const int row0 = blockIdx.x * 64;
    const int t = threadIdx.x;
    {
        const int r = t >> 2, d8 = (t & 3) * 8;
        *(bf16x8*)&T[r][d8] =
            *(const bf16x8*)&QKV[(size_t)(row0 + r) * QKV_N + 512 + h * 32 + d8];
    }
    __syncthreads();
    const int dim = t >> 3, ko = (t & 7) * 8;
    bf16x8 o;
#pragma unroll
    for (int j = 0; j < 8; j++) o[j] = (short)T[ko + j][dim];
    *(bf16x8*)&VT[((size_t)h * 32 + dim) * M_ROWS + row0 + ko] = o;
}

// ---------------------------------------------------------------------------
// LayerNorm: wave per row (64 lanes x float4), bf16 output.
// ---------------------------------------------------------------------------
__global__ __launch_bounds__(256) void ln_kernel(
    const float* __restrict__ X, const float* __restrict__ gamma,
    const float* __restrict__ beta, u16* __restrict__ Y)
{
    const int w = threadIdx.x >> 6, lane = threadIdx.x & 63;
    const int row = blockIdx.x * 4 + w;
    const float4 v = *(const float4*)(X + (size_t)row * 256 + lane * 4);
    float sum = v.x + v.y + v.z + v.w;
    float sq  = v.x * v.x + v.y * v.y + v.z * v.z + v.w * v.w;
#pragma unroll
    for (int off = 32; off > 0; off >>= 1) {
        sum += __shfl_xor(sum, off, 64);
        sq  += __shfl_xor(sq,  off, 64);
    }
    float mu  = sum * (1.0f / 256.0f);
    float var = sq * (1.0f / 256.0f) - mu * mu;
    float rr  = rsqrtf(var + 1e-5f);
    const float4 g  = *(const float4*)(gamma + lane * 4);
    const float4 bb = *(const float4*)(beta + lane * 4);
    bf16x4 o;
    o[0] = (short)f2bf((v.x - mu) * rr * g.x + bb.x);
    o[1] = (short)f2bf((v.y - mu) * rr * g.y + bb.y);
    o[2] = (short)f2bf((v.z - mu) * rr * g.z + bb.z);
    o[3] = (short)f2bf((v.w - mu) * rr * g.w + bb.w);
    *(bf16x4*)(Y + (size_t)row * 256 + lane * 4) = o;
}

// ---------------------------------------------------------------------------
// MFMA GEMM (m97 structure): 128x128 tile, BK=64, async width-16 staging.
// EPI: 0 = bf16 out (+bias); 1 = fp32 out (+bias+resid); 2 = bf16 gelu(+bias)
// ---------------------------------------------------------------------------
template <int EPI>
__global__ __launch_bounds__(256) void mfma_gemm(
    const u16* __restrict__ A, const u16* __restrict__ Bt,
    const float* __restrict__ bias, const float* __restrict__ resid,
    void* __restrict__ Cout, int N, int K)
{
    __shared__ u16 As[128 * 64];
    __shared__ u16 Bs[128 * 64];
    const int tid = threadIdx.x, w = tid >> 6, lane = tid & 63;
    const int c = lane & 15, quad = lane >> 4;
    const int row0 = blockIdx.y * 128, col0 = blockIdx.x * 128;
    const int wr = w >> 1, wc = w & 1;

    f32x4 acc[4][4] = {};

    for (int k0 = 0; k0 < K; k0 += 64) {
        __syncthreads();
#pragma unroll
        for (int ci = 0; ci < 4; ci++) {
            const int fb = (w * 4 + ci) * 1024;
            const int fl = fb + lane * 16;
            const int r = fl >> 7, col = (fl & 127) >> 1;
            async_lds16(A  + (size_t)(row0 + r) * K + k0 + col, (char*)As + fb);
            async_lds16(Bt + (size_t)(col0 + r) * K + k0 + col, (char*)Bs + fb);
        }
        __syncthreads();
#pragma unroll
        for (int kk = 0; kk < 2; kk++) {
            bf16x8 af[4], bfv[4];
#pragma unroll
            for (int i = 0; i < 4; i++)
                af[i] = *(const bf16x8*)&As[(wr * 64 + i * 16 + c) * 64 + kk * 32 + quad * 8];
#pragma unroll
            for (int j = 0; j < 4; j++)
                bfv[j] = *(const bf16x8*)&Bs[(wc * 64 + j * 16 + c) * 64 + kk * 32 + quad * 8];
#pragma unroll
            for (int i = 0; i < 4; i++)
#pragma unroll
                for (int j = 0; j < 4; j++)
                    acc[i][j] = __builtin_amdgcn_mfma_f32_16x16x32_bf16(
                        af[i], bfv[j], acc[i][j], 0, 0, 0);
        }
    }

    float bj[4];
#pragma unroll
    for (int j = 0; j < 4; j++) bj[j] = bias[col0 + wc * 64 + j * 16 + c];

#pragma unroll
    for (int i = 0; i < 4; i++) {
#pragma unroll
        for (int r = 0; r < 4; r++) {
            const int gr = row0 + wr * 64 + i * 16 + quad * 4 + r;
#pragma unroll
            for (int j = 0; j < 4; j++) {
                const int gc = col0 + wc * 64 + j * 16 + c;
                float v = acc[i][j][r] + bj[j];
                if (EPI == 1) {
                    ((float*)Cout)[(size_t)gr * N + gc] = v + resid[(size_t)gr * N + gc];
                } else {
                    if (EPI == 2) v = 0.5f * v * (1.0f + erff(v * 0.70710678118654752f));
                    ((u16*)Cout)[(size_t)gr * N + gc] = f2bf(v);
                }
            }
        }
    }
}

// ---------------------------------------------------------------------------
// MFMA flash attention v2: S^T formulation, in-register P exchange,
// lane-linear async LDS staging, 32 queries/wave (128/block).
//   St[key][q] = mfma(A=K-rows, B=Q^T)  -> lane(c,quad) = St[g*16+quad*4+r][c]
//   p = 2^St; pk pairs (bf16x2 per u32); P->A-frag via 4-lane bpermute
//   O[q][d]  = mfma(A=P, B=V) with V-fragments staged from global V^T.
// No online max (|S| << 1 by construction; exp2 domain, scale folded in wq).
// ---------------------------------------------------------------------------
__global__ __launch_bounds__(256) void attn_kernel(
    const u16* __restrict__ QKV, const u16* __restrict__ VT,
    u16* __restrict__ Ob)
{
    const int h = blockIdx.y, b = blockIdx.z;
    const int q0 = blockIdx.x * 128;
    const int tid = threadIdx.x, w = tid >> 6, lane = tid & 63;
    const int c = lane & 15, quad = lane >> 4;

    __shared__ u16 Kf[2048];   // fragment order: granule g*64+lane = K[g*16+c][quad*8..]
    __shared__ u16 Vf[2048];   // fragment order: granule q'*32+r   = V^T[r][q'*8..]

    const u16* qp = QKV + (size_t)(b * T_SEQ + q0 + w * 32 + c) * QKV_N + h * 32 + quad * 8;
    bf16x8 aQ0 = *(const bf16x8*)qp;                 // B-frag, q = qg*16+c
    bf16x8 aQ1 = *(const bf16x8*)(qp + 16 * QKV_N);

    float l0 = 0.f, l1 = 0.f;
    f32x4 O[2][2] = {};                              // [qg][dim half]

    // per-lane staging addresses (one async_lds16 each per tile)
    const u16* kgp = QKV + (size_t)(b * T_SEQ + w * 16 + c) * QKV_N + 256 + h * 32 + quad * 8;
    const u16* vgp = VT + ((size_t)h * 32 + (lane & 31)) * M_ROWS + b * T_SEQ
                     + (w * 2 + (lane >> 5)) * 8;
    u16* kfw = Kf + w * 512;
    u16* vfw = Vf + w * 512;
    const int LA = (quad & 1) * 32 + c, LB = LA + 16;
    const bool gsel = quad < 2;

    for (int k0 = 0; k0 < T_SEQ; k0 += 64) {
        __syncthreads();                             // prior readers done
        async_lds16(kgp + (size_t)k0 * QKV_N, kfw);
        async_lds16(vgp + k0, vfw);
        __syncthreads();                             // staging landed

        unsigned pk[4][2][2];
#pragma unroll
        for (int g = 0; g < 4; g++) {
            bf16x8 aK = *(const bf16x8*)&Kf[g * 512 + lane * 8];
            f32x4 S0 = __builtin_amdgcn_mfma_f32_16x16x32_bf16(
                aK, aQ0, (f32x4){0.f, 0.f, 0.f, 0.f}, 0, 0, 0);
            f32x4 S1 = __builtin_amdgcn_mfma_f32_16x16x32_bf16(
                aK, aQ1, (f32x4){0.f, 0.f, 0.f, 0.f}, 0, 0, 0);
            float p0 = exp2f(S0[0]), p1 = exp2f(S0[1]);
            float p2 = exp2f(S0[2]), p3 = exp2f(S0[3]);
            l0 += (p0 + p1) + (p2 + p3);
            pk[g][0][0] = pack2bf(p0, p1);
            pk[g][0][1] = pack2bf(p2, p3);
            p0 = exp2f(S1[0]); p1 = exp2f(S1[1]);
            p2 = exp2f(S1[2]); p3 = exp2f(S1[3]);
            l1 += (p0 + p1) + (p2 + p3);
            pk[g][1][0] = pack2bf(p0, p1);
            pk[g][1][1] = pack2bf(p2, p3);
        }

#pragma unroll
        for (int kh = 0; kh < 2; kh++) {
            bf16x8 bV0 = *(const bf16x8*)&Vf[((kh * 4 + quad) * 32 + c) * 8];
            bf16x8 bV1 = *(const bf16x8*)&Vf[((kh * 4 + quad) * 32 + 16 + c) * 8];
#pragma unroll
            for (int qg = 0; qg < 2; qg++) {
                int e00 = __shfl((int)pk[2 * kh][qg][0],     LA, 64);
                int e01 = __shfl((int)pk[2 * kh + 1][qg][0], LA, 64);
                int e10 = __shfl((int)pk[2 * kh][qg][1],     LA, 64);
                int e11 = __shfl((int)pk[2 * kh + 1][qg][1], LA, 64);
                int e20 = __shfl((int)pk[2 * kh][qg][0],     LB, 64);
                int e21 = __shfl((int)pk[2 * kh + 1][qg][0], LB, 64);
                int e30 = __shfl((int)pk[2 * kh][qg][1],     LB, 64);
                int e31 = __shfl((int)pk[2 * kh + 1][qg][1], LB, 64);
                u32x4 ap;
                ap[0] = (unsigned)(gsel ? e00 : e01);
                ap[1] = (unsigned)(gsel ? e10 : e11);
                ap[2] = (unsigned)(gsel ? e20 : e21);
                ap[3] = (unsigned)(gsel ? e30 : e31);
                bf16x8 aP = __builtin_bit_cast(bf16x8, ap);
                O[qg][0] = __builtin_amdgcn_mfma_f32_16x16x32_bf16(aP, bV0, O[qg][0], 0, 0, 0);
                O[qg][1] = __builtin_amdgcn_mfma_f32_16x16x32_bf16(aP, bV1, O[qg][1], 0, 0, 0);
            }
        }
    }

    // full l per q=qg*16+c on every lane
    l0 += __shfl_xor(l0, 16, 64); l0 += __shfl_xor(l0, 32, 64);
    l1 += __shfl_xor(l1, 16, 64); l1 += __shfl_xor(l1, 32, 64);

    u16* ob = Ob + (size_t)(b * T_SEQ + q0 + w * 32) * 256 + h * 32;
#pragma unroll
    for (int r = 0; r < 4; r++) {
        int src = quad * 4 + r;                      // output q-row (local)
        float i0 = 1.0f / __shfl(l0, src, 64);
        float i1 = 1.0f / __shfl(l1, src, 64);
        ob[(size_t)src * 256 + c]             = f2bf(O[0][0][r] * i0);
        ob[(size_t)src * 256 + 16 + c]        = f2bf(O[0][1][r] * i0);
        ob[(size_t)(16 + src) * 256 + c]      = f2bf(O[1][0][r] * i1);
        ob[(size_t)(16 + src) * 256 + 16 + c] = f2bf(O[1][1][r] * i1);
    }
}

// ---------------------------------------------------------------------------
extern "C" void kernel_launch(void* const* d_in, const int* in_sizes, int n_in,
                              void* d_out, int out_size, void* d_ws, size_t ws_size,
                              hipStream_t stream)
{
    const float* x     = (const float*)d_in[0];
    const float* ln1_s = (const float*)d_in[1];
    const float* ln1_b = (const float*)d_in[2];
    const float* wq    = (const float*)d_in[3];
    const float* bq    = (const float*)d_in[4];
    const float* wk    = (const float*)d_in[5];
    const float* bk    = (const float*)d_in[6];
    const float* wv    = (const float*)d_in[7];
    const float* bv    = (const float*)d_in[8];
    const float* wo    = (const float*)d_in[9];
    const float* bo    = (const float*)d_in[10];
    const float* ln2_s = (const float*)d_in[11];
    const float* ln2_b = (const float*)d_in[12];
    const float* w1    = (const float*)d_in[13];
    const float* b1    = (const float*)d_in[14];
    const float* w2    = (const float*)d_in[15];
    const float* b2    = (const float*)d_in[16];

    float* X = (float*)d_out;                   // fp32 residual stream

    u16* normed = (u16*)d_ws;                               // 8192*256
    u16* qkv    = normed + (size_t)M_ROWS * 256;            // 8192*768
    u16* ab     = qkv + (size_t)M_ROWS * QKV_N;             // 8192*256
    u16* h1     = qkv;   // aliases qkv+ab exactly: 8192*1024
    u16* wqkv_t = ab + (size_t)M_ROWS * 256;                // 6*768*256
    u16* wo_t   = wqkv_t + (size_t)N_LAYERSC * QKV_N * 256; // 6*256*256
    u16* w1_t   = wo_t + (size_t)N_LAYERSC * 256 * 256;     // 6*1024*256
    u16* w2_t   = w1_t + (size_t)N_LAYERSC * D_FFC * 256;   // 6*256*1024
    float* qkvb = (float*)(w2_t + (size_t)N_LAYERSC * 256 * D_FFC); // 6*768 fp32
    u16* VTb    = (u16*)(qkvb + N_LAYERSC * QKV_N);         // 256*8192

    dim3 blk(256);

    // ---- weight prep (every call; graph-safe)
    transpose_w<<<dim3(8, 8, 6),  blk, 0, stream>>>(wq, wqkv_t,             256, 256, 65536, QKV_N * 256, QSCALE);
    transpose_w<<<dim3(8, 8, 6),  blk, 0, stream>>>(wk, wqkv_t + 256 * 256, 256, 256, 65536, QKV_N * 256, 1.0f);
    transpose_w<<<dim3(8, 8, 6),  blk, 0, stream>>>(wv, wqkv_t + 512 * 256, 256, 256, 65536, QKV_N * 256, 1.0f);
    transpose_w<<<dim3(8, 8, 6),  blk, 0, stream>>>(wo, wo_t,               256, 256, 65536, 65536, 1.0f);
    transpose_w<<<dim3(32, 8, 6), blk, 0, stream>>>(w1, w1_t,               256, D_FFC, 256 * D_FFC, 256 * D_FFC, 1.0f);
    transpose_w<<<dim3(8, 32, 6), blk, 0, stream>>>(w2, w2_t,               D_FFC, 256, 256 * D_FFC, 256 * D_FFC, 1.0f);
    pack_bias<<<dim3(18), blk, 0, stream>>>(bq, bk, bv, qkvb);

    hipMemcpyAsync(X, x, (size_t)M_ROWS * 256 * sizeof(float),
                   hipMemcpyDeviceToDevice, stream);

    dim3 g_ln(M_ROWS / 4);
    dim3 g_qkv(QKV_N / 128, M_ROWS / 128);      // (6,64)
    dim3 g_d(256 / 128, M_ROWS / 128);          // (2,64)
    dim3 g_ff(D_FFC / 128, M_ROWS / 128);       // (8,64)
    dim3 g_vt(M_ROWS / 64, N_HEADSC);           // (128,8)
    dim3 g_attn(T_SEQ / 128, N_HEADSC, B_SZ);   // (16,8,4)

    for (int l = 0; l < N_LAYERSC; l++) {
        ln_kernel<<<g_ln, blk, 0, stream>>>(X, ln1_s + l * 256, ln1_b + l * 256, normed);
        mfma_gemm<0><<<g_qkv, blk, 0, stream>>>(
            normed, wqkv_t + (size_t)l * QKV_N * 256, qkvb + l * QKV_N,
            nullptr, qkv, QKV_N, 256);
        transpose_v<<<g_vt, blk, 0, stream>>>(qkv, VTb);
        attn_kernel<<<g_attn, blk, 0, stream>>>(qkv, VTb, ab);
        mfma_gemm<1><<<g_d, blk, 0, stream>>>(
            ab, wo_t + (size_t)l * 256 * 256, bo + l * 256, X, X, 256, 256);
        ln_kernel<<<g_ln, blk, 0, stream>>>(X, ln2_s + l * 256, ln2_b + l * 256, normed);
        mfma_gemm<2><<<g_ff, blk, 0, stream>>>(
            normed, w1_t + (size_t)l * D_FFC * 256, b1 + l * D_FFC,
            nullptr, h1, D_FFC, 256);
        mfma_gemm<1><<<g_d, blk, 0, stream>>>(
            h1, w2_t + (size_t)l * 256 * D_FFC, b2 + l * 256, X, X, 256, D_FFC);
    }
}

// Round 7
// 913.627 us; speedup vs baseline: 1.0582x; 1.0582x over previous
//
#include <hip/hip_runtime.h>
#include <math.h>

#define D_MODELC 256
#define N_LAYERSC 6
#define N_HEADSC 8
#define D_FFC 1024
#define HEAD_DIMC 32
#define B_SZ 4
#define T_SEQ 2048
#define M_ROWS 8192
#define QKV_N 768

typedef short bf16x8 __attribute__((ext_vector_type(8)));
typedef short bf16x4 __attribute__((ext_vector_type(4)));
typedef float f32x4  __attribute__((ext_vector_type(4)));
typedef unsigned u32x4 __attribute__((ext_vector_type(4)));
typedef unsigned short u16;

// scale(1/sqrt(32)) * log2(e) folded into wq at conversion time
#define QSCALE 0.25503488f

__device__ __forceinline__ u16 f2bf(float x) {
    unsigned u = __builtin_bit_cast(unsigned, x);
    u += 0x7FFF + ((u >> 16) & 1);          // round-to-nearest-even
    return (u16)(u >> 16);
}

__device__ __forceinline__ float bf2f(short x) {
    return __builtin_bit_cast(float, (unsigned)((u16)x) << 16);
}

__device__ __forceinline__ unsigned pack2bf(float a, float b) {  // truncating
    unsigned ua = __builtin_bit_cast(unsigned, a);
    unsigned ub = __builtin_bit_cast(unsigned, b);
    return (ua >> 16) | (ub & 0xFFFF0000u);
}

__device__ __forceinline__ void async_lds16(const void* g, void* l) {
    __builtin_amdgcn_global_load_lds(
        (const __attribute__((address_space(1))) unsigned int*)g,
        (__attribute__((address_space(3))) unsigned int*)l, 16, 0, 0);
}

// ---------------------------------------------------------------------------
// Weight transpose+convert: dst[n][k] = bf16(src[k][n] * scale), per layer z.
// ---------------------------------------------------------------------------
__global__ __launch_bounds__(256) void transpose_w(
    const float* __restrict__ src, u16* __restrict__ dst,
    int K, int N, int srcLS, int dstLS, float scale)
{
    __shared__ float t[32][33];
    src += (size_t)blockIdx.z * srcLS;
    dst += (size_t)blockIdx.z * dstLS;
    const int k0 = blockIdx.y * 32, n0 = blockIdx.x * 32;
    const int r = threadIdx.x >> 3, c4 = (threadIdx.x & 7) * 4;
    const float4 v = *(const float4*)(src + (size_t)(k0 + r) * N + n0 + c4);
    t[r][c4 + 0] = v.x; t[r][c4 + 1] = v.y;
    t[r][c4 + 2] = v.z; t[r][c4 + 3] = v.w;
    __syncthreads();
    bf16x4 o;
#pragma unroll
    for (int i = 0; i < 4; i++) o[i] = (short)f2bf(t[c4 + i][r] * scale);
    *(bf16x4*)(dst + (size_t)(n0 + r) * K + k0 + c4) = o;
}

// Fused QKV bias: [l][768] = [ bq*QSCALE | bk | bv ]
__global__ __launch_bounds__(256) void pack_bias(
    const float* __restrict__ bq, const float* __restrict__ bk,
    const float* __restrict__ bv, float* __restrict__ dst)
{
    int i = blockIdx.x * 256 + threadIdx.x;
    if (i >= N_LAYERSC * QKV_N) return;
    int l = i / QKV_N, j = i % QKV_N;
    float v;
    if (j < 256)      v = bq[l * 256 + j] * QSCALE;
    else if (j < 512) v = bk[l * 256 + j - 256];
    else              v = bv[l * 256 + j - 512];
    dst[i] = v;
}

// ---------------------------------------------------------------------------
// V transpose (per layer): VT[h*32+dim][token 0..8191] = V from qkv cols 512+.
// ---------------------------------------------------------------------------
__global__ __launch_bounds__(256) void transpose_v(
    const u16* __restrict__ QKV, u16* __restrict__ VT)
{
    __shared__ u16 T[64][40];                     // 80B rows: b128-aligned
    const int h = blockIdx.y;
    const int row0 = blockIdx.x * 64;
    const int t = threadIdx.x;
    {
        const int r = t >> 2, d8 = (t & 3) * 8;
        *(bf16x8*)&T[r][d8] =
            *(const bf16x8*)&QKV[(size_t)(row0 + r) * QKV_N + 512 + h * 32 + d8];
    }
    __syncthreads();
    const int dim = t >> 3, ko = (t & 7) * 8;
    bf16x8 o;
#pragma unroll
    for (int j = 0; j < 8; j++) o[j] = (short)T[ko + j][dim];
    *(bf16x8*)&VT[((size_t)h * 32 + dim) * M_ROWS + row0 + ko] = o;
}

// ---------------------------------------------------------------------------
// LayerNorm: wave per row (64 lanes x float4), bf16 output.
// ---------------------------------------------------------------------------
__global__ __launch_bounds__(256) void ln_kernel(
    const float* __restrict__ X, const float* __restrict__ gamma,
    const float* __restrict__ beta, u16* __restrict__ Y)
{
    const int w = threadIdx.x >> 6, lane = threadIdx.x & 63;
    const int row = blockIdx.x * 4 + w;
    const float4 v = *(const float4*)(X + (size_t)row * 256 + lane * 4);
    float sum = v.x + v.y + v.z + v.w;
    float sq  = v.x * v.x + v.y * v.y + v.z * v.z + v.w * v.w;
#pragma unroll
    for (int off = 32; off > 0; off >>= 1) {
        sum += __shfl_xor(sum, off, 64);
        sq  += __shfl_xor(sq,  off, 64);
    }
    float mu  = sum * (1.0f / 256.0f);
    float var = sq * (1.0f / 256.0f) - mu * mu;
    float rr  = rsqrtf(var + 1e-5f);
    const float4 g  = *(const float4*)(gamma + lane * 4);
    const float4 bb = *(const float4*)(beta + lane * 4);
    bf16x4 o;
    o[0] = (short)f2bf((v.x - mu) * rr * g.x + bb.x);
    o[1] = (short)f2bf((v.y - mu) * rr * g.y + bb.y);
    o[2] = (short)f2bf((v.z - mu) * rr * g.z + bb.z);
    o[3] = (short)f2bf((v.w - mu) * rr * g.w + bb.w);
    *(bf16x4*)(Y + (size_t)row * 256 + lane * 4) = o;
}

// ---------------------------------------------------------------------------
// MFMA GEMM (m97 structure): 128x128 tile, BK=64, async width-16 staging.
// EPI: 0 = bf16 out (+bias); 1 = fp32 out (+bias+resid); 2 = bf16 gelu(+bias)
// ---------------------------------------------------------------------------
template <int EPI>
__global__ __launch_bounds__(256) void mfma_gemm(
    const u16* __restrict__ A, const u16* __restrict__ Bt,
    const float* __restrict__ bias, const float* __restrict__ resid,
    void* __restrict__ Cout, int N, int K)
{
    __shared__ u16 As[128 * 64];
    __shared__ u16 Bs[128 * 64];
    const int tid = threadIdx.x, w = tid >> 6, lane = tid & 63;
    const int c = lane & 15, quad = lane >> 4;
    const int row0 = blockIdx.y * 128, col0 = blockIdx.x * 128;
    const int wr = w >> 1, wc = w & 1;

    f32x4 acc[4][4] = {};

    for (int k0 = 0; k0 < K; k0 += 64) {
        __syncthreads();
#pragma unroll
        for (int ci = 0; ci < 4; ci++) {
            const int fb = (w * 4 + ci) * 1024;
            const int fl = fb + lane * 16;
            const int r = fl >> 7, col = (fl & 127) >> 1;
            async_lds16(A  + (size_t)(row0 + r) * K + k0 + col, (char*)As + fb);
            async_lds16(Bt + (size_t)(col0 + r) * K + k0 + col, (char*)Bs + fb);
        }
        __syncthreads();
#pragma unroll
        for (int kk = 0; kk < 2; kk++) {
            bf16x8 af[4], bfv[4];
#pragma unroll
            for (int i = 0; i < 4; i++)
                af[i] = *(const bf16x8*)&As[(wr * 64 + i * 16 + c) * 64 + kk * 32 + quad * 8];
#pragma unroll
            for (int j = 0; j < 4; j++)
                bfv[j] = *(const bf16x8*)&Bs[(wc * 64 + j * 16 + c) * 64 + kk * 32 + quad * 8];
#pragma unroll
            for (int i = 0; i < 4; i++)
#pragma unroll
                for (int j = 0; j < 4; j++)
                    acc[i][j] = __builtin_amdgcn_mfma_f32_16x16x32_bf16(
                        af[i], bfv[j], acc[i][j], 0, 0, 0);
        }
    }

    float bj[4];
#pragma unroll
    for (int j = 0; j < 4; j++) bj[j] = bias[col0 + wc * 64 + j * 16 + c];

#pragma unroll
    for (int i = 0; i < 4; i++) {
#pragma unroll
        for (int r = 0; r < 4; r++) {
            const int gr = row0 + wr * 64 + i * 16 + quad * 4 + r;
#pragma unroll
            for (int j = 0; j < 4; j++) {
                const int gc = col0 + wc * 64 + j * 16 + c;
                float v = acc[i][j][r] + bj[j];
                if (EPI == 1) {
                    ((float*)Cout)[(size_t)gr * N + gc] = v + resid[(size_t)gr * N + gc];
                } else {
                    if (EPI == 2) v = 0.5f * v * (1.0f + erff(v * 0.70710678118654752f));
                    ((u16*)Cout)[(size_t)gr * N + gc] = f2bf(v);
                }
            }
        }
    }
}

// ---------------------------------------------------------------------------
// MFMA flash attention v3 (fixed): v2 structure + KEY-SPLIT x2 for occupancy.
// Partials are additive (p = 2^S, no max/rescale). Block (qtile, half) does
// 128 queries x 1024 keys; writes un-normalized O-partial (bf16) into its
// half's DEDICATED buffer (POa/POb - neither aliases any live input) +
// l-partial (fp32). attn_merge combines.
// ---------------------------------------------------------------------------
__global__ __launch_bounds__(256) void attn_kernel(
    const u16* __restrict__ QKV, const u16* __restrict__ VT,
    u16* __restrict__ POa, u16* __restrict__ POb, float* __restrict__ Lp)
{
    const int h = blockIdx.y, b = blockIdx.z;
    const int half = blockIdx.x & 1;
    const int q0 = (blockIdx.x >> 1) * 128;
    const int tid = threadIdx.x, w = tid >> 6, lane = tid & 63;
    const int c = lane & 15, quad = lane >> 4;

    __shared__ u16 Kf[2048];   // fragment order: granule g*64+lane
    __shared__ u16 Vf[2048];

    const u16* qp = QKV + (size_t)(b * T_SEQ + q0 + w * 32 + c) * QKV_N + h * 32 + quad * 8;
    bf16x8 aQ0 = *(const bf16x8*)qp;                 // B-frag, q = qg*16+c
    bf16x8 aQ1 = *(const bf16x8*)(qp + 16 * QKV_N);

    float l0 = 0.f, l1 = 0.f;
    f32x4 O[2][2] = {};                              // [qg][dim half]

    const u16* kgp = QKV + (size_t)(b * T_SEQ + w * 16 + c) * QKV_N + 256 + h * 32 + quad * 8;
    const u16* vgp = VT + ((size_t)h * 32 + (lane & 31)) * M_ROWS + b * T_SEQ
                     + (w * 2 + (lane >> 5)) * 8;
    u16* kfw = Kf + w * 512;
    u16* vfw = Vf + w * 512;
    const int LA = (quad & 1) * 32 + c, LB = LA + 16;
    const bool gsel = quad < 2;

    const int kbeg = half * (T_SEQ / 2);
    for (int k0 = kbeg; k0 < kbeg + T_SEQ / 2; k0 += 64) {
        __syncthreads();                             // prior readers done
        async_lds16(kgp + (size_t)k0 * QKV_N, kfw);
        async_lds16(vgp + k0, vfw);
        __syncthreads();                             // staging landed

        unsigned pk[4][2][2];
#pragma unroll
        for (int g = 0; g < 4; g++) {
            bf16x8 aK = *(const bf16x8*)&Kf[g * 512 + lane * 8];
            f32x4 S0 = __builtin_amdgcn_mfma_f32_16x16x32_bf16(
                aK, aQ0, (f32x4){0.f, 0.f, 0.f, 0.f}, 0, 0, 0);
            f32x4 S1 = __builtin_amdgcn_mfma_f32_16x16x32_bf16(
                aK, aQ1, (f32x4){0.f, 0.f, 0.f, 0.f}, 0, 0, 0);
            float p0 = exp2f(S0[0]), p1 = exp2f(S0[1]);
            float p2 = exp2f(S0[2]), p3 = exp2f(S0[3]);
            l0 += (p0 + p1) + (p2 + p3);
            pk[g][0][0] = pack2bf(p0, p1);
            pk[g][0][1] = pack2bf(p2, p3);
            p0 = exp2f(S1[0]); p1 = exp2f(S1[1]);
            p2 = exp2f(S1[2]); p3 = exp2f(S1[3]);
            l1 += (p0 + p1) + (p2 + p3);
            pk[g][1][0] = pack2bf(p0, p1);
            pk[g][1][1] = pack2bf(p2, p3);
        }

#pragma unroll
        for (int kh = 0; kh < 2; kh++) {
            bf16x8 bV0 = *(const bf16x8*)&Vf[((kh * 4 + quad) * 32 + c) * 8];
            bf16x8 bV1 = *(const bf16x8*)&Vf[((kh * 4 + quad) * 32 + 16 + c) * 8];
#pragma unroll
            for (int qg = 0; qg < 2; qg++) {
                int e00 = __shfl((int)pk[2 * kh][qg][0],     LA, 64);
                int e01 = __shfl((int)pk[2 * kh + 1][qg][0], LA, 64);
                int e10 = __shfl((int)pk[2 * kh][qg][1],     LA, 64);
                int e11 = __shfl((int)pk[2 * kh + 1][qg][1], LA, 64);
                int e20 = __shfl((int)pk[2 * kh][qg][0],     LB, 64);
                int e21 = __shfl((int)pk[2 * kh + 1][qg][0], LB, 64);
                int e30 = __shfl((int)pk[2 * kh][qg][1],     LB, 64);
                int e31 = __shfl((int)pk[2 * kh + 1][qg][1], LB, 64);
                u32x4 ap;
                ap[0] = (unsigned)(gsel ? e00 : e01);
                ap[1] = (unsigned)(gsel ? e10 : e11);
                ap[2] = (unsigned)(gsel ? e20 : e21);
                ap[3] = (unsigned)(gsel ? e30 : e31);
                bf16x8 aP = __builtin_bit_cast(bf16x8, ap);
                O[qg][0] = __builtin_amdgcn_mfma_f32_16x16x32_bf16(aP, bV0, O[qg][0], 0, 0, 0);
                O[qg][1] = __builtin_amdgcn_mfma_f32_16x16x32_bf16(aP, bV1, O[qg][1], 0, 0, 0);
            }
        }
    }

    // full l per q=qg*16+c on every lane
    l0 += __shfl_xor(l0, 16, 64); l0 += __shfl_xor(l0, 32, 64);
    l1 += __shfl_xor(l1, 16, 64); l1 += __shfl_xor(l1, 32, 64);

    // un-normalized partial O (bf16) + partial l (fp32) into THIS half's buffer
    u16* pb = (half ? POb : POa)
              + (size_t)(b * T_SEQ + q0 + w * 32) * 256 + h * 32;
    if (quad == 0) {
        float* lb = Lp + (size_t)half * M_ROWS * 8
                    + (size_t)(b * T_SEQ + q0 + w * 32) * 8 + h;
        lb[(size_t)c * 8]        = l0;
        lb[(size_t)(16 + c) * 8] = l1;
    }
#pragma unroll
    for (int r = 0; r < 4; r++) {
        int src = quad * 4 + r;
        pb[(size_t)src * 256 + c]             = f2bf(O[0][0][r]);
        pb[(size_t)src * 256 + 16 + c]        = f2bf(O[0][1][r]);
        pb[(size_t)(16 + src) * 256 + c]      = f2bf(O[1][0][r]);
        pb[(size_t)(16 + src) * 256 + 16 + c] = f2bf(O[1][1][r]);
    }
}

// ---------------------------------------------------------------------------
// Merge the two key-halves: Ob = (POa + POb) / (la + lb). Wave per row.
// ---------------------------------------------------------------------------
__global__ __launch_bounds__(256) void attn_merge(
    const u16* __restrict__ POa, const u16* __restrict__ POb,
    const float* __restrict__ Lp, u16* __restrict__ Ob)
{
    const int w = threadIdx.x >> 6, lane = threadIdx.x & 63;
    const int row = blockIdx.x * 4 + w;
    const int head = lane >> 3;
    const float la = Lp[(size_t)row * 8 + head];
    const float lb = Lp[(size_t)M_ROWS * 8 + (size_t)row * 8 + head];
    const float inv = 1.0f / (la + lb);
    bf16x4 a = *(const bf16x4*)&POa[(size_t)row * 256 + lane * 4];
    bf16x4 b = *(const bf16x4*)&POb[(size_t)row * 256 + lane * 4];
    bf16x4 o;
#pragma unroll
    for (int i = 0; i < 4; i++) o[i] = (short)f2bf((bf2f(a[i]) + bf2f(b[i])) * inv);
    *(bf16x4*)&Ob[(size_t)row * 256 + lane * 4] = o;
}

// ---------------------------------------------------------------------------
extern "C" void kernel_launch(void* const* d_in, const int* in_sizes, int n_in,
                              void* d_out, int out_size, void* d_ws, size_t ws_size,
                              hipStream_t stream)
{
    const float* x     = (const float*)d_in[0];
    const float* ln1_s = (const float*)d_in[1];
    const float* ln1_b = (const float*)d_in[2];
    const float* wq    = (const float*)d_in[3];
    const float* bq    = (const float*)d_in[4];
    const float* wk    = (const float*)d_in[5];
    const float* bk    = (const float*)d_in[6];
    const float* wv    = (const float*)d_in[7];
    const float* bv    = (const float*)d_in[8];
    const float* wo    = (const float*)d_in[9];
    const float* bo    = (const float*)d_in[10];
    const float* ln2_s = (const float*)d_in[11];
    const float* ln2_b = (const float*)d_in[12];
    const float* w1    = (const float*)d_in[13];
    const float* b1    = (const float*)d_in[14];
    const float* w2    = (const float*)d_in[15];
    const float* b2    = (const float*)d_in[16];

    float* X = (float*)d_out;                   // fp32 residual stream

    // Workspace layout (u16 elements). No live-overlap anywhere:
    //   attn writes POa/POb/Lp only; merge writes normed (dead then);
    //   h1 (=qkv..POa span) only live between ffn1/ffn2, when POa is dead.
    u16* normed = (u16*)d_ws;                               // 8192*256
    u16* qkv    = normed + (size_t)M_ROWS * 256;            // 8192*768
    u16* POa    = qkv + (size_t)M_ROWS * QKV_N;             // 8192*256
    u16* h1     = qkv;   // spans qkv+POa exactly: 8192*1024
    u16* wqkv_t = POa + (size_t)M_ROWS * 256;               // 6*768*256
    u16* wo_t   = wqkv_t + (size_t)N_LAYERSC * QKV_N * 256; // 6*256*256
    u16* w1_t   = wo_t + (size_t)N_LAYERSC * 256 * 256;     // 6*1024*256
    u16* w2_t   = w1_t + (size_t)N_LAYERSC * D_FFC * 256;   // 6*256*1024
    float* qkvb = (float*)(w2_t + (size_t)N_LAYERSC * 256 * D_FFC); // 6*768 fp32
    u16* VTb    = (u16*)(qkvb + N_LAYERSC * QKV_N);         // 256*8192
    u16* POb    = VTb + (size_t)256 * M_ROWS;               // 8192*256
    float* Lp   = (float*)(POb + (size_t)M_ROWS * 256);     // 2*8192*8 fp32
    // end ~= 37.5 MB (round 1 proved ws >= 40 MB)

    dim3 blk(256);

    // ---- weight prep (every call; graph-safe)
    transpose_w<<<dim3(8, 8, 6),  blk, 0, stream>>>(wq, wqkv_t,             256, 256, 65536, QKV_N * 256, QSCALE);
    transpose_w<<<dim3(8, 8, 6),  blk, 0, stream>>>(wk, wqkv_t + 256 * 256, 256, 256, 65536, QKV_N * 256, 1.0f);
    transpose_w<<<dim3(8, 8, 6),  blk, 0, stream>>>(wv, wqkv_t + 512 * 256, 256, 256, 65536, QKV_N * 256, 1.0f);
    transpose_w<<<dim3(8, 8, 6),  blk, 0, stream>>>(wo, wo_t,               256, 256, 65536, 65536, 1.0f);
    transpose_w<<<dim3(32, 8, 6), blk, 0, stream>>>(w1, w1_t,               256, D_FFC, 256 * D_FFC, 256 * D_FFC, 1.0f);
    transpose_w<<<dim3(8, 32, 6), blk, 0, stream>>>(w2, w2_t,               D_FFC, 256, 256 * D_FFC, 256 * D_FFC, 1.0f);
    pack_bias<<<dim3(18), blk, 0, stream>>>(bq, bk, bv, qkvb);

    hipMemcpyAsync(X, x, (size_t)M_ROWS * 256 * sizeof(float),
                   hipMemcpyDeviceToDevice, stream);

    dim3 g_ln(M_ROWS / 4);
    dim3 g_qkv(QKV_N / 128, M_ROWS / 128);          // (6,64)
    dim3 g_d(256 / 128, M_ROWS / 128);              // (2,64)
    dim3 g_ff(D_FFC / 128, M_ROWS / 128);           // (8,64)
    dim3 g_vt(M_ROWS / 64, N_HEADSC);               // (128,8)
    dim3 g_attn(2 * T_SEQ / 128, N_HEADSC, B_SZ);   // (32,8,4) = 1024 blocks
    dim3 g_mrg(M_ROWS / 4);

    for (int l = 0; l < N_LAYERSC; l++) {
        ln_kernel<<<g_ln, blk, 0, stream>>>(X, ln1_s + l * 256, ln1_b + l * 256, normed);
        mfma_gemm<0><<<g_qkv, blk, 0, stream>>>(
            normed, wqkv_t + (size_t)l * QKV_N * 256, qkvb + l * QKV_N,
            nullptr, qkv, QKV_N, 256);
        transpose_v<<<g_vt, blk, 0, stream>>>(qkv, VTb);
        attn_kernel<<<g_attn, blk, 0, stream>>>(qkv, VTb, POa, POb, Lp);
        attn_merge<<<g_mrg, blk, 0, stream>>>(POa, POb, Lp, normed);
        mfma_gemm<1><<<g_d, blk, 0, stream>>>(
            normed, wo_t + (size_t)l * 256 * 256, bo + l * 256, X, X, 256, 256);
        ln_kernel<<<g_ln, blk, 0, stream>>>(X, ln2_s + l * 256, ln2_b + l * 256, normed);
        mfma_gemm<2><<<g_ff, blk, 0, stream>>>(
            normed, w1_t + (size_t)l * D_FFC * 256, b1 + l * D_FFC,
            nullptr, h1, D_FFC, 256);
        mfma_gemm<1><<<g_d, blk, 0, stream>>>(
            h1, w2_t + (size_t)l * 256 * D_FFC, b2 + l * 256, X, X, 256, D_FFC);
    }
}

// Round 8
// 839.342 us; speedup vs baseline: 1.1518x; 1.0885x over previous
//
#include <hip/hip_runtime.h>
#include <math.h>

#define D_MODELC 256
#define N_LAYERSC 6
#define N_HEADSC 8
#define D_FFC 1024
#define HEAD_DIMC 32
#define B_SZ 4
#define T_SEQ 2048
#define M_ROWS 8192
#define QKV_N 768

typedef short bf16x8 __attribute__((ext_vector_type(8)));
typedef short bf16x4 __attribute__((ext_vector_type(4)));
typedef float f32x4  __attribute__((ext_vector_type(4)));
typedef unsigned u32x4 __attribute__((ext_vector_type(4)));
typedef unsigned short u16;

// scale(1/sqrt(32)) * log2(e) folded into wq at conversion time
#define QSCALE 0.25503488f

__device__ __forceinline__ u16 f2bf(float x) {
    unsigned u = __builtin_bit_cast(unsigned, x);
    u += 0x7FFF + ((u >> 16) & 1);          // round-to-nearest-even
    return (u16)(u >> 16);
}

__device__ __forceinline__ float bf2f(short x) {
    return __builtin_bit_cast(float, (unsigned)((u16)x) << 16);
}

__device__ __forceinline__ unsigned pack2bf(float a, float b) {  // truncating
    unsigned ua = __builtin_bit_cast(unsigned, a);
    unsigned ub = __builtin_bit_cast(unsigned, b);
    return (ua >> 16) | (ub & 0xFFFF0000u);
}

__device__ __forceinline__ void async_lds16(const void* g, void* l) {
    __builtin_amdgcn_global_load_lds(
        (const __attribute__((address_space(1))) unsigned int*)g,
        (__attribute__((address_space(3))) unsigned int*)l, 16, 0, 0);
}

// ---------------------------------------------------------------------------
// Weight transpose+convert: dst[n][k] = bf16(src[k][n] * scale), per layer z.
// ---------------------------------------------------------------------------
__global__ __launch_bounds__(256) void transpose_w(
    const float* __restrict__ src, u16* __restrict__ dst,
    int K, int N, int srcLS, int dstLS, float scale)
{
    __shared__ float t[32][33];
    src += (size_t)blockIdx.z * srcLS;
    dst += (size_t)blockIdx.z * dstLS;
    const int k0 = blockIdx.y * 32, n0 = blockIdx.x * 32;
    const int r = threadIdx.x >> 3, c4 = (threadIdx.x & 7) * 4;
    const float4 v = *(const float4*)(src + (size_t)(k0 + r) * N + n0 + c4);
    t[r][c4 + 0] = v.x; t[r][c4 + 1] = v.y;
    t[r][c4 + 2] = v.z; t[r][c4 + 3] = v.w;
    __syncthreads();
    bf16x4 o;
#pragma unroll
    for (int i = 0; i < 4; i++) o[i] = (short)f2bf(t[c4 + i][r] * scale);
    *(bf16x4*)(dst + (size_t)(n0 + r) * K + k0 + c4) = o;
}

// Fused QKV bias: [l][768] = [ bq*QSCALE | bk | bv ]
__global__ __launch_bounds__(256) void pack_bias(
    const float* __restrict__ bq, const float* __restrict__ bk,
    const float* __restrict__ bv, float* __restrict__ dst)
{
    int i = blockIdx.x * 256 + threadIdx.x;
    if (i >= N_LAYERSC * QKV_N) return;
    int l = i / QKV_N, j = i % QKV_N;
    float v;
    if (j < 256)      v = bq[l * 256 + j] * QSCALE;
    else if (j < 512) v = bk[l * 256 + j - 256];
    else              v = bv[l * 256 + j - 512];
    dst[i] = v;
}

// ---------------------------------------------------------------------------
// V transpose (per layer): VT[h*32+dim][token 0..8191] = V from qkv cols 512+.
// ---------------------------------------------------------------------------
__global__ __launch_bounds__(256) void transpose_v(
    const u16* __restrict__ QKV, u16* __restrict__ VT)
{
    __shared__ u16 T[64][40];                     // 80B rows: b128-aligned
    const int h = blockIdx.y;
    const int row0 = blockIdx.x * 64;
    const int t = threadIdx.x;
    {
        const int r = t >> 2, d8 = (t & 3) * 8;
        *(bf16x8*)&T[r][d8] =
            *(const bf16x8*)&QKV[(size_t)(row0 + r) * QKV_N + 512 + h * 32 + d8];
    }
    __syncthreads();
    const int dim = t >> 3, ko = (t & 7) * 8;
    bf16x8 o;
#pragma unroll
    for (int j = 0; j < 8; j++) o[j] = (short)T[ko + j][dim];
    *(bf16x8*)&VT[((size_t)h * 32 + dim) * M_ROWS + row0 + ko] = o;
}

// ---------------------------------------------------------------------------
// LayerNorm: wave per row (64 lanes x float4), bf16 output.
// ---------------------------------------------------------------------------
__global__ __launch_bounds__(256) void ln_kernel(
    const float* __restrict__ X, const float* __restrict__ gamma,
    const float* __restrict__ beta, u16* __restrict__ Y)
{
    const int w = threadIdx.x >> 6, lane = threadIdx.x & 63;
    const int row = blockIdx.x * 4 + w;
    const float4 v = *(const float4*)(X + (size_t)row * 256 + lane * 4);
    float sum = v.x + v.y + v.z + v.w;
    float sq  = v.x * v.x + v.y * v.y + v.z * v.z + v.w * v.w;
#pragma unroll
    for (int off = 32; off > 0; off >>= 1) {
        sum += __shfl_xor(sum, off, 64);
        sq  += __shfl_xor(sq,  off, 64);
    }
    float mu  = sum * (1.0f / 256.0f);
    float var = sq * (1.0f / 256.0f) - mu * mu;
    float rr  = rsqrtf(var + 1e-5f);
    const float4 g  = *(const float4*)(gamma + lane * 4);
    const float4 bb = *(const float4*)(beta + lane * 4);
    bf16x4 o;
    o[0] = (short)f2bf((v.x - mu) * rr * g.x + bb.x);
    o[1] = (short)f2bf((v.y - mu) * rr * g.y + bb.y);
    o[2] = (short)f2bf((v.z - mu) * rr * g.z + bb.z);
    o[3] = (short)f2bf((v.w - mu) * rr * g.w + bb.w);
    *(bf16x4*)(Y + (size_t)row * 256 + lane * 4) = o;
}

// ---------------------------------------------------------------------------
// MFMA GEMM (m97 structure), tile BM x 128, BK=64, async width-16 staging.
// BM = 128 (4x4 acc) or 64 (2x4 acc; grid 2x128 fills all 256 CUs for N=256).
// EPI: 0 = bf16 out (+bias); 1 = fp32 out (+bias+resid); 2 = bf16 gelu(+bias)
// ---------------------------------------------------------------------------
template <int EPI, int BM>
__global__ __launch_bounds__(256) void mfma_gemm(
    const u16* __restrict__ A, const u16* __restrict__ Bt,
    const float* __restrict__ bias, const float* __restrict__ resid,
    void* __restrict__ Cout, int N, int K)
{
    constexpr int IT = BM / 32;                  // acc rows per wave
    __shared__ u16 As[BM * 64];
    __shared__ u16 Bs[128 * 64];
    const int tid = threadIdx.x, w = tid >> 6, lane = tid & 63;
    const int c = lane & 15, quad = lane >> 4;
    const int row0 = blockIdx.y * BM, col0 = blockIdx.x * 128;
    const int wr = w >> 1, wc = w & 1;

    f32x4 acc[IT][4] = {};

    for (int k0 = 0; k0 < K; k0 += 64) {
        __syncthreads();
#pragma unroll
        for (int ci = 0; ci < IT; ci++) {        // A: BM*128 bytes total
            const int fb = (w * IT + ci) * 1024;
            const int fl = fb + lane * 16;
            const int r = fl >> 7, col = (fl & 127) >> 1;
            async_lds16(A + (size_t)(row0 + r) * K + k0 + col, (char*)As + fb);
        }
#pragma unroll
        for (int ci = 0; ci < 4; ci++) {         // B: 128*128 bytes total
            const int fb = (w * 4 + ci) * 1024;
            const int fl = fb + lane * 16;
            const int r = fl >> 7, col = (fl & 127) >> 1;
            async_lds16(Bt + (size_t)(col0 + r) * K + k0 + col, (char*)Bs + fb);
        }
        __syncthreads();
#pragma unroll
        for (int kk = 0; kk < 2; kk++) {
            bf16x8 af[IT], bfv[4];
#pragma unroll
            for (int i = 0; i < IT; i++)
                af[i] = *(const bf16x8*)&As[(wr * (BM / 2) + i * 16 + c) * 64 + kk * 32 + quad * 8];
#pragma unroll
            for (int j = 0; j < 4; j++)
                bfv[j] = *(const bf16x8*)&Bs[(wc * 64 + j * 16 + c) * 64 + kk * 32 + quad * 8];
#pragma unroll
            for (int i = 0; i < IT; i++)
#pragma unroll
                for (int j = 0; j < 4; j++)
                    acc[i][j] = __builtin_amdgcn_mfma_f32_16x16x32_bf16(
                        af[i], bfv[j], acc[i][j], 0, 0, 0);
        }
    }

    float bj[4];
#pragma unroll
    for (int j = 0; j < 4; j++) bj[j] = bias[col0 + wc * 64 + j * 16 + c];

#pragma unroll
    for (int i = 0; i < IT; i++) {
#pragma unroll
        for (int r = 0; r < 4; r++) {
            const int gr = row0 + wr * (BM / 2) + i * 16 + quad * 4 + r;
#pragma unroll
            for (int j = 0; j < 4; j++) {
                const int gc = col0 + wc * 64 + j * 16 + c;
                float v = acc[i][j][r] + bj[j];
                if (EPI == 1) {
                    ((float*)Cout)[(size_t)gr * N + gc] = v + resid[(size_t)gr * N + gc];
                } else {
                    if (EPI == 2) v = 0.5f * v * (1.0f + erff(v * 0.70710678118654752f));
                    ((u16*)Cout)[(size_t)gr * N + gc] = f2bf(v);
                }
            }
        }
    }
}

// ---------------------------------------------------------------------------
// MFMA flash attention v4: v3 + register-prefetch double buffering.
// K/V for tile t+1 are loaded into VGPRs while tile t computes; the barrier
// only orders ds_write -> ds_read (no cold global latency on the sync path).
// Key-split x2 across blocks; partials additive (p = 2^S, no max needed).
// ---------------------------------------------------------------------------
__global__ __launch_bounds__(256) void attn_kernel(
    const u16* __restrict__ QKV, const u16* __restrict__ VT,
    u16* __restrict__ POa, u16* __restrict__ POb, float* __restrict__ Lp)
{
    const int h = blockIdx.y, b = blockIdx.z;
    const int half = blockIdx.x & 1;
    const int q0 = (blockIdx.x >> 1) * 128;
    const int tid = threadIdx.x, w = tid >> 6, lane = tid & 63;
    const int c = lane & 15, quad = lane >> 4;

    __shared__ u16 Kf[2048];   // fragment order: granule g*64+lane
    __shared__ u16 Vf[2048];

    const u16* qp = QKV + (size_t)(b * T_SEQ + q0 + w * 32 + c) * QKV_N + h * 32 + quad * 8;
    bf16x8 aQ0 = *(const bf16x8*)qp;                 // B-frag, q = qg*16+c
    bf16x8 aQ1 = *(const bf16x8*)(qp + 16 * QKV_N);

    float l0 = 0.f, l1 = 0.f;
    f32x4 O[2][2] = {};                              // [qg][dim half]

    const u16* kgp = QKV + (size_t)(b * T_SEQ + w * 16 + c) * QKV_N + 256 + h * 32 + quad * 8;
    const u16* vgp = VT + ((size_t)h * 32 + (lane & 31)) * M_ROWS + b * T_SEQ
                     + (w * 2 + (lane >> 5)) * 8;
    u16* kfw = Kf + w * 512 + lane * 8;              // ds_write_b128 dest
    u16* vfw = Vf + w * 512 + lane * 8;
    const int LA = (quad & 1) * 32 + c, LB = LA + 16;
    const bool gsel = quad < 2;

    const int kbeg = half * (T_SEQ / 2);
    const int kend = kbeg + T_SEQ / 2;

    // prefetch tile 0 into registers
    bf16x8 gK = *(const bf16x8*)(kgp + (size_t)kbeg * QKV_N);
    bf16x8 gV = *(const bf16x8*)(vgp + kbeg);

    for (int k0 = kbeg; k0 < kend; k0 += 64) {
        __syncthreads();                             // prior tile's reads done
        *(bf16x8*)kfw = gK;                          // ds_write_b128
        *(bf16x8*)vfw = gV;
        if (k0 + 64 < kend) {                        // prefetch t+1 (in flight
            gK = *(const bf16x8*)(kgp + (size_t)(k0 + 64) * QKV_N);   // during
            gV = *(const bf16x8*)(vgp + (k0 + 64));                   // compute)
        }
        __syncthreads();                             // ds writes visible

        unsigned pk[4][2][2];
#pragma unroll
        for (int g = 0; g < 4; g++) {
            bf16x8 aK = *(const bf16x8*)&Kf[g * 512 + lane * 8];
            f32x4 S0 = __builtin_amdgcn_mfma_f32_16x16x32_bf16(
                aK, aQ0, (f32x4){0.f, 0.f, 0.f, 0.f}, 0, 0, 0);
            f32x4 S1 = __builtin_amdgcn_mfma_f32_16x16x32_bf16(
                aK, aQ1, (f32x4){0.f, 0.f, 0.f, 0.f}, 0, 0, 0);
            float p0 = exp2f(S0[0]), p1 = exp2f(S0[1]);
            float p2 = exp2f(S0[2]), p3 = exp2f(S0[3]);
            l0 += (p0 + p1) + (p2 + p3);
            pk[g][0][0] = pack2bf(p0, p1);
            pk[g][0][1] = pack2bf(p2, p3);
            p0 = exp2f(S1[0]); p1 = exp2f(S1[1]);
            p2 = exp2f(S1[2]); p3 = exp2f(S1[3]);
            l1 += (p0 + p1) + (p2 + p3);
            pk[g][1][0] = pack2bf(p0, p1);
            pk[g][1][1] = pack2bf(p2, p3);
        }

#pragma unroll
        for (int kh = 0; kh < 2; kh++) {
            bf16x8 bV0 = *(const bf16x8*)&Vf[((kh * 4 + quad) * 32 + c) * 8];
            bf16x8 bV1 = *(const bf16x8*)&Vf[((kh * 4 + quad) * 32 + 16 + c) * 8];
#pragma unroll
            for (int qg = 0; qg < 2; qg++) {
                int e00 = __shfl((int)pk[2 * kh][qg][0],     LA, 64);
                int e01 = __shfl((int)pk[2 * kh + 1][qg][0], LA, 64);
                int e10 = __shfl((int)pk[2 * kh][qg][1],     LA, 64);
                int e11 = __shfl((int)pk[2 * kh + 1][qg][1], LA, 64);
                int e20 = __shfl((int)pk[2 * kh][qg][0],     LB, 64);
                int e21 = __shfl((int)pk[2 * kh + 1][qg][0], LB, 64);
                int e30 = __shfl((int)pk[2 * kh][qg][1],     LB, 64);
                int e31 = __shfl((int)pk[2 * kh + 1][qg][1], LB, 64);
                u32x4 ap;
                ap[0] = (unsigned)(gsel ? e00 : e01);
                ap[1] = (unsigned)(gsel ? e10 : e11);
                ap[2] = (unsigned)(gsel ? e20 : e21);
                ap[3] = (unsigned)(gsel ? e30 : e31);
                bf16x8 aP = __builtin_bit_cast(bf16x8, ap);
                O[qg][0] = __builtin_amdgcn_mfma_f32_16x16x32_bf16(aP, bV0, O[qg][0], 0, 0, 0);
                O[qg][1] = __builtin_amdgcn_mfma_f32_16x16x32_bf16(aP, bV1, O[qg][1], 0, 0, 0);
            }
        }
    }

    // full l per q=qg*16+c on every lane
    l0 += __shfl_xor(l0, 16, 64); l0 += __shfl_xor(l0, 32, 64);
    l1 += __shfl_xor(l1, 16, 64); l1 += __shfl_xor(l1, 32, 64);

    // un-normalized partial O (bf16) + partial l (fp32) into THIS half's buffer
    u16* pb = (half ? POb : POa)
              + (size_t)(b * T_SEQ + q0 + w * 32) * 256 + h * 32;
    if (quad == 0) {
        float* lb = Lp + (size_t)half * M_ROWS * 8
                    + (size_t)(b * T_SEQ + q0 + w * 32) * 8 + h;
        lb[(size_t)c * 8]        = l0;
        lb[(size_t)(16 + c) * 8] = l1;
    }
#pragma unroll
    for (int r = 0; r < 4; r++) {
        int src = quad * 4 + r;
        pb[(size_t)src * 256 + c]             = f2bf(O[0][0][r]);
        pb[(size_t)src * 256 + 16 + c]        = f2bf(O[0][1][r]);
        pb[(size_t)(16 + src) * 256 + c]      = f2bf(O[1][0][r]);
        pb[(size_t)(16 + src) * 256 + 16 + c] = f2bf(O[1][1][r]);
    }
}

// ---------------------------------------------------------------------------
// Merge the two key-halves: Ob = (POa + POb) / (la + lb). Wave per row.
// ---------------------------------------------------------------------------
__global__ __launch_bounds__(256) void attn_merge(
    const u16* __restrict__ POa, const u16* __restrict__ POb,
    const float* __restrict__ Lp, u16* __restrict__ Ob)
{
    const int w = threadIdx.x >> 6, lane = threadIdx.x & 63;
    const int row = blockIdx.x * 4 + w;
    const int head = lane >> 3;
    const float la = Lp[(size_t)row * 8 + head];
    const float lb = Lp[(size_t)M_ROWS * 8 + (size_t)row * 8 + head];
    const float inv = 1.0f / (la + lb);
    bf16x4 a = *(const bf16x4*)&POa[(size_t)row * 256 + lane * 4];
    bf16x4 b = *(const bf16x4*)&POb[(size_t)row * 256 + lane * 4];
    bf16x4 o;
#pragma unroll
    for (int i = 0; i < 4; i++) o[i] = (short)f2bf((bf2f(a[i]) + bf2f(b[i])) * inv);
    *(bf16x4*)&Ob[(size_t)row * 256 + lane * 4] = o;
}

// ---------------------------------------------------------------------------
extern "C" void kernel_launch(void* const* d_in, const int* in_sizes, int n_in,
                              void* d_out, int out_size, void* d_ws, size_t ws_size,
                              hipStream_t stream)
{
    const float* x     = (const float*)d_in[0];
    const float* ln1_s = (const float*)d_in[1];
    const float* ln1_b = (const float*)d_in[2];
    const float* wq    = (const float*)d_in[3];
    const float* bq    = (const float*)d_in[4];
    const float* wk    = (const float*)d_in[5];
    const float* bk    = (const float*)d_in[6];
    const float* wv    = (const float*)d_in[7];
    const float* bv    = (const float*)d_in[8];
    const float* wo    = (const float*)d_in[9];
    const float* bo    = (const float*)d_in[10];
    const float* ln2_s = (const float*)d_in[11];
    const float* ln2_b = (const float*)d_in[12];
    const float* w1    = (const float*)d_in[13];
    const float* b1    = (const float*)d_in[14];
    const float* w2    = (const float*)d_in[15];
    const float* b2    = (const float*)d_in[16];

    float* X = (float*)d_out;                   // fp32 residual stream

    // Workspace layout (u16 elements). No live-overlap anywhere.
    u16* normed = (u16*)d_ws;                               // 8192*256
    u16* qkv    = normed + (size_t)M_ROWS * 256;            // 8192*768
    u16* POa    = qkv + (size_t)M_ROWS * QKV_N;             // 8192*256
    u16* h1     = qkv;   // spans qkv+POa exactly: 8192*1024
    u16* wqkv_t = POa + (size_t)M_ROWS * 256;               // 6*768*256
    u16* wo_t   = wqkv_t + (size_t)N_LAYERSC * QKV_N * 256; // 6*256*256
    u16* w1_t   = wo_t + (size_t)N_LAYERSC * 256 * 256;     // 6*1024*256
    u16* w2_t   = w1_t + (size_t)N_LAYERSC * D_FFC * 256;   // 6*256*1024
    float* qkvb = (float*)(w2_t + (size_t)N_LAYERSC * 256 * D_FFC); // 6*768 fp32
    u16* VTb    = (u16*)(qkvb + N_LAYERSC * QKV_N);         // 256*8192
    u16* POb    = VTb + (size_t)256 * M_ROWS;               // 8192*256
    float* Lp   = (float*)(POb + (size_t)M_ROWS * 256);     // 2*8192*8 fp32

    dim3 blk(256);

    // ---- weight prep (every call; graph-safe)
    transpose_w<<<dim3(8, 8, 6),  blk, 0, stream>>>(wq, wqkv_t,             256, 256, 65536, QKV_N * 256, QSCALE);
    transpose_w<<<dim3(8, 8, 6),  blk, 0, stream>>>(wk, wqkv_t + 256 * 256, 256, 256, 65536, QKV_N * 256, 1.0f);
    transpose_w<<<dim3(8, 8, 6),  blk, 0, stream>>>(wv, wqkv_t + 512 * 256, 256, 256, 65536, QKV_N * 256, 1.0f);
    transpose_w<<<dim3(8, 8, 6),  blk, 0, stream>>>(wo, wo_t,               256, 256, 65536, 65536, 1.0f);
    transpose_w<<<dim3(32, 8, 6), blk, 0, stream>>>(w1, w1_t,               256, D_FFC, 256 * D_FFC, 256 * D_FFC, 1.0f);
    transpose_w<<<dim3(8, 32, 6), blk, 0, stream>>>(w2, w2_t,               D_FFC, 256, 256 * D_FFC, 256 * D_FFC, 1.0f);
    pack_bias<<<dim3(18), blk, 0, stream>>>(bq, bk, bv, qkvb);

    hipMemcpyAsync(X, x, (size_t)M_ROWS * 256 * sizeof(float),
                   hipMemcpyDeviceToDevice, stream);

    dim3 g_ln(M_ROWS / 4);
    dim3 g_qkv(QKV_N / 128, M_ROWS / 128);          // (6,64)   = 384 blocks
    dim3 g_d(256 / 128, M_ROWS / 64);               // (2,128)  = 256 blocks, BM=64
    dim3 g_ff(D_FFC / 128, M_ROWS / 128);           // (8,64)   = 512 blocks
    dim3 g_vt(M_ROWS / 64, N_HEADSC);               // (128,8)
    dim3 g_attn(2 * T_SEQ / 128, N_HEADSC, B_SZ);   // (32,8,4) = 1024 blocks
    dim3 g_mrg(M_ROWS / 4);

    for (int l = 0; l < N_LAYERSC; l++) {
        ln_kernel<<<g_ln, blk, 0, stream>>>(X, ln1_s + l * 256, ln1_b + l * 256, normed);
        mfma_gemm<0, 128><<<g_qkv, blk, 0, stream>>>(
            normed, wqkv_t + (size_t)l * QKV_N * 256, qkvb + l * QKV_N,
            nullptr, qkv, QKV_N, 256);
        transpose_v<<<g_vt, blk, 0, stream>>>(qkv, VTb);
        attn_kernel<<<g_attn, blk, 0, stream>>>(qkv, VTb, POa, POb, Lp);
        attn_merge<<<g_mrg, blk, 0, stream>>>(POa, POb, Lp, normed);
        mfma_gemm<1, 64><<<g_d, blk, 0, stream>>>(
            normed, wo_t + (size_t)l * 256 * 256, bo + l * 256, X, X, 256, 256);
        ln_kernel<<<g_ln, blk, 0, stream>>>(X, ln2_s + l * 256, ln2_b + l * 256, normed);
        mfma_gemm<2, 128><<<g_ff, blk, 0, stream>>>(
            normed, w1_t + (size_t)l * D_FFC * 256, b1 + l * D_FFC,
            nullptr, h1, D_FFC, 256);
        mfma_gemm<1, 64><<<g_d, blk, 0, stream>>>(
            h1, w2_t + (size_t)l * 256 * D_FFC, b2 + l * 256, X, X, 256, D_FFC);
    }
}

// Round 9
// 816.330 us; speedup vs baseline: 1.1843x; 1.0282x over previous
//
#include <hip/hip_runtime.h>
#include <math.h>

#define D_MODELC 256
#define N_LAYERSC 6
#define N_HEADSC 8
#define D_FFC 1024
#define HEAD_DIMC 32
#define B_SZ 4
#define T_SEQ 2048
#define M_ROWS 8192
#define QKV_N 768

typedef short bf16x8 __attribute__((ext_vector_type(8)));
typedef short bf16x4 __attribute__((ext_vector_type(4)));
typedef float f32x4  __attribute__((ext_vector_type(4)));
typedef unsigned u32x4 __attribute__((ext_vector_type(4)));
typedef unsigned short u16;

// scale(1/sqrt(32)) * log2(e) folded into wq at conversion time
#define QSCALE 0.25503488f

__device__ __forceinline__ u16 f2bf(float x) {
    unsigned u = __builtin_bit_cast(unsigned, x);
    u += 0x7FFF + ((u >> 16) & 1);          // round-to-nearest-even
    return (u16)(u >> 16);
}

__device__ __forceinline__ float bf2f(short x) {
    return __builtin_bit_cast(float, (unsigned)((u16)x) << 16);
}

__device__ __forceinline__ unsigned pack2bf(float a, float b) {  // truncating
    unsigned ua = __builtin_bit_cast(unsigned, a);
    unsigned ub = __builtin_bit_cast(unsigned, b);
    return (ua >> 16) | (ub & 0xFFFF0000u);
}

__device__ __forceinline__ void async_lds16(const void* g, void* l) {
    __builtin_amdgcn_global_load_lds(
        (const __attribute__((address_space(1))) unsigned int*)g,
        (__attribute__((address_space(3))) unsigned int*)l, 16, 0, 0);
}

// ---------------------------------------------------------------------------
// Weight transpose+convert: dst[n][k] = bf16(src[k][n] * scale), per layer z.
// ---------------------------------------------------------------------------
__global__ __launch_bounds__(256) void transpose_w(
    const float* __restrict__ src, u16* __restrict__ dst,
    int K, int N, int srcLS, int dstLS, float scale)
{
    __shared__ float t[32][33];
    src += (size_t)blockIdx.z * srcLS;
    dst += (size_t)blockIdx.z * dstLS;
    const int k0 = blockIdx.y * 32, n0 = blockIdx.x * 32;
    const int r = threadIdx.x >> 3, c4 = (threadIdx.x & 7) * 4;
    const float4 v = *(const float4*)(src + (size_t)(k0 + r) * N + n0 + c4);
    t[r][c4 + 0] = v.x; t[r][c4 + 1] = v.y;
    t[r][c4 + 2] = v.z; t[r][c4 + 3] = v.w;
    __syncthreads();
    bf16x4 o;
#pragma unroll
    for (int i = 0; i < 4; i++) o[i] = (short)f2bf(t[c4 + i][r] * scale);
    *(bf16x4*)(dst + (size_t)(n0 + r) * K + k0 + c4) = o;
}

// Fused QKV bias: [l][768] = [ bq*QSCALE | bk | bv ]
__global__ __launch_bounds__(256) void pack_bias(
    const float* __restrict__ bq, const float* __restrict__ bk,
    const float* __restrict__ bv, float* __restrict__ dst)
{
    int i = blockIdx.x * 256 + threadIdx.x;
    if (i >= N_LAYERSC * QKV_N) return;
    int l = i / QKV_N, j = i % QKV_N;
    float v;
    if (j < 256)      v = bq[l * 256 + j] * QSCALE;
    else if (j < 512) v = bk[l * 256 + j - 256];
    else              v = bv[l * 256 + j - 512];
    dst[i] = v;
}

// ---------------------------------------------------------------------------
// LayerNorm (standalone; used only for layer 0's ln1).
// ---------------------------------------------------------------------------
__global__ __launch_bounds__(256) void ln_kernel(
    const float* __restrict__ X, const float* __restrict__ gamma,
    const float* __restrict__ beta, u16* __restrict__ Y)
{
    const int w = threadIdx.x >> 6, lane = threadIdx.x & 63;
    const int row = blockIdx.x * 4 + w;
    const float4 v = *(const float4*)(X + (size_t)row * 256 + lane * 4);
    float sum = v.x + v.y + v.z + v.w;
    float sq  = v.x * v.x + v.y * v.y + v.z * v.z + v.w * v.w;
#pragma unroll
    for (int off = 32; off > 0; off >>= 1) {
        sum += __shfl_xor(sum, off, 64);
        sq  += __shfl_xor(sq,  off, 64);
    }
    float mu  = sum * (1.0f / 256.0f);
    float var = sq * (1.0f / 256.0f) - mu * mu;
    float rr  = rsqrtf(var + 1e-5f);
    const float4 g  = *(const float4*)(gamma + lane * 4);
    const float4 bb = *(const float4*)(beta + lane * 4);
    bf16x4 o;
    o[0] = (short)f2bf((v.x - mu) * rr * g.x + bb.x);
    o[1] = (short)f2bf((v.y - mu) * rr * g.y + bb.y);
    o[2] = (short)f2bf((v.z - mu) * rr * g.z + bb.z);
    o[3] = (short)f2bf((v.w - mu) * rr * g.w + bb.w);
    *(bf16x4*)(Y + (size_t)row * 256 + lane * 4) = o;
}

// ---------------------------------------------------------------------------
// MFMA GEMM (m97 structure), 128x128 tile, BK=64, async width-16 staging.
// EPI: 0 = bf16 out (+bias); 2 = bf16 gelu(+bias);
//      3 = qkv mode: col<512 -> bf16 to Cout (ld=768); col>=512 -> V written
//          TRANSPOSED to Vout[dim][token] (bf16x4 = 4 consecutive tokens).
// ---------------------------------------------------------------------------
template <int EPI>
__global__ __launch_bounds__(256) void mfma_gemm(
    const u16* __restrict__ A, const u16* __restrict__ Bt,
    const float* __restrict__ bias, u16* __restrict__ Vout,
    void* __restrict__ Cout, int N, int K)
{
    __shared__ u16 As[128 * 64];
    __shared__ u16 Bs[128 * 64];
    const int tid = threadIdx.x, w = tid >> 6, lane = tid & 63;
    const int c = lane & 15, quad = lane >> 4;
    const int row0 = blockIdx.y * 128, col0 = blockIdx.x * 128;
    const int wr = w >> 1, wc = w & 1;

    f32x4 acc[4][4] = {};

    for (int k0 = 0; k0 < K; k0 += 64) {
        __syncthreads();
#pragma unroll
        for (int ci = 0; ci < 4; ci++) {
            const int fb = (w * 4 + ci) * 1024;
            const int fl = fb + lane * 16;
            const int r = fl >> 7, col = (fl & 127) >> 1;
            async_lds16(A  + (size_t)(row0 + r) * K + k0 + col, (char*)As + fb);
            async_lds16(Bt + (size_t)(col0 + r) * K + k0 + col, (char*)Bs + fb);
        }
        __syncthreads();
#pragma unroll
        for (int kk = 0; kk < 2; kk++) {
            bf16x8 af[4], bfv[4];
#pragma unroll
            for (int i = 0; i < 4; i++)
                af[i] = *(const bf16x8*)&As[(wr * 64 + i * 16 + c) * 64 + kk * 32 + quad * 8];
#pragma unroll
            for (int j = 0; j < 4; j++)
                bfv[j] = *(const bf16x8*)&Bs[(wc * 64 + j * 16 + c) * 64 + kk * 32 + quad * 8];
#pragma unroll
            for (int i = 0; i < 4; i++)
#pragma unroll
                for (int j = 0; j < 4; j++)
                    acc[i][j] = __builtin_amdgcn_mfma_f32_16x16x32_bf16(
                        af[i], bfv[j], acc[i][j], 0, 0, 0);
        }
    }

    float bj[4];
#pragma unroll
    for (int j = 0; j < 4; j++) bj[j] = bias[col0 + wc * 64 + j * 16 + c];

    if (EPI == 3 && col0 >= 512) {
        // V third: write transposed. 4 consecutive tokens per 8B store.
#pragma unroll
        for (int i = 0; i < 4; i++) {
            const int tok = row0 + wr * 64 + i * 16 + quad * 4;
#pragma unroll
            for (int j = 0; j < 4; j++) {
                const int dim = col0 - 512 + wc * 64 + j * 16 + c;
                bf16x4 o;
#pragma unroll
                for (int r = 0; r < 4; r++) o[r] = (short)f2bf(acc[i][j][r] + bj[j]);
                *(bf16x4*)&Vout[(size_t)dim * M_ROWS + tok] = o;
            }
        }
        return;
    }

#pragma unroll
    for (int i = 0; i < 4; i++) {
#pragma unroll
        for (int r = 0; r < 4; r++) {
            const int gr = row0 + wr * 64 + i * 16 + quad * 4 + r;
#pragma unroll
            for (int j = 0; j < 4; j++) {
                const int gc = col0 + wc * 64 + j * 16 + c;
                float v = acc[i][j][r] + bj[j];
                if (EPI == 2) v = 0.5f * v * (1.0f + erff(v * 0.70710678118654752f));
                ((u16*)Cout)[(size_t)gr * N + gc] = f2bf(v);
            }
        }
    }
}

// ---------------------------------------------------------------------------
// GEMM (N=256, BM=32, BN=256) + residual + optional fused LayerNorm.
// Block owns 32 full rows -> grid 256 = 1 block/CU. Wave w owns cols
// [w*64, w*64+64). Epilogue: x = acc+bias+resid -> X (fp32); if DOLN,
// row mean/var via shfl(16-group) + LDS cross-wave reduce -> Nout (bf16).
// ---------------------------------------------------------------------------
template <int DOLN>
__global__ __launch_bounds__(256) void gemm_ln(
    const u16* __restrict__ A, const u16* __restrict__ Bt,
    const float* __restrict__ bias, const float* __restrict__ resid,
    float* __restrict__ Xout, const float* __restrict__ gamma,
    const float* __restrict__ beta, u16* __restrict__ Nout, int K)
{
    __shared__ u16 As[32 * 64];
    __shared__ u16 Bs[256 * 64];
    __shared__ float2 red[4][32];                 // per-wave {sum,sq} per row
    const int tid = threadIdx.x, w = tid >> 6, lane = tid & 63;
    const int c = lane & 15, quad = lane >> 4;
    const int row0 = blockIdx.x * 32;

    f32x4 acc[2][4] = {};

    for (int k0 = 0; k0 < K; k0 += 64) {
        __syncthreads();
        {   // A: 4 KB = 4 granules, one per wave
            const int fb = w * 1024;
            const int fl = fb + lane * 16;
            const int r = fl >> 7, col = (fl & 127) >> 1;
            async_lds16(A + (size_t)(row0 + r) * K + k0 + col, (char*)As + fb);
        }
#pragma unroll
        for (int ci = 0; ci < 8; ci++) {          // B: 32 KB = 32 granules
            const int fb = (w * 8 + ci) * 1024;
            const int fl = fb + lane * 16;
            const int r = fl >> 7, col = (fl & 127) >> 1;
            async_lds16(Bt + (size_t)r * K + k0 + col, (char*)Bs + fb);
        }
        __syncthreads();
#pragma unroll
        for (int kk = 0; kk < 2; kk++) {
            bf16x8 af[2], bfv[4];
#pragma unroll
            for (int i = 0; i < 2; i++)
                af[i] = *(const bf16x8*)&As[(i * 16 + c) * 64 + kk * 32 + quad * 8];
#pragma unroll
            for (int j = 0; j < 4; j++)
                bfv[j] = *(const bf16x8*)&Bs[(w * 64 + j * 16 + c) * 64 + kk * 32 + quad * 8];
#pragma unroll
            for (int i = 0; i < 2; i++)
#pragma unroll
                for (int j = 0; j < 4; j++)
                    acc[i][j] = __builtin_amdgcn_mfma_f32_16x16x32_bf16(
                        af[i], bfv[j], acc[i][j], 0, 0, 0);
        }
    }

    // x = acc + bias + resid
    float bj[4];
#pragma unroll
    for (int j = 0; j < 4; j++) bj[j] = bias[w * 64 + j * 16 + c];
    float xv[2][4][4];
#pragma unroll
    for (int i = 0; i < 2; i++)
#pragma unroll
        for (int r = 0; r < 4; r++) {
            const int gr = row0 + i * 16 + quad * 4 + r;
#pragma unroll
            for (int j = 0; j < 4; j++) {
                const int gc = w * 64 + j * 16 + c;
                xv[i][j][r] = acc[i][j][r] + bj[j] + resid[(size_t)gr * 256 + gc];
            }
        }

    if (DOLN) {
        // per-row partial sums over this lane's 4 cols, reduce over 16-lane c-group
        float sm[2][4], sp[2][4];
#pragma unroll
        for (int i = 0; i < 2; i++)
#pragma unroll
            for (int r = 0; r < 4; r++) {
                float s = 0.f, q = 0.f;
#pragma unroll
                for (int j = 0; j < 4; j++) { s += xv[i][j][r]; q += xv[i][j][r] * xv[i][j][r]; }
                sm[i][r] = s; sp[i][r] = q;
            }
#pragma unroll
        for (int off = 1; off < 16; off <<= 1)
#pragma unroll
            for (int i = 0; i < 2; i++)
#pragma unroll
                for (int r = 0; r < 4; r++) {
                    sm[i][r] += __shfl_xor(sm[i][r], off, 64);
                    sp[i][r] += __shfl_xor(sp[i][r], off, 64);
                }
        __syncthreads();                          // As/Bs done; red reuse safe
        if (c == 0) {
#pragma unroll
            for (int i = 0; i < 2; i++)
#pragma unroll
                for (int r = 0; r < 4; r++)
                    red[w][i * 16 + quad * 4 + r] = make_float2(sm[i][r], sp[i][r]);
        }
        __syncthreads();
#pragma unroll
        for (int i = 0; i < 2; i++)
#pragma unroll
            for (int r = 0; r < 4; r++) {
                const int row = i * 16 + quad * 4 + r;
                float2 t0 = red[0][row], t1 = red[1][row];
                float2 t2 = red[2][row], t3 = red[3][row];
                float S = (t0.x + t1.x) + (t2.x + t3.x);
                float Q = (t0.y + t1.y) + (t2.y + t3.y);
                float mu = S * (1.0f / 256.0f);
                float var = Q * (1.0f / 256.0f) - mu * mu;
                float rr = rsqrtf(var + 1e-5f);
                const int gr = row0 + row;
#pragma unroll
                for (int j = 0; j < 4; j++) {
                    const int gc = w * 64 + j * 16 + c;
                    float x = xv[i][j][r];
                    Xout[(size_t)gr * 256 + gc] = x;
                    Nout[(size_t)gr * 256 + gc] =
                        f2bf((x - mu) * rr * gamma[gc] + beta[gc]);
                }
            }
    } else {
#pragma unroll
        for (int i = 0; i < 2; i++)
#pragma unroll
            for (int r = 0; r < 4; r++) {
                const int gr = row0 + i * 16 + quad * 4 + r;
#pragma unroll
                for (int j = 0; j < 4; j++)
                    Xout[(size_t)gr * 256 + w * 64 + j * 16 + c] = xv[i][j][r];
            }
    }
}

// ---------------------------------------------------------------------------
// MFMA flash attention v4 (unchanged from round 8): register-prefetch dbuf,
// key-split x2, additive partials (p = 2^S).
// ---------------------------------------------------------------------------
__global__ __launch_bounds__(256) void attn_kernel(
    const u16* __restrict__ QKV, const u16* __restrict__ VT,
    u16* __restrict__ POa, u16* __restrict__ POb, float* __restrict__ Lp)
{
    const int h = blockIdx.y, b = blockIdx.z;
    const int half = blockIdx.x & 1;
    const int q0 = (blockIdx.x >> 1) * 128;
    const int tid = threadIdx.x, w = tid >> 6, lane = tid & 63;
    const int c = lane & 15, quad = lane >> 4;

    __shared__ u16 Kf[2048];
    __shared__ u16 Vf[2048];

    const u16* qp = QKV + (size_t)(b * T_SEQ + q0 + w * 32 + c) * QKV_N + h * 32 + quad * 8;
    bf16x8 aQ0 = *(const bf16x8*)qp;
    bf16x8 aQ1 = *(const bf16x8*)(qp + 16 * QKV_N);

    float l0 = 0.f, l1 = 0.f;
    f32x4 O[2][2] = {};

    const u16* kgp = QKV + (size_t)(b * T_SEQ + w * 16 + c) * QKV_N + 256 + h * 32 + quad * 8;
    const u16* vgp = VT + ((size_t)h * 32 + (lane & 31)) * M_ROWS + b * T_SEQ
                     + (w * 2 + (lane >> 5)) * 8;
    u16* kfw = Kf + w * 512 + lane * 8;
    u16* vfw = Vf + w * 512 + lane * 8;
    const int LA = (quad & 1) * 32 + c, LB = LA + 16;
    const bool gsel = quad < 2;

    const int kbeg = half * (T_SEQ / 2);
    const int kend = kbeg + T_SEQ / 2;

    bf16x8 gK = *(const bf16x8*)(kgp + (size_t)kbeg * QKV_N);
    bf16x8 gV = *(const bf16x8*)(vgp + kbeg);

    for (int k0 = kbeg; k0 < kend; k0 += 64) {
        __syncthreads();
        *(bf16x8*)kfw = gK;
        *(bf16x8*)vfw = gV;
        if (k0 + 64 < kend) {
            gK = *(const bf16x8*)(kgp + (size_t)(k0 + 64) * QKV_N);
            gV = *(const bf16x8*)(vgp + (k0 + 64));
        }
        __syncthreads();

        unsigned pk[4][2][2];
#pragma unroll
        for (int g = 0; g < 4; g++) {
            bf16x8 aK = *(const bf16x8*)&Kf[g * 512 + lane * 8];
            f32x4 S0 = __builtin_amdgcn_mfma_f32_16x16x32_bf16(
                aK, aQ0, (f32x4){0.f, 0.f, 0.f, 0.f}, 0, 0, 0);
            f32x4 S1 = __builtin_amdgcn_mfma_f32_16x16x32_bf16(
                aK, aQ1, (f32x4){0.f, 0.f, 0.f, 0.f}, 0, 0, 0);
            float p0 = exp2f(S0[0]), p1 = exp2f(S0[1]);
            float p2 = exp2f(S0[2]), p3 = exp2f(S0[3]);
            l0 += (p0 + p1) + (p2 + p3);
            pk[g][0][0] = pack2bf(p0, p1);
            pk[g][0][1] = pack2bf(p2, p3);
            p0 = exp2f(S1[0]); p1 = exp2f(S1[1]);
            p2 = exp2f(S1[2]); p3 = exp2f(S1[3]);
            l1 += (p0 + p1) + (p2 + p3);
            pk[g][1][0] = pack2bf(p0, p1);
            pk[g][1][1] = pack2bf(p2, p3);
        }

#pragma unroll
        for (int kh = 0; kh < 2; kh++) {
            bf16x8 bV0 = *(const bf16x8*)&Vf[((kh * 4 + quad) * 32 + c) * 8];
            bf16x8 bV1 = *(const bf16x8*)&Vf[((kh * 4 + quad) * 32 + 16 + c) * 8];
#pragma unroll
            for (int qg = 0; qg < 2; qg++) {
                int e00 = __shfl((int)pk[2 * kh][qg][0],     LA, 64);
                int e01 = __shfl((int)pk[2 * kh + 1][qg][0], LA, 64);
                int e10 = __shfl((int)pk[2 * kh][qg][1],     LA, 64);
                int e11 = __shfl((int)pk[2 * kh + 1][qg][1], LA, 64);
                int e20 = __shfl((int)pk[2 * kh][qg][0],     LB, 64);
                int e21 = __shfl((int)pk[2 * kh + 1][qg][0], LB, 64);
                int e30 = __shfl((int)pk[2 * kh][qg][1],     LB, 64);
                int e31 = __shfl((int)pk[2 * kh + 1][qg][1], LB, 64);
                u32x4 ap;
                ap[0] = (unsigned)(gsel ? e00 : e01);
                ap[1] = (unsigned)(gsel ? e10 : e11);
                ap[2] = (unsigned)(gsel ? e20 : e21);
                ap[3] = (unsigned)(gsel ? e30 : e31);
                bf16x8 aP = __builtin_bit_cast(bf16x8, ap);
                O[qg][0] = __builtin_amdgcn_mfma_f32_16x16x32_bf16(aP, bV0, O[qg][0], 0, 0, 0);
                O[qg][1] = __builtin_amdgcn_mfma_f32_16x16x32_bf16(aP, bV1, O[qg][1], 0, 0, 0);
            }
        }
    }

    l0 += __shfl_xor(l0, 16, 64); l0 += __shfl_xor(l0, 32, 64);
    l1 += __shfl_xor(l1, 16, 64); l1 += __shfl_xor(l1, 32, 64);

    u16* pb = (half ? POb : POa)
              + (size_t)(b * T_SEQ + q0 + w * 32) * 256 + h * 32;
    if (quad == 0) {
        float* lb = Lp + (size_t)half * M_ROWS * 8
                    + (size_t)(b * T_SEQ + q0 + w * 32) * 8 + h;
        lb[(size_t)c * 8]        = l0;
        lb[(size_t)(16 + c) * 8] = l1;
    }
#pragma unroll
    for (int r = 0; r < 4; r++) {
        int src = quad * 4 + r;
        pb[(size_t)src * 256 + c]             = f2bf(O[0][0][r]);
        pb[(size_t)src * 256 + 16 + c]        = f2bf(O[0][1][r]);
        pb[(size_t)(16 + src) * 256 + c]      = f2bf(O[1][0][r]);
        pb[(size_t)(16 + src) * 256 + 16 + c] = f2bf(O[1][1][r]);
    }
}

// ---------------------------------------------------------------------------
// Merge the two key-halves: Ob = (POa + POb) / (la + lb). Wave per row.
// ---------------------------------------------------------------------------
__global__ __launch_bounds__(256) void attn_merge(
    const u16* __restrict__ POa, const u16* __restrict__ POb,
    const float* __restrict__ Lp, u16* __restrict__ Ob)
{
    const int w = threadIdx.x >> 6, lane = threadIdx.x & 63;
    const int row = blockIdx.x * 4 + w;
    const int head = lane >> 3;
    const float la = Lp[(size_t)row * 8 + head];
    const float lb = Lp[(size_t)M_ROWS * 8 + (size_t)row * 8 + head];
    const float inv = 1.0f / (la + lb);
    bf16x4 a = *(const bf16x4*)&POa[(size_t)row * 256 + lane * 4];
    bf16x4 b = *(const bf16x4*)&POb[(size_t)row * 256 + lane * 4];
    bf16x4 o;
#pragma unroll
    for (int i = 0; i < 4; i++) o[i] = (short)f2bf((bf2f(a[i]) + bf2f(b[i])) * inv);
    *(bf16x4*)&Ob[(size_t)row * 256 + lane * 4] = o;
}

// ---------------------------------------------------------------------------
extern "C" void kernel_launch(void* const* d_in, const int* in_sizes, int n_in,
                              void* d_out, int out_size, void* d_ws, size_t ws_size,
                              hipStream_t stream)
{
    const float* x     = (const float*)d_in[0];
    const float* ln1_s = (const float*)d_in[1];
    const float* ln1_b = (const float*)d_in[2];
    const float* wq    = (const float*)d_in[3];
    const float* bq    = (const float*)d_in[4];
    const float* wk    = (const float*)d_in[5];
    const float* bk    = (const float*)d_in[6];
    const float* wv    = (const float*)d_in[7];
    const float* bv    = (const float*)d_in[8];
    const float* wo    = (const float*)d_in[9];
    const float* bo    = (const float*)d_in[10];
    const float* ln2_s = (const float*)d_in[11];
    const float* ln2_b = (const float*)d_in[12];
    const float* w1    = (const float*)d_in[13];
    const float* b1    = (const float*)d_in[14];
    const float* w2    = (const float*)d_in[15];
    const float* b2    = (const float*)d_in[16];

    float* X = (float*)d_out;                   // fp32 residual stream

    // Workspace (u16 elems). Liveness: normed = ln1-out -> (qkv reads) ->
    // merge-out -> (wo reads) -> ln1-next (ffn2 epi). VTb = V^T -> (attn
    // reads) -> ln2-out (wo epi) -> (ffn1 reads). h1 = qkv|POa span, only
    // live ffn1->ffn2 when both dead. POa/POb/Lp: attn -> merge only.
    u16* normed = (u16*)d_ws;                               // 8192*256
    u16* qkv    = normed + (size_t)M_ROWS * 256;            // 8192*768 (V third unused)
    u16* POa    = qkv + (size_t)M_ROWS * QKV_N;             // 8192*256
    u16* h1     = qkv;   // spans qkv+POa: 8192*1024
    u16* wqkv_t = POa + (size_t)M_ROWS * 256;               // 6*768*256
    u16* wo_t   = wqkv_t + (size_t)N_LAYERSC * QKV_N * 256; // 6*256*256
    u16* w1_t   = wo_t + (size_t)N_LAYERSC * 256 * 256;     // 6*1024*256
    u16* w2_t   = w1_t + (size_t)N_LAYERSC * D_FFC * 256;   // 6*256*1024
    float* qkvb = (float*)(w2_t + (size_t)N_LAYERSC * 256 * D_FFC); // 6*768 fp32
    u16* VTb    = (u16*)(qkvb + N_LAYERSC * QKV_N);         // 256*8192
    u16* POb    = VTb + (size_t)256 * M_ROWS;               // 8192*256
    float* Lp   = (float*)(POb + (size_t)M_ROWS * 256);     // 2*8192*8 fp32

    dim3 blk(256);

    // ---- weight prep (every call; graph-safe)
    transpose_w<<<dim3(8, 8, 6),  blk, 0, stream>>>(wq, wqkv_t,             256, 256, 65536, QKV_N * 256, QSCALE);
    transpose_w<<<dim3(8, 8, 6),  blk, 0, stream>>>(wk, wqkv_t + 256 * 256, 256, 256, 65536, QKV_N * 256, 1.0f);
    transpose_w<<<dim3(8, 8, 6),  blk, 0, stream>>>(wv, wqkv_t + 512 * 256, 256, 256, 65536, QKV_N * 256, 1.0f);
    transpose_w<<<dim3(8, 8, 6),  blk, 0, stream>>>(wo, wo_t,               256, 256, 65536, 65536, 1.0f);
    transpose_w<<<dim3(32, 8, 6), blk, 0, stream>>>(w1, w1_t,               256, D_FFC, 256 * D_FFC, 256 * D_FFC, 1.0f);
    transpose_w<<<dim3(8, 32, 6), blk, 0, stream>>>(w2, w2_t,               D_FFC, 256, 256 * D_FFC, 256 * D_FFC, 1.0f);
    pack_bias<<<dim3(18), blk, 0, stream>>>(bq, bk, bv, qkvb);

    hipMemcpyAsync(X, x, (size_t)M_ROWS * 256 * sizeof(float),
                   hipMemcpyDeviceToDevice, stream);

    dim3 g_qkv(QKV_N / 128, M_ROWS / 128);          // (6,64)
    dim3 g_ff(D_FFC / 128, M_ROWS / 128);           // (8,64)
    dim3 g_ln32(M_ROWS / 32);                       // 256 blocks
    dim3 g_attn(2 * T_SEQ / 128, N_HEADSC, B_SZ);   // 1024 blocks
    dim3 g_mrg(M_ROWS / 4);

    ln_kernel<<<dim3(M_ROWS / 4), blk, 0, stream>>>(X, ln1_s, ln1_b, normed);

    for (int l = 0; l < N_LAYERSC; l++) {
        // QKV (+ fused V transpose into VTb)
        mfma_gemm<3><<<g_qkv, blk, 0, stream>>>(
            normed, wqkv_t + (size_t)l * QKV_N * 256, qkvb + l * QKV_N,
            VTb, qkv, QKV_N, 256);
        attn_kernel<<<g_attn, blk, 0, stream>>>(qkv, VTb, POa, POb, Lp);
        attn_merge<<<g_mrg, blk, 0, stream>>>(POa, POb, Lp, normed);
        // Wo + residual + fused ln2 -> X, VTb
        gemm_ln<1><<<g_ln32, blk, 0, stream>>>(
            normed, wo_t + (size_t)l * 256 * 256, bo + l * 256, X,
            X, ln2_s + l * 256, ln2_b + l * 256, VTb, 256);
        // FFN1 (gelu) : VTb -> h1
        mfma_gemm<2><<<g_ff, blk, 0, stream>>>(
            VTb, w1_t + (size_t)l * D_FFC * 256, b1 + l * D_FFC,
            nullptr, h1, D_FFC, 256);
        // FFN2 + residual + fused ln1[l+1] -> X, normed
        if (l + 1 < N_LAYERSC) {
            gemm_ln<1><<<g_ln32, blk, 0, stream>>>(
                h1, w2_t + (size_t)l * 256 * D_FFC, b2 + l * 256, X,
                X, ln1_s + (l + 1) * 256, ln1_b + (l + 1) * 256, normed, D_FFC);
        } else {
            gemm_ln<0><<<g_ln32, blk, 0, stream>>>(
                h1, w2_t + (size_t)l * 256 * D_FFC, b2 + l * 256, X,
                X, nullptr, nullptr, nullptr, D_FFC);
        }
    }
}

// Round 10
// 767.519 us; speedup vs baseline: 1.2596x; 1.0636x over previous
//
#include <hip/hip_runtime.h>
#include <math.h>

#define D_MODELC 256
#define N_LAYERSC 6
#define N_HEADSC 8
#define D_FFC 1024
#define HEAD_DIMC 32
#define B_SZ 4
#define T_SEQ 2048
#define M_ROWS 8192
#define QKV_N 768

typedef short bf16x8 __attribute__((ext_vector_type(8)));
typedef short bf16x4 __attribute__((ext_vector_type(4)));
typedef float f32x4  __attribute__((ext_vector_type(4)));
typedef unsigned u32x4 __attribute__((ext_vector_type(4)));
typedef unsigned short u16;

// scale(1/sqrt(32)) * log2(e) folded into wq at conversion time
#define QSCALE 0.25503488f

__device__ __forceinline__ u16 f2bf(float x) {
    unsigned u = __builtin_bit_cast(unsigned, x);
    u += 0x7FFF + ((u >> 16) & 1);          // round-to-nearest-even
    return (u16)(u >> 16);
}

__device__ __forceinline__ float bf2f(short x) {
    return __builtin_bit_cast(float, (unsigned)((u16)x) << 16);
}

__device__ __forceinline__ unsigned pack2bf(float a, float b) {  // truncating
    unsigned ua = __builtin_bit_cast(unsigned, a);
    unsigned ub = __builtin_bit_cast(unsigned, b);
    return (ua >> 16) | (ub & 0xFFFF0000u);
}

__device__ __forceinline__ void async_lds16(const void* g, void* l) {
    __builtin_amdgcn_global_load_lds(
        (const __attribute__((address_space(1))) unsigned int*)g,
        (__attribute__((address_space(3))) unsigned int*)l, 16, 0, 0);
}

// A&S 7.1.26 erf (|err|<=1.5e-7), one v_exp + one v_rcp; exact-gelu drop-in.
__device__ __forceinline__ float fast_gelu(float x) {
    float y  = x * 0.70710678118654752f;
    float ay = __builtin_fabsf(y);
    float t  = __builtin_amdgcn_rcpf(1.0f + 0.3275911f * ay);
    float p  = t * (0.254829592f + t * (-0.284496736f + t * (1.421413741f
               + t * (-1.453152027f + t * 1.061405429f))));
    float e  = __builtin_amdgcn_exp2f(-ay * ay * 1.4426950408889634f);
    float er = 1.0f - p * e;
    er = y < 0.0f ? -er : er;
    return 0.5f * x * (1.0f + er);
}

// ---------------------------------------------------------------------------
// Weight transpose+convert: dst[n][k] = bf16(src[k][n] * scale), per layer z.
// ---------------------------------------------------------------------------
__global__ __launch_bounds__(256) void transpose_w(
    const float* __restrict__ src, u16* __restrict__ dst,
    int K, int N, int srcLS, int dstLS, float scale)
{
    __shared__ float t[32][33];
    src += (size_t)blockIdx.z * srcLS;
    dst += (size_t)blockIdx.z * dstLS;
    const int k0 = blockIdx.y * 32, n0 = blockIdx.x * 32;
    const int r = threadIdx.x >> 3, c4 = (threadIdx.x & 7) * 4;
    const float4 v = *(const float4*)(src + (size_t)(k0 + r) * N + n0 + c4);
    t[r][c4 + 0] = v.x; t[r][c4 + 1] = v.y;
    t[r][c4 + 2] = v.z; t[r][c4 + 3] = v.w;
    __syncthreads();
    bf16x4 o;
#pragma unroll
    for (int i = 0; i < 4; i++) o[i] = (short)f2bf(t[c4 + i][r] * scale);
    *(bf16x4*)(dst + (size_t)(n0 + r) * K + k0 + c4) = o;
}

// Fused QKV bias: [l][768] = [ bq*QSCALE | bk | bv ]
__global__ __launch_bounds__(256) void pack_bias(
    const float* __restrict__ bq, const float* __restrict__ bk,
    const float* __restrict__ bv, float* __restrict__ dst)
{
    int i = blockIdx.x * 256 + threadIdx.x;
    if (i >= N_LAYERSC * QKV_N) return;
    int l = i / QKV_N, j = i % QKV_N;
    float v;
    if (j < 256)      v = bq[l * 256 + j] * QSCALE;
    else if (j < 512) v = bk[l * 256 + j - 256];
    else              v = bv[l * 256 + j - 512];
    dst[i] = v;
}

// ---------------------------------------------------------------------------
// LayerNorm (standalone; used only for layer 0's ln1).
// ---------------------------------------------------------------------------
__global__ __launch_bounds__(256) void ln_kernel(
    const float* __restrict__ X, const float* __restrict__ gamma,
    const float* __restrict__ beta, u16* __restrict__ Y)
{
    const int w = threadIdx.x >> 6, lane = threadIdx.x & 63;
    const int row = blockIdx.x * 4 + w;
    const float4 v = *(const float4*)(X + (size_t)row * 256 + lane * 4);
    float sum = v.x + v.y + v.z + v.w;
    float sq  = v.x * v.x + v.y * v.y + v.z * v.z + v.w * v.w;
#pragma unroll
    for (int off = 32; off > 0; off >>= 1) {
        sum += __shfl_xor(sum, off, 64);
        sq  += __shfl_xor(sq,  off, 64);
    }
    float mu  = sum * (1.0f / 256.0f);
    float var = sq * (1.0f / 256.0f) - mu * mu;
    float rr  = rsqrtf(var + 1e-5f);
    const float4 g  = *(const float4*)(gamma + lane * 4);
    const float4 bb = *(const float4*)(beta + lane * 4);
    bf16x4 o;
    o[0] = (short)f2bf((v.x - mu) * rr * g.x + bb.x);
    o[1] = (short)f2bf((v.y - mu) * rr * g.y + bb.y);
    o[2] = (short)f2bf((v.z - mu) * rr * g.z + bb.z);
    o[3] = (short)f2bf((v.w - mu) * rr * g.w + bb.w);
    *(bf16x4*)(Y + (size_t)row * 256 + lane * 4) = o;
}

// ---------------------------------------------------------------------------
// MFMA GEMM (m97 structure), 128x128 tile, BK=64, async width-16 staging.
// EPI: 0 = bf16 out (+bias); 2 = bf16 gelu(+bias);
//      3 = qkv mode: col<512 -> bf16 to Cout (ld=768); col>=512 -> V written
//          TRANSPOSED to Vout[dim][token] (bf16x4 = 4 consecutive tokens).
// ---------------------------------------------------------------------------
template <int EPI>
__global__ __launch_bounds__(256) void mfma_gemm(
    const u16* __restrict__ A, const u16* __restrict__ Bt,
    const float* __restrict__ bias, u16* __restrict__ Vout,
    void* __restrict__ Cout, int N, int K)
{
    __shared__ u16 As[128 * 64];
    __shared__ u16 Bs[128 * 64];
    const int tid = threadIdx.x, w = tid >> 6, lane = tid & 63;
    const int c = lane & 15, quad = lane >> 4;
    const int row0 = blockIdx.y * 128, col0 = blockIdx.x * 128;
    const int wr = w >> 1, wc = w & 1;

    f32x4 acc[4][4] = {};

    for (int k0 = 0; k0 < K; k0 += 64) {
        __syncthreads();
#pragma unroll
        for (int ci = 0; ci < 4; ci++) {
            const int fb = (w * 4 + ci) * 1024;
            const int fl = fb + lane * 16;
            const int r = fl >> 7, col = (fl & 127) >> 1;
            async_lds16(A  + (size_t)(row0 + r) * K + k0 + col, (char*)As + fb);
            async_lds16(Bt + (size_t)(col0 + r) * K + k0 + col, (char*)Bs + fb);
        }
        __syncthreads();
#pragma unroll
        for (int kk = 0; kk < 2; kk++) {
            bf16x8 af[4], bfv[4];
#pragma unroll
            for (int i = 0; i < 4; i++)
                af[i] = *(const bf16x8*)&As[(wr * 64 + i * 16 + c) * 64 + kk * 32 + quad * 8];
#pragma unroll
            for (int j = 0; j < 4; j++)
                bfv[j] = *(const bf16x8*)&Bs[(wc * 64 + j * 16 + c) * 64 + kk * 32 + quad * 8];
#pragma unroll
            for (int i = 0; i < 4; i++)
#pragma unroll
                for (int j = 0; j < 4; j++)
                    acc[i][j] = __builtin_amdgcn_mfma_f32_16x16x32_bf16(
                        af[i], bfv[j], acc[i][j], 0, 0, 0);
        }
    }

    float bj[4];
#pragma unroll
    for (int j = 0; j < 4; j++) bj[j] = bias[col0 + wc * 64 + j * 16 + c];

    if (EPI == 3 && col0 >= 512) {
        // V third: write transposed. 4 consecutive tokens per 8B store.
#pragma unroll
        for (int i = 0; i < 4; i++) {
            const int tok = row0 + wr * 64 + i * 16 + quad * 4;
#pragma unroll
            for (int j = 0; j < 4; j++) {
                const int dim = col0 - 512 + wc * 64 + j * 16 + c;
                bf16x4 o;
#pragma unroll
                for (int r = 0; r < 4; r++) o[r] = (short)f2bf(acc[i][j][r] + bj[j]);
                *(bf16x4*)&Vout[(size_t)dim * M_ROWS + tok] = o;
            }
        }
        return;
    }

#pragma unroll
    for (int i = 0; i < 4; i++) {
#pragma unroll
        for (int r = 0; r < 4; r++) {
            const int gr = row0 + wr * 64 + i * 16 + quad * 4 + r;
#pragma unroll
            for (int j = 0; j < 4; j++) {
                const int gc = col0 + wc * 64 + j * 16 + c;
                float v = acc[i][j][r] + bj[j];
                if (EPI == 2) v = fast_gelu(v);
                ((u16*)Cout)[(size_t)gr * N + gc] = f2bf(v);
            }
        }
    }
}

// ---------------------------------------------------------------------------
// GEMM (N=256, BM=32, BN=256) + residual + optional fused LayerNorm.
// ---------------------------------------------------------------------------
template <int DOLN>
__global__ __launch_bounds__(256) void gemm_ln(
    const u16* __restrict__ A, const u16* __restrict__ Bt,
    const float* __restrict__ bias, const float* __restrict__ resid,
    float* __restrict__ Xout, const float* __restrict__ gamma,
    const float* __restrict__ beta, u16* __restrict__ Nout, int K)
{
    __shared__ u16 As[32 * 64];
    __shared__ u16 Bs[256 * 64];
    __shared__ float2 red[4][32];                 // per-wave {sum,sq} per row
    const int tid = threadIdx.x, w = tid >> 6, lane = tid & 63;
    const int c = lane & 15, quad = lane >> 4;
    const int row0 = blockIdx.x * 32;

    f32x4 acc[2][4] = {};

    for (int k0 = 0; k0 < K; k0 += 64) {
        __syncthreads();
        {   // A: 4 KB = 4 granules, one per wave
            const int fb = w * 1024;
            const int fl = fb + lane * 16;
            const int r = fl >> 7, col = (fl & 127) >> 1;
            async_lds16(A + (size_t)(row0 + r) * K + k0 + col, (char*)As + fb);
        }
#pragma unroll
        for (int ci = 0; ci < 8; ci++) {          // B: 32 KB = 32 granules
            const int fb = (w * 8 + ci) * 1024;
            const int fl = fb + lane * 16;
            const int r = fl >> 7, col = (fl & 127) >> 1;
            async_lds16(Bt + (size_t)r * K + k0 + col, (char*)Bs + fb);
        }
        __syncthreads();
#pragma unroll
        for (int kk = 0; kk < 2; kk++) {
            bf16x8 af[2], bfv[4];
#pragma unroll
            for (int i = 0; i < 2; i++)
                af[i] = *(const bf16x8*)&As[(i * 16 + c) * 64 + kk * 32 + quad * 8];
#pragma unroll
            for (int j = 0; j < 4; j++)
                bfv[j] = *(const bf16x8*)&Bs[(w * 64 + j * 16 + c) * 64 + kk * 32 + quad * 8];
#pragma unroll
            for (int i = 0; i < 2; i++)
#pragma unroll
                for (int j = 0; j < 4; j++)
                    acc[i][j] = __builtin_amdgcn_mfma_f32_16x16x32_bf16(
                        af[i], bfv[j], acc[i][j], 0, 0, 0);
        }
    }

    // x = acc + bias + resid
    float bj[4];
#pragma unroll
    for (int j = 0; j < 4; j++) bj[j] = bias[w * 64 + j * 16 + c];
    float xv[2][4][4];
#pragma unroll
    for (int i = 0; i < 2; i++)
#pragma unroll
        for (int r = 0; r < 4; r++) {
            const int gr = row0 + i * 16 + quad * 4 + r;
#pragma unroll
            for (int j = 0; j < 4; j++) {
                const int gc = w * 64 + j * 16 + c;
                xv[i][j][r] = acc[i][j][r] + bj[j] + resid[(size_t)gr * 256 + gc];
            }
        }

    if (DOLN) {
        float sm[2][4], sp[2][4];
#pragma unroll
        for (int i = 0; i < 2; i++)
#pragma unroll
            for (int r = 0; r < 4; r++) {
                float s = 0.f, q = 0.f;
#pragma unroll
                for (int j = 0; j < 4; j++) { s += xv[i][j][r]; q += xv[i][j][r] * xv[i][j][r]; }
                sm[i][r] = s; sp[i][r] = q;
            }
#pragma unroll
        for (int off = 1; off < 16; off <<= 1)
#pragma unroll
            for (int i = 0; i < 2; i++)
#pragma unroll
                for (int r = 0; r < 4; r++) {
                    sm[i][r] += __shfl_xor(sm[i][r], off, 64);
                    sp[i][r] += __shfl_xor(sp[i][r], off, 64);
                }
        __syncthreads();
        if (c == 0) {
#pragma unroll
            for (int i = 0; i < 2; i++)
#pragma unroll
                for (int r = 0; r < 4; r++)
                    red[w][i * 16 + quad * 4 + r] = make_float2(sm[i][r], sp[i][r]);
        }
        __syncthreads();
#pragma unroll
        for (int i = 0; i < 2; i++)
#pragma unroll
            for (int r = 0; r < 4; r++) {
                const int row = i * 16 + quad * 4 + r;
                float2 t0 = red[0][row], t1 = red[1][row];
                float2 t2 = red[2][row], t3 = red[3][row];
                float S = (t0.x + t1.x) + (t2.x + t3.x);
                float Q = (t0.y + t1.y) + (t2.y + t3.y);
                float mu = S * (1.0f / 256.0f);
                float var = Q * (1.0f / 256.0f) - mu * mu;
                float rr = rsqrtf(var + 1e-5f);
                const int gr = row0 + row;
#pragma unroll
                for (int j = 0; j < 4; j++) {
                    const int gc = w * 64 + j * 16 + c;
                    float x = xv[i][j][r];
                    Xout[(size_t)gr * 256 + gc] = x;
                    Nout[(size_t)gr * 256 + gc] =
                        f2bf((x - mu) * rr * gamma[gc] + beta[gc]);
                }
            }
    } else {
#pragma unroll
        for (int i = 0; i < 2; i++)
#pragma unroll
            for (int r = 0; r < 4; r++) {
                const int gr = row0 + i * 16 + quad * 4 + r;
#pragma unroll
                for (int j = 0; j < 4; j++)
                    Xout[(size_t)gr * 256 + w * 64 + j * 16 + c] = xv[i][j][r];
            }
    }
}

// ---------------------------------------------------------------------------
// MFMA flash attention v5: v4 + raw v_exp_f32 + 128-key super-tiles
// (2 x 64-key tiles per barrier pair; halves sync count).
// ---------------------------------------------------------------------------
__global__ __launch_bounds__(256) void attn_kernel(
    const u16* __restrict__ QKV, const u16* __restrict__ VT,
    u16* __restrict__ POa, u16* __restrict__ POb, float* __restrict__ Lp)
{
    const int h = blockIdx.y, b = blockIdx.z;
    const int half = blockIdx.x & 1;
    const int q0 = (blockIdx.x >> 1) * 128;
    const int tid = threadIdx.x, w = tid >> 6, lane = tid & 63;
    const int c = lane & 15, quad = lane >> 4;

    __shared__ u16 Kf[4096];     // two 64-key fragments
    __shared__ u16 Vf[4096];

    const u16* qp = QKV + (size_t)(b * T_SEQ + q0 + w * 32 + c) * QKV_N + h * 32 + quad * 8;
    bf16x8 aQ0 = *(const bf16x8*)qp;
    bf16x8 aQ1 = *(const bf16x8*)(qp + 16 * QKV_N);

    float l0 = 0.f, l1 = 0.f;
    f32x4 O[2][2] = {};

    const u16* kgp = QKV + (size_t)(b * T_SEQ + w * 16 + c) * QKV_N + 256 + h * 32 + quad * 8;
    const u16* vgp = VT + ((size_t)h * 32 + (lane & 31)) * M_ROWS + b * T_SEQ
                     + (w * 2 + (lane >> 5)) * 8;
    u16* kfw = Kf + w * 512 + lane * 8;
    u16* vfw = Vf + w * 512 + lane * 8;
    const int LA = (quad & 1) * 32 + c, LB = LA + 16;
    const bool gsel = quad < 2;

    const int kbeg = half * (T_SEQ / 2);
    const int kend = kbeg + T_SEQ / 2;

    bf16x8 gK0 = *(const bf16x8*)(kgp + (size_t)kbeg * QKV_N);
    bf16x8 gK1 = *(const bf16x8*)(kgp + (size_t)(kbeg + 64) * QKV_N);
    bf16x8 gV0 = *(const bf16x8*)(vgp + kbeg);
    bf16x8 gV1 = *(const bf16x8*)(vgp + kbeg + 64);

    for (int k0 = kbeg; k0 < kend; k0 += 128) {
        __syncthreads();
        *(bf16x8*)kfw          = gK0;
        *(bf16x8*)(kfw + 2048) = gK1;
        *(bf16x8*)vfw          = gV0;
        *(bf16x8*)(vfw + 2048) = gV1;
        if (k0 + 128 < kend) {
            gK0 = *(const bf16x8*)(kgp + (size_t)(k0 + 128) * QKV_N);
            gK1 = *(const bf16x8*)(kgp + (size_t)(k0 + 192) * QKV_N);
            gV0 = *(const bf16x8*)(vgp + k0 + 128);
            gV1 = *(const bf16x8*)(vgp + k0 + 192);
        }
        __syncthreads();

#pragma unroll
        for (int hf = 0; hf < 2; hf++) {
            const u16* Kb = Kf + hf * 2048;
            const u16* Vb = Vf + hf * 2048;

            unsigned pk[4][2][2];
#pragma unroll
            for (int g = 0; g < 4; g++) {
                bf16x8 aK = *(const bf16x8*)&Kb[g * 512 + lane * 8];
                f32x4 S0 = __builtin_amdgcn_mfma_f32_16x16x32_bf16(
                    aK, aQ0, (f32x4){0.f, 0.f, 0.f, 0.f}, 0, 0, 0);
                f32x4 S1 = __builtin_amdgcn_mfma_f32_16x16x32_bf16(
                    aK, aQ1, (f32x4){0.f, 0.f, 0.f, 0.f}, 0, 0, 0);
                float p0 = __builtin_amdgcn_exp2f(S0[0]);
                float p1 = __builtin_amdgcn_exp2f(S0[1]);
                float p2 = __builtin_amdgcn_exp2f(S0[2]);
                float p3 = __builtin_amdgcn_exp2f(S0[3]);
                l0 += (p0 + p1) + (p2 + p3);
                pk[g][0][0] = pack2bf(p0, p1);
                pk[g][0][1] = pack2bf(p2, p3);
                p0 = __builtin_amdgcn_exp2f(S1[0]);
                p1 = __builtin_amdgcn_exp2f(S1[1]);
                p2 = __builtin_amdgcn_exp2f(S1[2]);
                p3 = __builtin_amdgcn_exp2f(S1[3]);
                l1 += (p0 + p1) + (p2 + p3);
                pk[g][1][0] = pack2bf(p0, p1);
                pk[g][1][1] = pack2bf(p2, p3);
            }

#pragma unroll
            for (int kh = 0; kh < 2; kh++) {
                bf16x8 bV0 = *(const bf16x8*)&Vb[((kh * 4 + quad) * 32 + c) * 8];
                bf16x8 bV1 = *(const bf16x8*)&Vb[((kh * 4 + quad) * 32 + 16 + c) * 8];
#pragma unroll
                for (int qg = 0; qg < 2; qg++) {
                    int e00 = __shfl((int)pk[2 * kh][qg][0],     LA, 64);
                    int e01 = __shfl((int)pk[2 * kh + 1][qg][0], LA, 64);
                    int e10 = __shfl((int)pk[2 * kh][qg][1],     LA, 64);
                    int e11 = __shfl((int)pk[2 * kh + 1][qg][1], LA, 64);
                    int e20 = __shfl((int)pk[2 * kh][qg][0],     LB, 64);
                    int e21 = __shfl((int)pk[2 * kh + 1][qg][0], LB, 64);
                    int e30 = __shfl((int)pk[2 * kh][qg][1],     LB, 64);
                    int e31 = __shfl((int)pk[2 * kh + 1][qg][1], LB, 64);
                    u32x4 ap;
                    ap[0] = (unsigned)(gsel ? e00 : e01);
                    ap[1] = (unsigned)(gsel ? e10 : e11);
                    ap[2] = (unsigned)(gsel ? e20 : e21);
                    ap[3] = (unsigned)(gsel ? e30 : e31);
                    bf16x8 aP = __builtin_bit_cast(bf16x8, ap);
                    O[qg][0] = __builtin_amdgcn_mfma_f32_16x16x32_bf16(aP, bV0, O[qg][0], 0, 0, 0);
                    O[qg][1] = __builtin_amdgcn_mfma_f32_16x16x32_bf16(aP, bV1, O[qg][1], 0, 0, 0);
                }
            }
        }
    }

    l0 += __shfl_xor(l0, 16, 64); l0 += __shfl_xor(l0, 32, 64);
    l1 += __shfl_xor(l1, 16, 64); l1 += __shfl_xor(l1, 32, 64);

    u16* pb = (half ? POb : POa)
              + (size_t)(b * T_SEQ + q0 + w * 32) * 256 + h * 32;
    if (quad == 0) {
        float* lb = Lp + (size_t)half * M_ROWS * 8
                    + (size_t)(b * T_SEQ + q0 + w * 32) * 8 + h;
        lb[(size_t)c * 8]        = l0;
        lb[(size_t)(16 + c) * 8] = l1;
    }
#pragma unroll
    for (int r = 0; r < 4; r++) {
        int src = quad * 4 + r;
        pb[(size_t)src * 256 + c]             = f2bf(O[0][0][r]);
        pb[(size_t)src * 256 + 16 + c]        = f2bf(O[0][1][r]);
        pb[(size_t)(16 + src) * 256 + c]      = f2bf(O[1][0][r]);
        pb[(size_t)(16 + src) * 256 + 16 + c] = f2bf(O[1][1][r]);
    }
}

// ---------------------------------------------------------------------------
// Merge the two key-halves: Ob = (POa + POb) / (la + lb). Wave per row.
// ---------------------------------------------------------------------------
__global__ __launch_bounds__(256) void attn_merge(
    const u16* __restrict__ POa, const u16* __restrict__ POb,
    const float* __restrict__ Lp, u16* __restrict__ Ob)
{
    const int w = threadIdx.x >> 6, lane = threadIdx.x & 63;
    const int row = blockIdx.x * 4 + w;
    const int head = lane >> 3;
    const float la = Lp[(size_t)row * 8 + head];
    const float lb = Lp[(size_t)M_ROWS * 8 + (size_t)row * 8 + head];
    const float inv = 1.0f / (la + lb);
    bf16x4 a = *(const bf16x4*)&POa[(size_t)row * 256 + lane * 4];
    bf16x4 b = *(const bf16x4*)&POb[(size_t)row * 256 + lane * 4];
    bf16x4 o;
#pragma unroll
    for (int i = 0; i < 4; i++) o[i] = (short)f2bf((bf2f(a[i]) + bf2f(b[i])) * inv);
    *(bf16x4*)&Ob[(size_t)row * 256 + lane * 4] = o;
}

// ---------------------------------------------------------------------------
extern "C" void kernel_launch(void* const* d_in, const int* in_sizes, int n_in,
                              void* d_out, int out_size, void* d_ws, size_t ws_size,
                              hipStream_t stream)
{
    const float* x     = (const float*)d_in[0];
    const float* ln1_s = (const float*)d_in[1];
    const float* ln1_b = (const float*)d_in[2];
    const float* wq    = (const float*)d_in[3];
    const float* bq    = (const float*)d_in[4];
    const float* wk    = (const float*)d_in[5];
    const float* bk    = (const float*)d_in[6];
    const float* wv    = (const float*)d_in[7];
    const float* bv    = (const float*)d_in[8];
    const float* wo    = (const float*)d_in[9];
    const float* bo    = (const float*)d_in[10];
    const float* ln2_s = (const float*)d_in[11];
    const float* ln2_b = (const float*)d_in[12];
    const float* w1    = (const float*)d_in[13];
    const float* b1    = (const float*)d_in[14];
    const float* w2    = (const float*)d_in[15];
    const float* b2    = (const float*)d_in[16];

    float* X = (float*)d_out;                   // fp32 residual stream

    // Workspace (u16 elems). Liveness as in round 9 (no live overlap).
    u16* normed = (u16*)d_ws;                               // 8192*256
    u16* qkv    = normed + (size_t)M_ROWS * 256;            // 8192*768 (V third unused)
    u16* POa    = qkv + (size_t)M_ROWS * QKV_N;             // 8192*256
    u16* h1     = qkv;   // spans qkv+POa: 8192*1024
    u16* wqkv_t = POa + (size_t)M_ROWS * 256;               // 6*768*256
    u16* wo_t   = wqkv_t + (size_t)N_LAYERSC * QKV_N * 256; // 6*256*256
    u16* w1_t   = wo_t + (size_t)N_LAYERSC * 256 * 256;     // 6*1024*256
    u16* w2_t   = w1_t + (size_t)N_LAYERSC * D_FFC * 256;   // 6*256*1024
    float* qkvb = (float*)(w2_t + (size_t)N_LAYERSC * 256 * D_FFC); // 6*768 fp32
    u16* VTb    = (u16*)(qkvb + N_LAYERSC * QKV_N);         // 256*8192
    u16* POb    = VTb + (size_t)256 * M_ROWS;               // 8192*256
    float* Lp   = (float*)(POb + (size_t)M_ROWS * 256);     // 2*8192*8 fp32

    dim3 blk(256);

    // ---- weight prep (every call; graph-safe)
    transpose_w<<<dim3(8, 8, 6),  blk, 0, stream>>>(wq, wqkv_t,             256, 256, 65536, QKV_N * 256, QSCALE);
    transpose_w<<<dim3(8, 8, 6),  blk, 0, stream>>>(wk, wqkv_t + 256 * 256, 256, 256, 65536, QKV_N * 256, 1.0f);
    transpose_w<<<dim3(8, 8, 6),  blk, 0, stream>>>(wv, wqkv_t + 512 * 256, 256, 256, 65536, QKV_N * 256, 1.0f);
    transpose_w<<<dim3(8, 8, 6),  blk, 0, stream>>>(wo, wo_t,               256, 256, 65536, 65536, 1.0f);
    transpose_w<<<dim3(32, 8, 6), blk, 0, stream>>>(w1, w1_t,               256, D_FFC, 256 * D_FFC, 256 * D_FFC, 1.0f);
    transpose_w<<<dim3(8, 32, 6), blk, 0, stream>>>(w2, w2_t,               D_FFC, 256, 256 * D_FFC, 256 * D_FFC, 1.0f);
    pack_bias<<<dim3(18), blk, 0, stream>>>(bq, bk, bv, qkvb);

    hipMemcpyAsync(X, x, (size_t)M_ROWS * 256 * sizeof(float),
                   hipMemcpyDeviceToDevice, stream);

    dim3 g_qkv(QKV_N / 128, M_ROWS / 128);          // (6,64)
    dim3 g_ff(D_FFC / 128, M_ROWS / 128);           // (8,64)
    dim3 g_ln32(M_ROWS / 32);                       // 256 blocks
    dim3 g_attn(2 * T_SEQ / 128, N_HEADSC, B_SZ);   // 1024 blocks
    dim3 g_mrg(M_ROWS / 4);

    ln_kernel<<<dim3(M_ROWS / 4), blk, 0, stream>>>(X, ln1_s, ln1_b, normed);

    for (int l = 0; l < N_LAYERSC; l++) {
        mfma_gemm<3><<<g_qkv, blk, 0, stream>>>(
            normed, wqkv_t + (size_t)l * QKV_N * 256, qkvb + l * QKV_N,
            VTb, qkv, QKV_N, 256);
        attn_kernel<<<g_attn, blk, 0, stream>>>(qkv, VTb, POa, POb, Lp);
        attn_merge<<<g_mrg, blk, 0, stream>>>(POa, POb, Lp, normed);
        gemm_ln<1><<<g_ln32, blk, 0, stream>>>(
            normed, wo_t + (size_t)l * 256 * 256, bo + l * 256, X,
            X, ln2_s + l * 256, ln2_b + l * 256, VTb, 256);
        mfma_gemm<2><<<g_ff, blk, 0, stream>>>(
            VTb, w1_t + (size_t)l * D_FFC * 256, b1 + l * D_FFC,
            nullptr, h1, D_FFC, 256);
        if (l + 1 < N_LAYERSC) {
            gemm_ln<1><<<g_ln32, blk, 0, stream>>>(
                h1, w2_t + (size_t)l * 256 * D_FFC, b2 + l * 256, X,
                X, ln1_s + (l + 1) * 256, ln1_b + (l + 1) * 256, normed, D_FFC);
        } else {
            gemm_ln<0><<<g_ln32, blk, 0, stream>>>(
                h1, w2_t + (size_t)l * 256 * D_FFC, b2 + l * 256, X,
                X, nullptr, nullptr, nullptr, D_FFC);
        }
    }
}

// Round 11
// 754.374 us; speedup vs baseline: 1.2816x; 1.0174x over previous
//
#include <hip/hip_runtime.h>
#include <math.h>

#define D_MODELC 256
#define N_LAYERSC 6
#define N_HEADSC 8
#define D_FFC 1024
#define HEAD_DIMC 32
#define B_SZ 4
#define T_SEQ 2048
#define M_ROWS 8192
#define QKV_N 768

typedef short bf16x8 __attribute__((ext_vector_type(8)));
typedef short bf16x4 __attribute__((ext_vector_type(4)));
typedef float f32x4  __attribute__((ext_vector_type(4)));
typedef unsigned u32x4 __attribute__((ext_vector_type(4)));
typedef unsigned short u16;

// scale(1/sqrt(32)) * log2(e) folded into wq at conversion time
#define QSCALE 0.25503488f

__device__ __forceinline__ u16 f2bf(float x) {
    unsigned u = __builtin_bit_cast(unsigned, x);
    u += 0x7FFF + ((u >> 16) & 1);          // round-to-nearest-even
    return (u16)(u >> 16);
}

__device__ __forceinline__ float bf2f(short x) {
    return __builtin_bit_cast(float, (unsigned)((u16)x) << 16);
}

__device__ __forceinline__ unsigned pack2bf(float a, float b) {  // truncating
    unsigned ua = __builtin_bit_cast(unsigned, a);
    unsigned ub = __builtin_bit_cast(unsigned, b);
    return (ua >> 16) | (ub & 0xFFFF0000u);
}

// A&S 7.1.26 erf (|err|<=1.5e-7), one v_exp + one v_rcp; exact-gelu drop-in.
__device__ __forceinline__ float fast_gelu(float x) {
    float y  = x * 0.70710678118654752f;
    float ay = __builtin_fabsf(y);
    float t  = __builtin_amdgcn_rcpf(1.0f + 0.3275911f * ay);
    float p  = t * (0.254829592f + t * (-0.284496736f + t * (1.421413741f
               + t * (-1.453152027f + t * 1.061405429f))));
    float e  = __builtin_amdgcn_exp2f(-ay * ay * 1.4426950408889634f);
    float er = 1.0f - p * e;
    er = y < 0.0f ? -er : er;
    return 0.5f * x * (1.0f + er);
}

// ---------------------------------------------------------------------------
// Weight transpose+convert: dst[n][k] = bf16(src[k][n] * scale), per layer z.
// ---------------------------------------------------------------------------
__global__ __launch_bounds__(256) void transpose_w(
    const float* __restrict__ src, u16* __restrict__ dst,
    int K, int N, int srcLS, int dstLS, float scale)
{
    __shared__ float t[32][33];
    src += (size_t)blockIdx.z * srcLS;
    dst += (size_t)blockIdx.z * dstLS;
    const int k0 = blockIdx.y * 32, n0 = blockIdx.x * 32;
    const int r = threadIdx.x >> 3, c4 = (threadIdx.x & 7) * 4;
    const float4 v = *(const float4*)(src + (size_t)(k0 + r) * N + n0 + c4);
    t[r][c4 + 0] = v.x; t[r][c4 + 1] = v.y;
    t[r][c4 + 2] = v.z; t[r][c4 + 3] = v.w;
    __syncthreads();
    bf16x4 o;
#pragma unroll
    for (int i = 0; i < 4; i++) o[i] = (short)f2bf(t[c4 + i][r] * scale);
    *(bf16x4*)(dst + (size_t)(n0 + r) * K + k0 + c4) = o;
}

// Fused QKV bias: [l][768] = [ bq*QSCALE | bk | bv ]
__global__ __launch_bounds__(256) void pack_bias(
    const float* __restrict__ bq, const float* __restrict__ bk,
    const float* __restrict__ bv, float* __restrict__ dst)
{
    int i = blockIdx.x * 256 + threadIdx.x;
    if (i >= N_LAYERSC * QKV_N) return;
    int l = i / QKV_N, j = i % QKV_N;
    float v;
    if (j < 256)      v = bq[l * 256 + j] * QSCALE;
    else if (j < 512) v = bk[l * 256 + j - 256];
    else              v = bv[l * 256 + j - 512];
    dst[i] = v;
}

// ---------------------------------------------------------------------------
// LayerNorm (standalone; used only for layer 0's ln1).
// ---------------------------------------------------------------------------
__global__ __launch_bounds__(256) void ln_kernel(
    const float* __restrict__ X, const float* __restrict__ gamma,
    const float* __restrict__ beta, u16* __restrict__ Y)
{
    const int w = threadIdx.x >> 6, lane = threadIdx.x & 63;
    const int row = blockIdx.x * 4 + w;
    const float4 v = *(const float4*)(X + (size_t)row * 256 + lane * 4);
    float sum = v.x + v.y + v.z + v.w;
    float sq  = v.x * v.x + v.y * v.y + v.z * v.z + v.w * v.w;
#pragma unroll
    for (int off = 32; off > 0; off >>= 1) {
        sum += __shfl_xor(sum, off, 64);
        sq  += __shfl_xor(sq,  off, 64);
    }
    float mu  = sum * (1.0f / 256.0f);
    float var = sq * (1.0f / 256.0f) - mu * mu;
    float rr  = rsqrtf(var + 1e-5f);
    const float4 g  = *(const float4*)(gamma + lane * 4);
    const float4 bb = *(const float4*)(beta + lane * 4);
    bf16x4 o;
    o[0] = (short)f2bf((v.x - mu) * rr * g.x + bb.x);
    o[1] = (short)f2bf((v.y - mu) * rr * g.y + bb.y);
    o[2] = (short)f2bf((v.z - mu) * rr * g.z + bb.z);
    o[3] = (short)f2bf((v.w - mu) * rr * g.w + bb.w);
    *(bf16x4*)(Y + (size_t)row * 256 + lane * 4) = o;
}

// ---------------------------------------------------------------------------
// MFMA GEMM, 128x128 tile, BK=64, REGISTER-PREFETCH double buffering:
// k-tile t+1 is loaded into VGPRs while tile t computes; ds_write_b128 at
// barrier time only (no cold global latency on the sync path).
// EPI: 0 = bf16 out (+bias); 2 = bf16 gelu(+bias);
//      3 = qkv mode: col<512 -> bf16 to Cout (ld=768); col>=512 -> V written
//          TRANSPOSED to Vout[dim][token].
// ---------------------------------------------------------------------------
template <int EPI>
__global__ __launch_bounds__(256) void mfma_gemm(
    const u16* __restrict__ A, const u16* __restrict__ Bt,
    const float* __restrict__ bias, u16* __restrict__ Vout,
    void* __restrict__ Cout, int N, int K)
{
    __shared__ u16 As[128 * 64];
    __shared__ u16 Bs[128 * 64];
    const int tid = threadIdx.x, w = tid >> 6, lane = tid & 63;
    const int c = lane & 15, quad = lane >> 4;
    const int row0 = blockIdx.y * 128, col0 = blockIdx.x * 128;
    const int wr = w >> 1, wc = w & 1;

    // per-thread staging slots: chunk ci -> byte fl in tile, row/col in global
    int flv[4], rA[4], colA[4];
#pragma unroll
    for (int ci = 0; ci < 4; ci++) {
        flv[ci]  = (w * 4 + ci) * 1024 + lane * 16;
        rA[ci]   = flv[ci] >> 7;
        colA[ci] = (flv[ci] & 127) >> 1;
    }

    f32x4 acc[4][4] = {};
    bf16x8 pA[4], pB[4];
#pragma unroll
    for (int ci = 0; ci < 4; ci++) {
        pA[ci] = *(const bf16x8*)(A  + (size_t)(row0 + rA[ci]) * K + colA[ci]);
        pB[ci] = *(const bf16x8*)(Bt + (size_t)(col0 + rA[ci]) * K + colA[ci]);
    }

    for (int k0 = 0; k0 < K; k0 += 64) {
        __syncthreads();                       // prior iter's LDS reads done
#pragma unroll
        for (int ci = 0; ci < 4; ci++) {
            *(bf16x8*)((char*)As + flv[ci]) = pA[ci];
            *(bf16x8*)((char*)Bs + flv[ci]) = pB[ci];
        }
        if (k0 + 64 < K) {                     // prefetch t+1 (flies over compute)
#pragma unroll
            for (int ci = 0; ci < 4; ci++) {
                pA[ci] = *(const bf16x8*)(A  + (size_t)(row0 + rA[ci]) * K + k0 + 64 + colA[ci]);
                pB[ci] = *(const bf16x8*)(Bt + (size_t)(col0 + rA[ci]) * K + k0 + 64 + colA[ci]);
            }
        }
        __syncthreads();                       // staging visible
#pragma unroll
        for (int kk = 0; kk < 2; kk++) {
            bf16x8 af[4], bfv[4];
#pragma unroll
            for (int i = 0; i < 4; i++)
                af[i] = *(const bf16x8*)&As[(wr * 64 + i * 16 + c) * 64 + kk * 32 + quad * 8];
#pragma unroll
            for (int j = 0; j < 4; j++)
                bfv[j] = *(const bf16x8*)&Bs[(wc * 64 + j * 16 + c) * 64 + kk * 32 + quad * 8];
#pragma unroll
            for (int i = 0; i < 4; i++)
#pragma unroll
                for (int j = 0; j < 4; j++)
                    acc[i][j] = __builtin_amdgcn_mfma_f32_16x16x32_bf16(
                        af[i], bfv[j], acc[i][j], 0, 0, 0);
        }
    }

    float bj[4];
#pragma unroll
    for (int j = 0; j < 4; j++) bj[j] = bias[col0 + wc * 64 + j * 16 + c];

    if (EPI == 3 && col0 >= 512) {
        // V third: write transposed. 4 consecutive tokens per 8B store.
#pragma unroll
        for (int i = 0; i < 4; i++) {
            const int tok = row0 + wr * 64 + i * 16 + quad * 4;
#pragma unroll
            for (int j = 0; j < 4; j++) {
                const int dim = col0 - 512 + wc * 64 + j * 16 + c;
                bf16x4 o;
#pragma unroll
                for (int r = 0; r < 4; r++) o[r] = (short)f2bf(acc[i][j][r] + bj[j]);
                *(bf16x4*)&Vout[(size_t)dim * M_ROWS + tok] = o;
            }
        }
        return;
    }

#pragma unroll
    for (int i = 0; i < 4; i++) {
#pragma unroll
        for (int r = 0; r < 4; r++) {
            const int gr = row0 + wr * 64 + i * 16 + quad * 4 + r;
#pragma unroll
            for (int j = 0; j < 4; j++) {
                const int gc = col0 + wc * 64 + j * 16 + c;
                float v = acc[i][j][r] + bj[j];
                if (EPI == 2) v = fast_gelu(v);
                ((u16*)Cout)[(size_t)gr * N + gc] = f2bf(v);
            }
        }
    }
}

// ---------------------------------------------------------------------------
// GEMM (N=256, BM=32, BN=256) + residual + optional fused LayerNorm, with
// register-prefetch double buffering (1 block/CU -> latency hiding is ILP).
// ---------------------------------------------------------------------------
template <int DOLN>
__global__ __launch_bounds__(256) void gemm_ln(
    const u16* __restrict__ A, const u16* __restrict__ Bt,
    const float* __restrict__ bias, const float* __restrict__ resid,
    float* __restrict__ Xout, const float* __restrict__ gamma,
    const float* __restrict__ beta, u16* __restrict__ Nout, int K)
{
    __shared__ u16 As[32 * 64];
    __shared__ u16 Bs[256 * 64];
    __shared__ float2 red[4][32];                 // per-wave {sum,sq} per row
    const int tid = threadIdx.x, w = tid >> 6, lane = tid & 63;
    const int c = lane & 15, quad = lane >> 4;
    const int row0 = blockIdx.x * 32;

    const int flA  = w * 1024 + lane * 16;        // A: one chunk/thread
    const int rAa  = flA >> 7, colAa = (flA & 127) >> 1;
    int flB[8], rB[8], colB[8];
#pragma unroll
    for (int ci = 0; ci < 8; ci++) {
        flB[ci]  = (w * 8 + ci) * 1024 + lane * 16;
        rB[ci]   = flB[ci] >> 7;
        colB[ci] = (flB[ci] & 127) >> 1;
    }

    f32x4 acc[2][4] = {};
    bf16x8 pA = *(const bf16x8*)(A + (size_t)(row0 + rAa) * K + colAa);
    bf16x8 pB[8];
#pragma unroll
    for (int ci = 0; ci < 8; ci++)
        pB[ci] = *(const bf16x8*)(Bt + (size_t)rB[ci] * K + colB[ci]);

    for (int k0 = 0; k0 < K; k0 += 64) {
        __syncthreads();
        *(bf16x8*)((char*)As + flA) = pA;
#pragma unroll
        for (int ci = 0; ci < 8; ci++)
            *(bf16x8*)((char*)Bs + flB[ci]) = pB[ci];
        if (k0 + 64 < K) {
            pA = *(const bf16x8*)(A + (size_t)(row0 + rAa) * K + k0 + 64 + colAa);
#pragma unroll
            for (int ci = 0; ci < 8; ci++)
                pB[ci] = *(const bf16x8*)(Bt + (size_t)rB[ci] * K + k0 + 64 + colB[ci]);
        }
        __syncthreads();
#pragma unroll
        for (int kk = 0; kk < 2; kk++) {
            bf16x8 af[2], bfv[4];
#pragma unroll
            for (int i = 0; i < 2; i++)
                af[i] = *(const bf16x8*)&As[(i * 16 + c) * 64 + kk * 32 + quad * 8];
#pragma unroll
            for (int j = 0; j < 4; j++)
                bfv[j] = *(const bf16x8*)&Bs[(w * 64 + j * 16 + c) * 64 + kk * 32 + quad * 8];
#pragma unroll
            for (int i = 0; i < 2; i++)
#pragma unroll
                for (int j = 0; j < 4; j++)
                    acc[i][j] = __builtin_amdgcn_mfma_f32_16x16x32_bf16(
                        af[i], bfv[j], acc[i][j], 0, 0, 0);
        }
    }

    // x = acc + bias + resid
    float bj[4];
#pragma unroll
    for (int j = 0; j < 4; j++) bj[j] = bias[w * 64 + j * 16 + c];
    float xv[2][4][4];
#pragma unroll
    for (int i = 0; i < 2; i++)
#pragma unroll
        for (int r = 0; r < 4; r++) {
            const int gr = row0 + i * 16 + quad * 4 + r;
#pragma unroll
            for (int j = 0; j < 4; j++) {
                const int gc = w * 64 + j * 16 + c;
                xv[i][j][r] = acc[i][j][r] + bj[j] + resid[(size_t)gr * 256 + gc];
            }
        }

    if (DOLN) {
        float sm[2][4], sp[2][4];
#pragma unroll
        for (int i = 0; i < 2; i++)
#pragma unroll
            for (int r = 0; r < 4; r++) {
                float s = 0.f, q = 0.f;
#pragma unroll
                for (int j = 0; j < 4; j++) { s += xv[i][j][r]; q += xv[i][j][r] * xv[i][j][r]; }
                sm[i][r] = s; sp[i][r] = q;
            }
#pragma unroll
        for (int off = 1; off < 16; off <<= 1)
#pragma unroll
            for (int i = 0; i < 2; i++)
#pragma unroll
                for (int r = 0; r < 4; r++) {
                    sm[i][r] += __shfl_xor(sm[i][r], off, 64);
                    sp[i][r] += __shfl_xor(sp[i][r], off, 64);
                }
        __syncthreads();
        if (c == 0) {
#pragma unroll
            for (int i = 0; i < 2; i++)
#pragma unroll
                for (int r = 0; r < 4; r++)
                    red[w][i * 16 + quad * 4 + r] = make_float2(sm[i][r], sp[i][r]);
        }
        __syncthreads();
#pragma unroll
        for (int i = 0; i < 2; i++)
#pragma unroll
            for (int r = 0; r < 4; r++) {
                const int row = i * 16 + quad * 4 + r;
                float2 t0 = red[0][row], t1 = red[1][row];
                float2 t2 = red[2][row], t3 = red[3][row];
                float S = (t0.x + t1.x) + (t2.x + t3.x);
                float Q = (t0.y + t1.y) + (t2.y + t3.y);
                float mu = S * (1.0f / 256.0f);
                float var = Q * (1.0f / 256.0f) - mu * mu;
                float rr = rsqrtf(var + 1e-5f);
                const int gr = row0 + row;
#pragma unroll
                for (int j = 0; j < 4; j++) {
                    const int gc = w * 64 + j * 16 + c;
                    float x = xv[i][j][r];
                    Xout[(size_t)gr * 256 + gc] = x;
                    Nout[(size_t)gr * 256 + gc] =
                        f2bf((x - mu) * rr * gamma[gc] + beta[gc]);
                }
            }
    } else {
#pragma unroll
        for (int i = 0; i < 2; i++)
#pragma unroll
            for (int r = 0; r < 4; r++) {
                const int gr = row0 + i * 16 + quad * 4 + r;
#pragma unroll
                for (int j = 0; j < 4; j++)
                    Xout[(size_t)gr * 256 + w * 64 + j * 16 + c] = xv[i][j][r];
            }
    }
}

// ---------------------------------------------------------------------------
// MFMA flash attention v6: v5 with 64-query blocks (grid x2 = 2048 blocks,
// 8 blocks/CU) for latency hiding. Register-prefetch dbuf, 128-key
// super-tiles, raw v_exp, key-split x2, additive partials.
// ---------------------------------------------------------------------------
__global__ __launch_bounds__(256) void attn_kernel(
    const u16* __restrict__ QKV, const u16* __restrict__ VT,
    u16* __restrict__ POa, u16* __restrict__ POb, float* __restrict__ Lp)
{
    const int h = blockIdx.y, b = blockIdx.z;
    const int half = blockIdx.x & 1;
    const int q0 = (blockIdx.x >> 1) * 64;
    const int tid = threadIdx.x, w = tid >> 6, lane = tid & 63;
    const int c = lane & 15, quad = lane >> 4;

    __shared__ u16 Kf[4096];     // two 64-key fragments
    __shared__ u16 Vf[4096];

    // wave owns 16 queries: q0 + w*16 + c
    bf16x8 aQ = *(const bf16x8*)(QKV + (size_t)(b * T_SEQ + q0 + w * 16 + c) * QKV_N
                                 + h * 32 + quad * 8);

    float l0 = 0.f;
    f32x4 O0 = {0.f, 0.f, 0.f, 0.f}, O1 = {0.f, 0.f, 0.f, 0.f};

    const u16* kgp = QKV + (size_t)(b * T_SEQ + w * 16 + c) * QKV_N + 256 + h * 32 + quad * 8;
    const u16* vgp = VT + ((size_t)h * 32 + (lane & 31)) * M_ROWS + b * T_SEQ
                     + (w * 2 + (lane >> 5)) * 8;
    u16* kfw = Kf + w * 512 + lane * 8;
    u16* vfw = Vf + w * 512 + lane * 8;
    const int LA = (quad & 1) * 32 + c, LB = LA + 16;
    const bool gsel = quad < 2;

    const int kbeg = half * (T_SEQ / 2);
    const int kend = kbeg + T_SEQ / 2;

    bf16x8 gK0 = *(const bf16x8*)(kgp + (size_t)kbeg * QKV_N);
    bf16x8 gK1 = *(const bf16x8*)(kgp + (size_t)(kbeg + 64) * QKV_N);
    bf16x8 gV0 = *(const bf16x8*)(vgp + kbeg);
    bf16x8 gV1 = *(const bf16x8*)(vgp + kbeg + 64);

    for (int k0 = kbeg; k0 < kend; k0 += 128) {
        __syncthreads();
        *(bf16x8*)kfw          = gK0;
        *(bf16x8*)(kfw + 2048) = gK1;
        *(bf16x8*)vfw          = gV0;
        *(bf16x8*)(vfw + 2048) = gV1;
        if (k0 + 128 < kend) {
            gK0 = *(const bf16x8*)(kgp + (size_t)(k0 + 128) * QKV_N);
            gK1 = *(const bf16x8*)(kgp + (size_t)(k0 + 192) * QKV_N);
            gV0 = *(const bf16x8*)(vgp + k0 + 128);
            gV1 = *(const bf16x8*)(vgp + k0 + 192);
        }
        __syncthreads();

#pragma unroll
        for (int hf = 0; hf < 2; hf++) {
            const u16* Kb = Kf + hf * 2048;
            const u16* Vb = Vf + hf * 2048;

            unsigned pk[4][2];
#pragma unroll
            for (int g = 0; g < 4; g++) {
                bf16x8 aK = *(const bf16x8*)&Kb[g * 512 + lane * 8];
                f32x4 S = __builtin_amdgcn_mfma_f32_16x16x32_bf16(
                    aK, aQ, (f32x4){0.f, 0.f, 0.f, 0.f}, 0, 0, 0);
                float p0 = __builtin_amdgcn_exp2f(S[0]);
                float p1 = __builtin_amdgcn_exp2f(S[1]);
                float p2 = __builtin_amdgcn_exp2f(S[2]);
                float p3 = __builtin_amdgcn_exp2f(S[3]);
                l0 += (p0 + p1) + (p2 + p3);
                pk[g][0] = pack2bf(p0, p1);
                pk[g][1] = pack2bf(p2, p3);
            }

#pragma unroll
            for (int kh = 0; kh < 2; kh++) {
                bf16x8 bV0 = *(const bf16x8*)&Vb[((kh * 4 + quad) * 32 + c) * 8];
                bf16x8 bV1 = *(const bf16x8*)&Vb[((kh * 4 + quad) * 32 + 16 + c) * 8];
                int e00 = __shfl((int)pk[2 * kh][0],     LA, 64);
                int e01 = __shfl((int)pk[2 * kh + 1][0], LA, 64);
                int e10 = __shfl((int)pk[2 * kh][1],     LA, 64);
                int e11 = __shfl((int)pk[2 * kh + 1][1], LA, 64);
                int e20 = __shfl((int)pk[2 * kh][0],     LB, 64);
                int e21 = __shfl((int)pk[2 * kh + 1][0], LB, 64);
                int e30 = __shfl((int)pk[2 * kh][1],     LB, 64);
                int e31 = __shfl((int)pk[2 * kh + 1][1], LB, 64);
                u32x4 ap;
                ap[0] = (unsigned)(gsel ? e00 : e01);
                ap[1] = (unsigned)(gsel ? e10 : e11);
                ap[2] = (unsigned)(gsel ? e20 : e21);
                ap[3] = (unsigned)(gsel ? e30 : e31);
                bf16x8 aP = __builtin_bit_cast(bf16x8, ap);
                O0 = __builtin_amdgcn_mfma_f32_16x16x32_bf16(aP, bV0, O0, 0, 0, 0);
                O1 = __builtin_amdgcn_mfma_f32_16x16x32_bf16(aP, bV1, O1, 0, 0, 0);
            }
        }
    }

    l0 += __shfl_xor(l0, 16, 64); l0 += __shfl_xor(l0, 32, 64);

    u16* pb = (half ? POb : POa)
              + (size_t)(b * T_SEQ + q0 + w * 16) * 256 + h * 32;
    if (quad == 0) {
        float* lb = Lp + (size_t)half * M_ROWS * 8
                    + (size_t)(b * T_SEQ + q0 + w * 16) * 8 + h;
        lb[(size_t)c * 8] = l0;
    }
#pragma unroll
    for (int r = 0; r < 4; r++) {
        int src = quad * 4 + r;
        pb[(size_t)src * 256 + c]      = f2bf(O0[r]);
        pb[(size_t)src * 256 + 16 + c] = f2bf(O1[r]);
    }
}

// ---------------------------------------------------------------------------
// Merge the two key-halves: Ob = (POa + POb) / (la + lb). Wave per row.
// ---------------------------------------------------------------------------
__global__ __launch_bounds__(256) void attn_merge(
    const u16* __restrict__ POa, const u16* __restrict__ POb,
    const float* __restrict__ Lp, u16* __restrict__ Ob)
{
    const int w = threadIdx.x >> 6, lane = threadIdx.x & 63;
    const int row = blockIdx.x * 4 + w;
    const int head = lane >> 3;
    const float la = Lp[(size_t)row * 8 + head];
    const float lb = Lp[(size_t)M_ROWS * 8 + (size_t)row * 8 + head];
    const float inv = 1.0f / (la + lb);
    bf16x4 a = *(const bf16x4*)&POa[(size_t)row * 256 + lane * 4];
    bf16x4 b = *(const bf16x4*)&POb[(size_t)row * 256 + lane * 4];
    bf16x4 o;
#pragma unroll
    for (int i = 0; i < 4; i++) o[i] = (short)f2bf((bf2f(a[i]) + bf2f(b[i])) * inv);
    *(bf16x4*)&Ob[(size_t)row * 256 + lane * 4] = o;
}

// ---------------------------------------------------------------------------
extern "C" void kernel_launch(void* const* d_in, const int* in_sizes, int n_in,
                              void* d_out, int out_size, void* d_ws, size_t ws_size,
                              hipStream_t stream)
{
    const float* x     = (const float*)d_in[0];
    const float* ln1_s = (const float*)d_in[1];
    const float* ln1_b = (const float*)d_in[2];
    const float* wq    = (const float*)d_in[3];
    const float* bq    = (const float*)d_in[4];
    const float* wk    = (const float*)d_in[5];
    const float* bk    = (const float*)d_in[6];
    const float* wv    = (const float*)d_in[7];
    const float* bv    = (const float*)d_in[8];
    const float* wo    = (const float*)d_in[9];
    const float* bo    = (const float*)d_in[10];
    const float* ln2_s = (const float*)d_in[11];
    const float* ln2_b = (const float*)d_in[12];
    const float* w1    = (const float*)d_in[13];
    const float* b1    = (const float*)d_in[14];
    const float* w2    = (const float*)d_in[15];
    const float* b2    = (const float*)d_in[16];

    float* X = (float*)d_out;                   // fp32 residual stream

    // Workspace (u16 elems). Liveness as in round 9 (no live overlap).
    u16* normed = (u16*)d_ws;                               // 8192*256
    u16* qkv    = normed + (size_t)M_ROWS * 256;            // 8192*768 (V third unused)
    u16* POa    = qkv + (size_t)M_ROWS * QKV_N;             // 8192*256
    u16* h1     = qkv;   // spans qkv+POa: 8192*1024
    u16* wqkv_t = POa + (size_t)M_ROWS * 256;               // 6*768*256
    u16* wo_t   = wqkv_t + (size_t)N_LAYERSC * QKV_N * 256; // 6*256*256
    u16* w1_t   = wo_t + (size_t)N_LAYERSC * 256 * 256;     // 6*1024*256
    u16* w2_t   = w1_t + (size_t)N_LAYERSC * D_FFC * 256;   // 6*256*1024
    float* qkvb = (float*)(w2_t + (size_t)N_LAYERSC * 256 * D_FFC); // 6*768 fp32
    u16* VTb    = (u16*)(qkvb + N_LAYERSC * QKV_N);         // 256*8192
    u16* POb    = VTb + (size_t)256 * M_ROWS;               // 8192*256
    float* Lp   = (float*)(POb + (size_t)M_ROWS * 256);     // 2*8192*8 fp32

    dim3 blk(256);

    // ---- weight prep (every call; graph-safe)
    transpose_w<<<dim3(8, 8, 6),  blk, 0, stream>>>(wq, wqkv_t,             256, 256, 65536, QKV_N * 256, QSCALE);
    transpose_w<<<dim3(8, 8, 6),  blk, 0, stream>>>(wk, wqkv_t + 256 * 256, 256, 256, 65536, QKV_N * 256, 1.0f);
    transpose_w<<<dim3(8, 8, 6),  blk, 0, stream>>>(wv, wqkv_t + 512 * 256, 256, 256, 65536, QKV_N * 256, 1.0f);
    transpose_w<<<dim3(8, 8, 6),  blk, 0, stream>>>(wo, wo_t,               256, 256, 65536, 65536, 1.0f);
    transpose_w<<<dim3(32, 8, 6), blk, 0, stream>>>(w1, w1_t,               256, D_FFC, 256 * D_FFC, 256 * D_FFC, 1.0f);
    transpose_w<<<dim3(8, 32, 6), blk, 0, stream>>>(w2, w2_t,               D_FFC, 256, 256 * D_FFC, 256 * D_FFC, 1.0f);
    pack_bias<<<dim3(18), blk, 0, stream>>>(bq, bk, bv, qkvb);

    hipMemcpyAsync(X, x, (size_t)M_ROWS * 256 * sizeof(float),
                   hipMemcpyDeviceToDevice, stream);

    dim3 g_qkv(QKV_N / 128, M_ROWS / 128);          // (6,64)
    dim3 g_ff(D_FFC / 128, M_ROWS / 128);           // (8,64)
    dim3 g_ln32(M_ROWS / 32);                       // 256 blocks
    dim3 g_attn(2 * T_SEQ / 64, N_HEADSC, B_SZ);    // (64,8,4) = 2048 blocks
    dim3 g_mrg(M_ROWS / 4);

    ln_kernel<<<dim3(M_ROWS / 4), blk, 0, stream>>>(X, ln1_s, ln1_b, normed);

    for (int l = 0; l < N_LAYERSC; l++) {
        mfma_gemm<3><<<g_qkv, blk, 0, stream>>>(
            normed, wqkv_t + (size_t)l * QKV_N * 256, qkvb + l * QKV_N,
            VTb, qkv, QKV_N, 256);
        attn_kernel<<<g_attn, blk, 0, stream>>>(qkv, VTb, POa, POb, Lp);
        attn_merge<<<g_mrg, blk, 0, stream>>>(POa, POb, Lp, normed);
        gemm_ln<1><<<g_ln32, blk, 0, stream>>>(
            normed, wo_t + (size_t)l * 256 * 256, bo + l * 256, X,
            X, ln2_s + l * 256, ln2_b + l * 256, VTb, 256);
        mfma_gemm<2><<<g_ff, blk, 0, stream>>>(
            VTb, w1_t + (size_t)l * D_FFC * 256, b1 + l * D_FFC,
            nullptr, h1, D_FFC, 256);
        if (l + 1 < N_LAYERSC) {
            gemm_ln<1><<<g_ln32, blk, 0, stream>>>(
                h1, w2_t + (size_t)l * 256 * D_FFC, b2 + l * 256, X,
                X, ln1_s + (l + 1) * 256, ln1_b + (l + 1) * 256, normed, D_FFC);
        } else {
            gemm_ln<0><<<g_ln32, blk, 0, stream>>>(
                h1, w2_t + (size_t)l * 256 * D_FFC, b2 + l * 256, X,
                X, nullptr, nullptr, nullptr, D_FFC);
        }
    }
}

// Round 12
// 653.635 us; speedup vs baseline: 1.4791x; 1.1541x over previous
//
#include <hip/hip_runtime.h>
#include <math.h>

#define D_MODELC 256
#define N_LAYERSC 6
#define N_HEADSC 8
#define D_FFC 1024
#define HEAD_DIMC 32
#define B_SZ 4
#define T_SEQ 2048
#define M_ROWS 8192
#define QKV_N 768

typedef short bf16x8 __attribute__((ext_vector_type(8)));
typedef short bf16x4 __attribute__((ext_vector_type(4)));
typedef float f32x4  __attribute__((ext_vector_type(4)));
typedef unsigned u32x4 __attribute__((ext_vector_type(4)));
typedef unsigned short u16;

// scale(1/sqrt(32)) * log2(e) folded into wq at conversion time
#define QSCALE 0.25503488f

__device__ __forceinline__ u16 f2bf(float x) {
    unsigned u = __builtin_bit_cast(unsigned, x);
    u += 0x7FFF + ((u >> 16) & 1);          // round-to-nearest-even
    return (u16)(u >> 16);
}

__device__ __forceinline__ float bf2f(short x) {
    return __builtin_bit_cast(float, (unsigned)((u16)x) << 16);
}

// packed bf16 pair (truncating) via single v_perm_b32: low16=a.hi, high16=b.hi
__device__ __forceinline__ unsigned pack2bf(float a, float b) {
    return __builtin_amdgcn_perm(__builtin_bit_cast(unsigned, b),
                                 __builtin_bit_cast(unsigned, a), 0x07060302u);
}

// A&S 7.1.26 erf (|err|<=1.5e-7), one v_exp + one v_rcp; exact-gelu drop-in.
__device__ __forceinline__ float fast_gelu(float x) {
    float y  = x * 0.70710678118654752f;
    float ay = __builtin_fabsf(y);
    float t  = __builtin_amdgcn_rcpf(1.0f + 0.3275911f * ay);
    float p  = t * (0.254829592f + t * (-0.284496736f + t * (1.421413741f
               + t * (-1.453152027f + t * 1.061405429f))));
    float e  = __builtin_amdgcn_exp2f(-ay * ay * 1.4426950408889634f);
    float er = 1.0f - p * e;
    er = y < 0.0f ? -er : er;
    return 0.5f * x * (1.0f + er);
}

// ---------------------------------------------------------------------------
// Weight transpose+convert: dst[n][k] = bf16(src[k][n] * scale), per layer z.
// ---------------------------------------------------------------------------
__global__ __launch_bounds__(256) void transpose_w(
    const float* __restrict__ src, u16* __restrict__ dst,
    int K, int N, int srcLS, int dstLS, float scale)
{
    __shared__ float t[32][33];
    src += (size_t)blockIdx.z * srcLS;
    dst += (size_t)blockIdx.z * dstLS;
    const int k0 = blockIdx.y * 32, n0 = blockIdx.x * 32;
    const int r = threadIdx.x >> 3, c4 = (threadIdx.x & 7) * 4;
    const float4 v = *(const float4*)(src + (size_t)(k0 + r) * N + n0 + c4);
    t[r][c4 + 0] = v.x; t[r][c4 + 1] = v.y;
    t[r][c4 + 2] = v.z; t[r][c4 + 3] = v.w;
    __syncthreads();
    bf16x4 o;
#pragma unroll
    for (int i = 0; i < 4; i++) o[i] = (short)f2bf(t[c4 + i][r] * scale);
    *(bf16x4*)(dst + (size_t)(n0 + r) * K + k0 + c4) = o;
}

// Fused QKV bias: [l][768] = [ bq*QSCALE | bk | bv ]
__global__ __launch_bounds__(256) void pack_bias(
    const float* __restrict__ bq, const float* __restrict__ bk,
    const float* __restrict__ bv, float* __restrict__ dst)
{
    int i = blockIdx.x * 256 + threadIdx.x;
    if (i >= N_LAYERSC * QKV_N) return;
    int l = i / QKV_N, j = i % QKV_N;
    float v;
    if (j < 256)      v = bq[l * 256 + j] * QSCALE;
    else if (j < 512) v = bk[l * 256 + j - 256];
    else              v = bv[l * 256 + j - 512];
    dst[i] = v;
}

// ---------------------------------------------------------------------------
// LayerNorm (standalone; used only for layer 0's ln1).
// ---------------------------------------------------------------------------
__global__ __launch_bounds__(256) void ln_kernel(
    const float* __restrict__ X, const float* __restrict__ gamma,
    const float* __restrict__ beta, u16* __restrict__ Y)
{
    const int w = threadIdx.x >> 6, lane = threadIdx.x & 63;
    const int row = blockIdx.x * 4 + w;
    const float4 v = *(const float4*)(X + (size_t)row * 256 + lane * 4);
    float sum = v.x + v.y + v.z + v.w;
    float sq  = v.x * v.x + v.y * v.y + v.z * v.z + v.w * v.w;
#pragma unroll
    for (int off = 32; off > 0; off >>= 1) {
        sum += __shfl_xor(sum, off, 64);
        sq  += __shfl_xor(sq,  off, 64);
    }
    float mu  = sum * (1.0f / 256.0f);
    float var = sq * (1.0f / 256.0f) - mu * mu;
    float rr  = rsqrtf(var + 1e-5f);
    const float4 g  = *(const float4*)(gamma + lane * 4);
    const float4 bb = *(const float4*)(beta + lane * 4);
    bf16x4 o;
    o[0] = (short)f2bf((v.x - mu) * rr * g.x + bb.x);
    o[1] = (short)f2bf((v.y - mu) * rr * g.y + bb.y);
    o[2] = (short)f2bf((v.z - mu) * rr * g.z + bb.z);
    o[3] = (short)f2bf((v.w - mu) * rr * g.w + bb.w);
    *(bf16x4*)(Y + (size_t)row * 256 + lane * 4) = o;
}

// ---------------------------------------------------------------------------
// MFMA GEMM, 128x128 tile, BK=64, register-prefetch double buffering.
// EPI: 0 = bf16 out (+bias); 2 = bf16 gelu(+bias);
//      3 = qkv mode: col<512 -> bf16 to Cout (ld=768); col>=512 -> V written
//          TRANSPOSED to Vout[dim][token].
// ---------------------------------------------------------------------------
template <int EPI>
__global__ __launch_bounds__(256) void mfma_gemm(
    const u16* __restrict__ A, const u16* __restrict__ Bt,
    const float* __restrict__ bias, u16* __restrict__ Vout,
    void* __restrict__ Cout, int N, int K)
{
    __shared__ u16 As[128 * 64];
    __shared__ u16 Bs[128 * 64];
    const int tid = threadIdx.x, w = tid >> 6, lane = tid & 63;
    const int c = lane & 15, quad = lane >> 4;
    const int row0 = blockIdx.y * 128, col0 = blockIdx.x * 128;
    const int wr = w >> 1, wc = w & 1;

    int flv[4], rA[4], colA[4];
#pragma unroll
    for (int ci = 0; ci < 4; ci++) {
        flv[ci]  = (w * 4 + ci) * 1024 + lane * 16;
        rA[ci]   = flv[ci] >> 7;
        colA[ci] = (flv[ci] & 127) >> 1;
    }

    f32x4 acc[4][4] = {};
    bf16x8 pA[4], pB[4];
#pragma unroll
    for (int ci = 0; ci < 4; ci++) {
        pA[ci] = *(const bf16x8*)(A  + (size_t)(row0 + rA[ci]) * K + colA[ci]);
        pB[ci] = *(const bf16x8*)(Bt + (size_t)(col0 + rA[ci]) * K + colA[ci]);
    }

    for (int k0 = 0; k0 < K; k0 += 64) {
        __syncthreads();
#pragma unroll
        for (int ci = 0; ci < 4; ci++) {
            *(bf16x8*)((char*)As + flv[ci]) = pA[ci];
            *(bf16x8*)((char*)Bs + flv[ci]) = pB[ci];
        }
        if (k0 + 64 < K) {
#pragma unroll
            for (int ci = 0; ci < 4; ci++) {
                pA[ci] = *(const bf16x8*)(A  + (size_t)(row0 + rA[ci]) * K + k0 + 64 + colA[ci]);
                pB[ci] = *(const bf16x8*)(Bt + (size_t)(col0 + rA[ci]) * K + k0 + 64 + colA[ci]);
            }
        }
        __syncthreads();
#pragma unroll
        for (int kk = 0; kk < 2; kk++) {
            bf16x8 af[4], bfv[4];
#pragma unroll
            for (int i = 0; i < 4; i++)
                af[i] = *(const bf16x8*)&As[(wr * 64 + i * 16 + c) * 64 + kk * 32 + quad * 8];
#pragma unroll
            for (int j = 0; j < 4; j++)
                bfv[j] = *(const bf16x8*)&Bs[(wc * 64 + j * 16 + c) * 64 + kk * 32 + quad * 8];
#pragma unroll
            for (int i = 0; i < 4; i++)
#pragma unroll
                for (int j = 0; j < 4; j++)
                    acc[i][j] = __builtin_amdgcn_mfma_f32_16x16x32_bf16(
                        af[i], bfv[j], acc[i][j], 0, 0, 0);
        }
    }

    float bj[4];
#pragma unroll
    for (int j = 0; j < 4; j++) bj[j] = bias[col0 + wc * 64 + j * 16 + c];

    if (EPI == 3 && col0 >= 512) {
#pragma unroll
        for (int i = 0; i < 4; i++) {
            const int tok = row0 + wr * 64 + i * 16 + quad * 4;
#pragma unroll
            for (int j = 0; j < 4; j++) {
                const int dim = col0 - 512 + wc * 64 + j * 16 + c;
                bf16x4 o;
#pragma unroll
                for (int r = 0; r < 4; r++) o[r] = (short)f2bf(acc[i][j][r] + bj[j]);
                *(bf16x4*)&Vout[(size_t)dim * M_ROWS + tok] = o;
            }
        }
        return;
    }

#pragma unroll
    for (int i = 0; i < 4; i++) {
#pragma unroll
        for (int r = 0; r < 4; r++) {
            const int gr = row0 + wr * 64 + i * 16 + quad * 4 + r;
#pragma unroll
            for (int j = 0; j < 4; j++) {
                const int gc = col0 + wc * 64 + j * 16 + c;
                float v = acc[i][j][r] + bj[j];
                if (EPI == 2) v = fast_gelu(v);
                ((u16*)Cout)[(size_t)gr * N + gc] = f2bf(v);
            }
        }
    }
}

// ---------------------------------------------------------------------------
// GEMM (N=256, BM=32, BN=256) + residual + optional fused LayerNorm, with
// register-prefetch double buffering.
// ---------------------------------------------------------------------------
template <int DOLN>
__global__ __launch_bounds__(256) void gemm_ln(
    const u16* __restrict__ A, const u16* __restrict__ Bt,
    const float* __restrict__ bias, const float* __restrict__ resid,
    float* __restrict__ Xout, const float* __restrict__ gamma,
    const float* __restrict__ beta, u16* __restrict__ Nout, int K)
{
    __shared__ u16 As[32 * 64];
    __shared__ u16 Bs[256 * 64];
    __shared__ float2 red[4][32];
    const int tid = threadIdx.x, w = tid >> 6, lane = tid & 63;
    const int c = lane & 15, quad = lane >> 4;
    const int row0 = blockIdx.x * 32;

    const int flA  = w * 1024 + lane * 16;
    const int rAa  = flA >> 7, colAa = (flA & 127) >> 1;
    int flB[8], rB[8], colB[8];
#pragma unroll
    for (int ci = 0; ci < 8; ci++) {
        flB[ci]  = (w * 8 + ci) * 1024 + lane * 16;
        rB[ci]   = flB[ci] >> 7;
        colB[ci] = (flB[ci] & 127) >> 1;
    }

    f32x4 acc[2][4] = {};
    bf16x8 pA = *(const bf16x8*)(A + (size_t)(row0 + rAa) * K + colAa);
    bf16x8 pB[8];
#pragma unroll
    for (int ci = 0; ci < 8; ci++)
        pB[ci] = *(const bf16x8*)(Bt + (size_t)rB[ci] * K + colB[ci]);

    for (int k0 = 0; k0 < K; k0 += 64) {
        __syncthreads();
        *(bf16x8*)((char*)As + flA) = pA;
#pragma unroll
        for (int ci = 0; ci < 8; ci++)
            *(bf16x8*)((char*)Bs + flB[ci]) = pB[ci];
        if (k0 + 64 < K) {
            pA = *(const bf16x8*)(A + (size_t)(row0 + rAa) * K + k0 + 64 + colAa);
#pragma unroll
            for (int ci = 0; ci < 8; ci++)
                pB[ci] = *(const bf16x8*)(Bt + (size_t)rB[ci] * K + k0 + 64 + colB[ci]);
        }
        __syncthreads();
#pragma unroll
        for (int kk = 0; kk < 2; kk++) {
            bf16x8 af[2], bfv[4];
#pragma unroll
            for (int i = 0; i < 2; i++)
                af[i] = *(const bf16x8*)&As[(i * 16 + c) * 64 + kk * 32 + quad * 8];
#pragma unroll
            for (int j = 0; j < 4; j++)
                bfv[j] = *(const bf16x8*)&Bs[(w * 64 + j * 16 + c) * 64 + kk * 32 + quad * 8];
#pragma unroll
            for (int i = 0; i < 2; i++)
#pragma unroll
                for (int j = 0; j < 4; j++)
                    acc[i][j] = __builtin_amdgcn_mfma_f32_16x16x32_bf16(
                        af[i], bfv[j], acc[i][j], 0, 0, 0);
        }
    }

    float bj[4];
#pragma unroll
    for (int j = 0; j < 4; j++) bj[j] = bias[w * 64 + j * 16 + c];
    float xv[2][4][4];
#pragma unroll
    for (int i = 0; i < 2; i++)
#pragma unroll
        for (int r = 0; r < 4; r++) {
            const int gr = row0 + i * 16 + quad * 4 + r;
#pragma unroll
            for (int j = 0; j < 4; j++) {
                const int gc = w * 64 + j * 16 + c;
                xv[i][j][r] = acc[i][j][r] + bj[j] + resid[(size_t)gr * 256 + gc];
            }
        }

    if (DOLN) {
        float sm[2][4], sp[2][4];
#pragma unroll
        for (int i = 0; i < 2; i++)
#pragma unroll
            for (int r = 0; r < 4; r++) {
                float s = 0.f, q = 0.f;
#pragma unroll
                for (int j = 0; j < 4; j++) { s += xv[i][j][r]; q += xv[i][j][r] * xv[i][j][r]; }
                sm[i][r] = s; sp[i][r] = q;
            }
#pragma unroll
        for (int off = 1; off < 16; off <<= 1)
#pragma unroll
            for (int i = 0; i < 2; i++)
#pragma unroll
                for (int r = 0; r < 4; r++) {
                    sm[i][r] += __shfl_xor(sm[i][r], off, 64);
                    sp[i][r] += __shfl_xor(sp[i][r], off, 64);
                }
        __syncthreads();
        if (c == 0) {
#pragma unroll
            for (int i = 0; i < 2; i++)
#pragma unroll
                for (int r = 0; r < 4; r++)
                    red[w][i * 16 + quad * 4 + r] = make_float2(sm[i][r], sp[i][r]);
        }
        __syncthreads();
#pragma unroll
        for (int i = 0; i < 2; i++)
#pragma unroll
            for (int r = 0; r < 4; r++) {
                const int row = i * 16 + quad * 4 + r;
                float2 t0 = red[0][row], t1 = red[1][row];
                float2 t2 = red[2][row], t3 = red[3][row];
                float S = (t0.x + t1.x) + (t2.x + t3.x);
                float Q = (t0.y + t1.y) + (t2.y + t3.y);
                float mu = S * (1.0f / 256.0f);
                float var = Q * (1.0f / 256.0f) - mu * mu;
                float rr = rsqrtf(var + 1e-5f);
                const int gr = row0 + row;
#pragma unroll
                for (int j = 0; j < 4; j++) {
                    const int gc = w * 64 + j * 16 + c;
                    float x = xv[i][j][r];
                    Xout[(size_t)gr * 256 + gc] = x;
                    Nout[(size_t)gr * 256 + gc] =
                        f2bf((x - mu) * rr * gamma[gc] + beta[gc]);
                }
            }
    } else {
#pragma unroll
        for (int i = 0; i < 2; i++)
#pragma unroll
            for (int r = 0; r < 4; r++) {
                const int gr = row0 + i * 16 + quad * 4 + r;
#pragma unroll
                for (int j = 0; j < 4; j++)
                    Xout[(size_t)gr * 256 + w * 64 + j * 16 + c] = xv[i][j][r];
            }
    }
}

// ---------------------------------------------------------------------------
// MFMA flash attention v7: EXCHANGE-FREE PV via virtual-k composite.
// For a 32-key chunk (S^T tiles g0,g1): virtual k = quad*8+j with j=0..3 ->
// g0 keys quad*4+r, j=4..7 -> g1 keys quad*4+r. Then A-frag for PV is this
// lane's own exp(S^T) C-output pairs concatenated -> ZERO cross-lane ops.
// V staged in matching B-frag granule order (lane-linear b128 reads).
// l computed by MFMA against ones-B (lands in C layout, row=query).
// 128q blocks (32q/wave, amortized reads), key-split x2, reg-prefetch,
// 128-key supertiles, raw v_exp.
// ---------------------------------------------------------------------------
__global__ __launch_bounds__(256) void attn_kernel(
    const u16* __restrict__ QKV, const u16* __restrict__ VT,
    u16* __restrict__ POa, u16* __restrict__ POb, float* __restrict__ Lp)
{
    const int h = blockIdx.y, b = blockIdx.z;
    const int half = blockIdx.x & 1;
    const int q0 = (blockIdx.x >> 1) * 128;
    const int tid = threadIdx.x, w = tid >> 6, lane = tid & 63;
    const int c = lane & 15, quad = lane >> 4;

    __shared__ u16 Kf[4096];   // two 64-key tiles, fragment order g*512+lane*8
    __shared__ u16 Vf[4096];   // two 64-key tiles, PV B-frag granule order

    const u16* qp = QKV + (size_t)(b * T_SEQ + q0 + w * 32 + c) * QKV_N + h * 32 + quad * 8;
    bf16x8 aQ0 = *(const bf16x8*)qp;                 // queries qg0: n=c
    bf16x8 aQ1 = *(const bf16x8*)(qp + 16 * QKV_N);  // queries qg1

    const bf16x8 bOnes = {0x3F80, 0x3F80, 0x3F80, 0x3F80,
                          0x3F80, 0x3F80, 0x3F80, 0x3F80};  // bf16 1.0

    f32x4 O[2][2] = {};                              // [qg][dim half]
    f32x4 Ol0 = {0.f, 0.f, 0.f, 0.f}, Ol1 = {0.f, 0.f, 0.f, 0.f};

    const u16* kgp = QKV + (size_t)(b * T_SEQ + w * 16 + c) * QKV_N + 256 + h * 32 + quad * 8;
    const u16* vgp = VT + ((size_t)h * 32 + (lane & 31)) * M_ROWS + b * T_SEQ
                     + (w * 2 + (lane >> 5)) * 8;
    u16* kfw = Kf + w * 512 + lane * 8;

    // V staging dest: granule(kh,dh,quad,c) = ((kh*2+dh)*4+quad)*16+c (16B),
    // this thread's 16B global load = dims d=lane&31, tokens t0..t0+7 ->
    // two b64 halves at quads 2*hi, 2*hi+1, seg half = w&1, kh = w>>1.
    const int vd  = lane & 31, vdh = vd >> 4, vc = vd & 15, vhi = lane >> 5;
    const int vkh = w >> 1, vseg = w & 1;
    const int voff = ((((vkh * 2 + vdh) * 4 + 2 * vhi) * 16 + vc) * 8) + vseg * 4;

    const int kbeg = half * (T_SEQ / 2);
    const int kend = kbeg + T_SEQ / 2;

    bf16x8 gK0 = *(const bf16x8*)(kgp + (size_t)kbeg * QKV_N);
    bf16x8 gK1 = *(const bf16x8*)(kgp + (size_t)(kbeg + 64) * QKV_N);
    bf16x8 gV0 = *(const bf16x8*)(vgp + kbeg);
    bf16x8 gV1 = *(const bf16x8*)(vgp + kbeg + 64);

    for (int k0 = kbeg; k0 < kend; k0 += 128) {
        __syncthreads();
        *(bf16x8*)kfw          = gK0;
        *(bf16x8*)(kfw + 2048) = gK1;
        {
            bf16x4 l0v = __builtin_shufflevector(gV0, gV0, 0, 1, 2, 3);
            bf16x4 h0v = __builtin_shufflevector(gV0, gV0, 4, 5, 6, 7);
            bf16x4 l1v = __builtin_shufflevector(gV1, gV1, 0, 1, 2, 3);
            bf16x4 h1v = __builtin_shufflevector(gV1, gV1, 4, 5, 6, 7);
            *(bf16x4*)&Vf[voff]              = l0v;
            *(bf16x4*)&Vf[voff + 128]        = h0v;
            *(bf16x4*)&Vf[2048 + voff]       = l1v;
            *(bf16x4*)&Vf[2048 + voff + 128] = h1v;
        }
        if (k0 + 128 < kend) {
            gK0 = *(const bf16x8*)(kgp + (size_t)(k0 + 128) * QKV_N);
            gK1 = *(const bf16x8*)(kgp + (size_t)(k0 + 192) * QKV_N);
            gV0 = *(const bf16x8*)(vgp + k0 + 128);
            gV1 = *(const bf16x8*)(vgp + k0 + 192);
        }
        __syncthreads();

#pragma unroll
        for (int hf = 0; hf < 2; hf++) {
            const u16* Kb = Kf + hf * 2048;
            const u16* Vb = Vf + hf * 2048;

            unsigned pk0[4][2], pk1[4][2];
#pragma unroll
            for (int g = 0; g < 4; g++) {
                bf16x8 aK = *(const bf16x8*)&Kb[g * 512 + lane * 8];
                f32x4 S0 = __builtin_amdgcn_mfma_f32_16x16x32_bf16(
                    aK, aQ0, (f32x4){0.f, 0.f, 0.f, 0.f}, 0, 0, 0);
                f32x4 S1 = __builtin_amdgcn_mfma_f32_16x16x32_bf16(
                    aK, aQ1, (f32x4){0.f, 0.f, 0.f, 0.f}, 0, 0, 0);
                pk0[g][0] = pack2bf(__builtin_amdgcn_exp2f(S0[0]),
                                    __builtin_amdgcn_exp2f(S0[1]));
                pk0[g][1] = pack2bf(__builtin_amdgcn_exp2f(S0[2]),
                                    __builtin_amdgcn_exp2f(S0[3]));
                pk1[g][0] = pack2bf(__builtin_amdgcn_exp2f(S1[0]),
                                    __builtin_amdgcn_exp2f(S1[1]));
                pk1[g][1] = pack2bf(__builtin_amdgcn_exp2f(S1[2]),
                                    __builtin_amdgcn_exp2f(S1[3]));
            }

#pragma unroll
            for (int kh = 0; kh < 2; kh++) {
                bf16x8 aP0 = __builtin_bit_cast(bf16x8,
                    (u32x4){pk0[2 * kh][0], pk0[2 * kh][1],
                            pk0[2 * kh + 1][0], pk0[2 * kh + 1][1]});
                bf16x8 aP1 = __builtin_bit_cast(bf16x8,
                    (u32x4){pk1[2 * kh][0], pk1[2 * kh][1],
                            pk1[2 * kh + 1][0], pk1[2 * kh + 1][1]});
                Ol0 = __builtin_amdgcn_mfma_f32_16x16x32_bf16(aP0, bOnes, Ol0, 0, 0, 0);
                Ol1 = __builtin_amdgcn_mfma_f32_16x16x32_bf16(aP1, bOnes, Ol1, 0, 0, 0);
#pragma unroll
                for (int dh = 0; dh < 2; dh++) {
                    bf16x8 bV = *(const bf16x8*)&Vb[((kh * 2 + dh) * 64 + lane) * 8];
                    O[0][dh] = __builtin_amdgcn_mfma_f32_16x16x32_bf16(aP0, bV, O[0][dh], 0, 0, 0);
                    O[1][dh] = __builtin_amdgcn_mfma_f32_16x16x32_bf16(aP1, bV, O[1][dh], 0, 0, 0);
                }
            }
        }
    }

    // O rows: query = qg*16 + quad*4 + r, col = dim dh*16 + c. Ol likewise.
    u16* pb = (half ? POb : POa)
              + (size_t)(b * T_SEQ + q0 + w * 32) * 256 + h * 32;
    if (c == 0) {
        float* lb = Lp + (size_t)half * M_ROWS * 8
                    + (size_t)(b * T_SEQ + q0 + w * 32) * 8 + h;
#pragma unroll
        for (int r = 0; r < 4; r++) {
            lb[(size_t)(quad * 4 + r) * 8]      = Ol0[r];
            lb[(size_t)(16 + quad * 4 + r) * 8] = Ol1[r];
        }
    }
#pragma unroll
    for (int r = 0; r < 4; r++) {
        int src = quad * 4 + r;
        pb[(size_t)src * 256 + c]             = f2bf(O[0][0][r]);
        pb[(size_t)src * 256 + 16 + c]        = f2bf(O[0][1][r]);
        pb[(size_t)(16 + src) * 256 + c]      = f2bf(O[1][0][r]);
        pb[(size_t)(16 + src) * 256 + 16 + c] = f2bf(O[1][1][r]);
    }
}

// ---------------------------------------------------------------------------
// Merge the two key-halves: Ob = (POa + POb) / (la + lb). Wave per row.
// ---------------------------------------------------------------------------
__global__ __launch_bounds__(256) void attn_merge(
    const u16* __restrict__ POa, const u16* __restrict__ POb,
    const float* __restrict__ Lp, u16* __restrict__ Ob)
{
    const int w = threadIdx.x >> 6, lane = threadIdx.x & 63;
    const int row = blockIdx.x * 4 + w;
    const int head = lane >> 3;
    const float la = Lp[(size_t)row * 8 + head];
    const float lb = Lp[(size_t)M_ROWS * 8 + (size_t)row * 8 + head];
    const float inv = 1.0f / (la + lb);
    bf16x4 a = *(const bf16x4*)&POa[(size_t)row * 256 + lane * 4];
    bf16x4 b = *(const bf16x4*)&POb[(size_t)row * 256 + lane * 4];
    bf16x4 o;
#pragma unroll
    for (int i = 0; i < 4; i++) o[i] = (short)f2bf((bf2f(a[i]) + bf2f(b[i])) * inv);
    *(bf16x4*)&Ob[(size_t)row * 256 + lane * 4] = o;
}

// ---------------------------------------------------------------------------
extern "C" void kernel_launch(void* const* d_in, const int* in_sizes, int n_in,
                              void* d_out, int out_size, void* d_ws, size_t ws_size,
                              hipStream_t stream)
{
    const float* x     = (const float*)d_in[0];
    const float* ln1_s = (const float*)d_in[1];
    const float* ln1_b = (const float*)d_in[2];
    const float* wq    = (const float*)d_in[3];
    const float* bq    = (const float*)d_in[4];
    const float* wk    = (const float*)d_in[5];
    const float* bk    = (const float*)d_in[6];
    const float* wv    = (const float*)d_in[7];
    const float* bv    = (const float*)d_in[8];
    const float* wo    = (const float*)d_in[9];
    const float* bo    = (const float*)d_in[10];
    const float* ln2_s = (const float*)d_in[11];
    const float* ln2_b = (const float*)d_in[12];
    const float* w1    = (const float*)d_in[13];
    const float* b1    = (const float*)d_in[14];
    const float* w2    = (const float*)d_in[15];
    const float* b2    = (const float*)d_in[16];

    float* X = (float*)d_out;                   // fp32 residual stream

    u16* normed = (u16*)d_ws;                               // 8192*256
    u16* qkv    = normed + (size_t)M_ROWS * 256;            // 8192*768 (V third unused)
    u16* POa    = qkv + (size_t)M_ROWS * QKV_N;             // 8192*256
    u16* h1     = qkv;   // spans qkv+POa: 8192*1024
    u16* wqkv_t = POa + (size_t)M_ROWS * 256;               // 6*768*256
    u16* wo_t   = wqkv_t + (size_t)N_LAYERSC * QKV_N * 256; // 6*256*256
    u16* w1_t   = wo_t + (size_t)N_LAYERSC * 256 * 256;     // 6*1024*256
    u16* w2_t   = w1_t + (size_t)N_LAYERSC * D_FFC * 256;   // 6*256*1024
    float* qkvb = (float*)(w2_t + (size_t)N_LAYERSC * 256 * D_FFC); // 6*768 fp32
    u16* VTb    = (u16*)(qkvb + N_LAYERSC * QKV_N);         // 256*8192
    u16* POb    = VTb + (size_t)256 * M_ROWS;               // 8192*256
    float* Lp   = (float*)(POb + (size_t)M_ROWS * 256);     // 2*8192*8 fp32

    dim3 blk(256);

    // ---- weight prep (every call; graph-safe)
    transpose_w<<<dim3(8, 8, 6),  blk, 0, stream>>>(wq, wqkv_t,             256, 256, 65536, QKV_N * 256, QSCALE);
    transpose_w<<<dim3(8, 8, 6),  blk, 0, stream>>>(wk, wqkv_t + 256 * 256, 256, 256, 65536, QKV_N * 256, 1.0f);
    transpose_w<<<dim3(8, 8, 6),  blk, 0, stream>>>(wv, wqkv_t + 512 * 256, 256, 256, 65536, QKV_N * 256, 1.0f);
    transpose_w<<<dim3(8, 8, 6),  blk, 0, stream>>>(wo, wo_t,               256, 256, 65536, 65536, 1.0f);
    transpose_w<<<dim3(32, 8, 6), blk, 0, stream>>>(w1, w1_t,               256, D_FFC, 256 * D_FFC, 256 * D_FFC, 1.0f);
    transpose_w<<<dim3(8, 32, 6), blk, 0, stream>>>(w2, w2_t,               D_FFC, 256, 256 * D_FFC, 256 * D_FFC, 1.0f);
    pack_bias<<<dim3(18), blk, 0, stream>>>(bq, bk, bv, qkvb);

    hipMemcpyAsync(X, x, (size_t)M_ROWS * 256 * sizeof(float),
                   hipMemcpyDeviceToDevice, stream);

    dim3 g_qkv(QKV_N / 128, M_ROWS / 128);          // (6,64)
    dim3 g_ff(D_FFC / 128, M_ROWS / 128);           // (8,64)
    dim3 g_ln32(M_ROWS / 32);                       // 256 blocks
    dim3 g_attn(2 * T_SEQ / 128, N_HEADSC, B_SZ);   // (32,8,4) = 1024 blocks
    dim3 g_mrg(M_ROWS / 4);

    ln_kernel<<<dim3(M_ROWS / 4), blk, 0, stream>>>(X, ln1_s, ln1_b, normed);

    for (int l = 0; l < N_LAYERSC; l++) {
        mfma_gemm<3><<<g_qkv, blk, 0, stream>>>(
            normed, wqkv_t + (size_t)l * QKV_N * 256, qkvb + l * QKV_N,
            VTb, qkv, QKV_N, 256);
        attn_kernel<<<g_attn, blk, 0, stream>>>(qkv, VTb, POa, POb, Lp);
        attn_merge<<<g_mrg, blk, 0, stream>>>(POa, POb, Lp, normed);
        gemm_ln<1><<<g_ln32, blk, 0, stream>>>(
            normed, wo_t + (size_t)l * 256 * 256, bo + l * 256, X,
            X, ln2_s + l * 256, ln2_b + l * 256, VTb, 256);
        mfma_gemm<2><<<g_ff, blk, 0, stream>>>(
            VTb, w1_t + (size_t)l * D_FFC * 256, b1 + l * D_FFC,
            nullptr, h1, D_FFC, 256);
        if (l + 1 < N_LAYERSC) {
            gemm_ln<1><<<g_ln32, blk, 0, stream>>>(
                h1, w2_t + (size_t)l * 256 * D_FFC, b2 + l * 256, X,
                X, ln1_s + (l + 1) * 256, ln1_b + (l + 1) * 256, normed, D_FFC);
        } else {
            gemm_ln<0><<<g_ln32, blk, 0, stream>>>(
                h1, w2_t + (size_t)l * 256 * D_FFC, b2 + l * 256, X,
                X, nullptr, nullptr, nullptr, D_FFC);
        }
    }
}

// Round 13
// 617.060 us; speedup vs baseline: 1.5668x; 1.0593x over previous
//
#include <hip/hip_runtime.h>
#include <math.h>

#define D_MODELC 256
#define N_LAYERSC 6
#define N_HEADSC 8
#define D_FFC 1024
#define HEAD_DIMC 32
#define B_SZ 4
#define T_SEQ 2048
#define M_ROWS 8192
#define QKV_N 768

typedef short bf16x8 __attribute__((ext_vector_type(8)));
typedef short bf16x4 __attribute__((ext_vector_type(4)));
typedef float f32x4  __attribute__((ext_vector_type(4)));
typedef unsigned u32x4 __attribute__((ext_vector_type(4)));
typedef unsigned short u16;

// scale(1/sqrt(32)) * log2(e) folded into wq at conversion time
#define QSCALE 0.25503488f

__device__ __forceinline__ u16 f2bf(float x) {
    unsigned u = __builtin_bit_cast(unsigned, x);
    u += 0x7FFF + ((u >> 16) & 1);          // round-to-nearest-even
    return (u16)(u >> 16);
}

__device__ __forceinline__ float bf2f(short x) {
    return __builtin_bit_cast(float, (unsigned)((u16)x) << 16);
}

// packed bf16 pair (truncating) via single v_perm_b32: low16=a.hi, high16=b.hi
__device__ __forceinline__ unsigned pack2bf(float a, float b) {
    return __builtin_amdgcn_perm(__builtin_bit_cast(unsigned, b),
                                 __builtin_bit_cast(unsigned, a), 0x07060302u);
}

// A&S 7.1.26 erf (|err|<=1.5e-7), one v_exp + one v_rcp; exact-gelu drop-in.
__device__ __forceinline__ float fast_gelu(float x) {
    float y  = x * 0.70710678118654752f;
    float ay = __builtin_fabsf(y);
    float t  = __builtin_amdgcn_rcpf(1.0f + 0.3275911f * ay);
    float p  = t * (0.254829592f + t * (-0.284496736f + t * (1.421413741f
               + t * (-1.453152027f + t * 1.061405429f))));
    float e  = __builtin_amdgcn_exp2f(-ay * ay * 1.4426950408889634f);
    float er = 1.0f - p * e;
    er = y < 0.0f ? -er : er;
    return 0.5f * x * (1.0f + er);
}

// ---------------------------------------------------------------------------
// prep_all: ALL weight prep in ONE dispatch. Block-index ranges:
// [0,1152) wq/wk/wv -> wqkv_t, [1152,1536) wo, [1536,3072) w1,
// [3072,4608) w2, [4608,4626) fused qkv bias. Branches are block-uniform.
// ---------------------------------------------------------------------------
__device__ __forceinline__ void transpose_tile(
    const float* __restrict__ src, u16* __restrict__ dst,
    int K, int N, int k0, int n0, float scale, float (*ts)[33])
{
    const int r = threadIdx.x >> 3, c4 = (threadIdx.x & 7) * 4;
    const float4 v = *(const float4*)(src + (size_t)(k0 + r) * N + n0 + c4);
    ts[r][c4 + 0] = v.x; ts[r][c4 + 1] = v.y;
    ts[r][c4 + 2] = v.z; ts[r][c4 + 3] = v.w;
    __syncthreads();
    bf16x4 o;
#pragma unroll
    for (int i = 0; i < 4; i++) o[i] = (short)f2bf(ts[c4 + i][r] * scale);
    *(bf16x4*)(dst + (size_t)(n0 + r) * K + k0 + c4) = o;
}

__global__ __launch_bounds__(256) void prep_all(
    const float* __restrict__ wq, const float* __restrict__ wk,
    const float* __restrict__ wv, const float* __restrict__ wo,
    const float* __restrict__ w1, const float* __restrict__ w2,
    const float* __restrict__ bq, const float* __restrict__ bk,
    const float* __restrict__ bv,
    u16* __restrict__ wqkv_t, u16* __restrict__ wo_t,
    u16* __restrict__ w1_t, u16* __restrict__ w2_t,
    float* __restrict__ qkvb)
{
    __shared__ float ts[32][33];
    const int bid = blockIdx.x;
    if (bid < 1152) {                 // wq/wk/wv: 3 x 6 x 64 tiles
        const int sec = bid / 384, t = bid % 384;
        const int z = t >> 6, rem = t & 63, ty = rem >> 3, tx = rem & 7;
        const float* src = sec == 0 ? wq : (sec == 1 ? wk : wv);
        transpose_tile(src + (size_t)z * 65536,
                       wqkv_t + (size_t)z * QKV_N * 256 + sec * 256 * 256,
                       256, 256, ty * 32, tx * 32,
                       sec == 0 ? QSCALE : 1.0f, ts);
    } else if (bid < 1536) {          // wo
        const int t = bid - 1152;
        const int z = t >> 6, rem = t & 63, ty = rem >> 3, tx = rem & 7;
        transpose_tile(wo + (size_t)z * 65536, wo_t + (size_t)z * 65536,
                       256, 256, ty * 32, tx * 32, 1.0f, ts);
    } else if (bid < 3072) {          // w1: K=256, N=1024, 6 x 256 tiles
        const int t = bid - 1536;
        const int z = t >> 8, rem = t & 255, ty = rem >> 5, tx = rem & 31;
        transpose_tile(w1 + (size_t)z * 262144, w1_t + (size_t)z * 262144,
                       256, D_FFC, ty * 32, tx * 32, 1.0f, ts);
    } else if (bid < 4608) {          // w2: K=1024, N=256
        const int t = bid - 3072;
        const int z = t >> 8, rem = t & 255, ty = rem >> 3, tx = rem & 7;
        transpose_tile(w2 + (size_t)z * 262144, w2_t + (size_t)z * 262144,
                       D_FFC, 256, ty * 32, tx * 32, 1.0f, ts);
    } else {                          // fused qkv bias
        const int i = (bid - 4608) * 256 + threadIdx.x;
        const int l = i / QKV_N, j = i % QKV_N;
        float v;
        if (j < 256)      v = bq[l * 256 + j] * QSCALE;
        else if (j < 512) v = bk[l * 256 + j - 256];
        else              v = bv[l * 256 + j - 512];
        qkvb[i] = v;
    }
}

// ---------------------------------------------------------------------------
// ln0 + residual-stream init in one pass: X = x; Y = bf16(LN(x)).
// ---------------------------------------------------------------------------
__global__ __launch_bounds__(256) void ln_copy(
    const float* __restrict__ x, const float* __restrict__ gamma,
    const float* __restrict__ beta, float* __restrict__ X,
    u16* __restrict__ Y)
{
    const int w = threadIdx.x >> 6, lane = threadIdx.x & 63;
    const int row = blockIdx.x * 4 + w;
    const float4 v = *(const float4*)(x + (size_t)row * 256 + lane * 4);
    *(float4*)(X + (size_t)row * 256 + lane * 4) = v;
    float sum = v.x + v.y + v.z + v.w;
    float sq  = v.x * v.x + v.y * v.y + v.z * v.z + v.w * v.w;
#pragma unroll
    for (int off = 32; off > 0; off >>= 1) {
        sum += __shfl_xor(sum, off, 64);
        sq  += __shfl_xor(sq,  off, 64);
    }
    float mu  = sum * (1.0f / 256.0f);
    float var = sq * (1.0f / 256.0f) - mu * mu;
    float rr  = rsqrtf(var + 1e-5f);
    const float4 g  = *(const float4*)(gamma + lane * 4);
    const float4 bb = *(const float4*)(beta + lane * 4);
    bf16x4 o;
    o[0] = (short)f2bf((v.x - mu) * rr * g.x + bb.x);
    o[1] = (short)f2bf((v.y - mu) * rr * g.y + bb.y);
    o[2] = (short)f2bf((v.z - mu) * rr * g.z + bb.z);
    o[3] = (short)f2bf((v.w - mu) * rr * g.w + bb.w);
    *(bf16x4*)(Y + (size_t)row * 256 + lane * 4) = o;
}

// ---------------------------------------------------------------------------
// MFMA GEMM, 128x128 tile, BK=64, register-prefetch double buffering.
// EPI: 0 = bf16 out (+bias); 2 = bf16 gelu(+bias);
//      3 = qkv mode: col<512 -> bf16 to Cout (ld=768); col>=512 -> V written
//          TRANSPOSED to Vout[dim][token].
// ---------------------------------------------------------------------------
template <int EPI>
__global__ __launch_bounds__(256) void mfma_gemm(
    const u16* __restrict__ A, const u16* __restrict__ Bt,
    const float* __restrict__ bias, u16* __restrict__ Vout,
    void* __restrict__ Cout, int N, int K)
{
    __shared__ u16 As[128 * 64];
    __shared__ u16 Bs[128 * 64];
    const int tid = threadIdx.x, w = tid >> 6, lane = tid & 63;
    const int c = lane & 15, quad = lane >> 4;
    const int row0 = blockIdx.y * 128, col0 = blockIdx.x * 128;
    const int wr = w >> 1, wc = w & 1;

    int flv[4], rA[4], colA[4];
#pragma unroll
    for (int ci = 0; ci < 4; ci++) {
        flv[ci]  = (w * 4 + ci) * 1024 + lane * 16;
        rA[ci]   = flv[ci] >> 7;
        colA[ci] = (flv[ci] & 127) >> 1;
    }

    f32x4 acc[4][4] = {};
    bf16x8 pA[4], pB[4];
#pragma unroll
    for (int ci = 0; ci < 4; ci++) {
        pA[ci] = *(const bf16x8*)(A  + (size_t)(row0 + rA[ci]) * K + colA[ci]);
        pB[ci] = *(const bf16x8*)(Bt + (size_t)(col0 + rA[ci]) * K + colA[ci]);
    }

    for (int k0 = 0; k0 < K; k0 += 64) {
        __syncthreads();
#pragma unroll
        for (int ci = 0; ci < 4; ci++) {
            *(bf16x8*)((char*)As + flv[ci]) = pA[ci];
            *(bf16x8*)((char*)Bs + flv[ci]) = pB[ci];
        }
        if (k0 + 64 < K) {
#pragma unroll
            for (int ci = 0; ci < 4; ci++) {
                pA[ci] = *(const bf16x8*)(A  + (size_t)(row0 + rA[ci]) * K + k0 + 64 + colA[ci]);
                pB[ci] = *(const bf16x8*)(Bt + (size_t)(col0 + rA[ci]) * K + k0 + 64 + colA[ci]);
            }
        }
        __syncthreads();
#pragma unroll
        for (int kk = 0; kk < 2; kk++) {
            bf16x8 af[4], bfv[4];
#pragma unroll
            for (int i = 0; i < 4; i++)
                af[i] = *(const bf16x8*)&As[(wr * 64 + i * 16 + c) * 64 + kk * 32 + quad * 8];
#pragma unroll
            for (int j = 0; j < 4; j++)
                bfv[j] = *(const bf16x8*)&Bs[(wc * 64 + j * 16 + c) * 64 + kk * 32 + quad * 8];
#pragma unroll
            for (int i = 0; i < 4; i++)
#pragma unroll
                for (int j = 0; j < 4; j++)
                    acc[i][j] = __builtin_amdgcn_mfma_f32_16x16x32_bf16(
                        af[i], bfv[j], acc[i][j], 0, 0, 0);
        }
    }

    float bj[4];
#pragma unroll
    for (int j = 0; j < 4; j++) bj[j] = bias[col0 + wc * 64 + j * 16 + c];

    if (EPI == 3 && col0 >= 512) {
#pragma unroll
        for (int i = 0; i < 4; i++) {
            const int tok = row0 + wr * 64 + i * 16 + quad * 4;
#pragma unroll
            for (int j = 0; j < 4; j++) {
                const int dim = col0 - 512 + wc * 64 + j * 16 + c;
                bf16x4 o;
#pragma unroll
                for (int r = 0; r < 4; r++) o[r] = (short)f2bf(acc[i][j][r] + bj[j]);
                *(bf16x4*)&Vout[(size_t)dim * M_ROWS + tok] = o;
            }
        }
        return;
    }

#pragma unroll
    for (int i = 0; i < 4; i++) {
#pragma unroll
        for (int r = 0; r < 4; r++) {
            const int gr = row0 + wr * 64 + i * 16 + quad * 4 + r;
#pragma unroll
            for (int j = 0; j < 4; j++) {
                const int gc = col0 + wc * 64 + j * 16 + c;
                float v = acc[i][j][r] + bj[j];
                if (EPI == 2) v = fast_gelu(v);
                ((u16*)Cout)[(size_t)gr * N + gc] = f2bf(v);
            }
        }
    }
}

// ---------------------------------------------------------------------------
// GEMM (N=256, BM=32, BN=256) + residual + optional fused LayerNorm.
// MERGE=1: A is the attention partials pair (POa=A, POb=Ab, Lp=Lmrg) and the
// key-half merge (a+b)*rcp(la+lb) happens inline during A staging -> the
// standalone attn_merge kernel disappears.
// ---------------------------------------------------------------------------
template <int DOLN, int MERGE>
__global__ __launch_bounds__(256) void gemm_ln(
    const u16* __restrict__ A, const u16* __restrict__ Ab,
    const float* __restrict__ Lmrg,
    const u16* __restrict__ Bt, const float* __restrict__ bias,
    const float* __restrict__ resid, float* __restrict__ Xout,
    const float* __restrict__ gamma, const float* __restrict__ beta,
    u16* __restrict__ Nout, int K)
{
    __shared__ u16 As[32 * 64];
    __shared__ u16 Bs[256 * 64];
    __shared__ float2 red[4][32];
    const int tid = threadIdx.x, w = tid >> 6, lane = tid & 63;
    const int c = lane & 15, quad = lane >> 4;
    const int row0 = blockIdx.x * 32;

    const int flA  = w * 1024 + lane * 16;
    const int rAa  = flA >> 7, colAa = (flA & 127) >> 1;
    int flB[8], rB[8], colB[8];
#pragma unroll
    for (int ci = 0; ci < 8; ci++) {
        flB[ci]  = (w * 8 + ci) * 1024 + lane * 16;
        rB[ci]   = flB[ci] >> 7;
        colB[ci] = (flB[ci] & 127) >> 1;
    }

    f32x4 acc[2][4] = {};

    auto loadA = [&](int gc) -> bf16x8 {
        const int row = row0 + rAa;
        if (MERGE) {
            const int head = gc >> 5;
            const float la = Lmrg[(size_t)row * 8 + head];
            const float lb = Lmrg[(size_t)M_ROWS * 8 + (size_t)row * 8 + head];
            const float inv = __builtin_amdgcn_rcpf(la + lb);
            bf16x8 a = *(const bf16x8*)(A  + (size_t)row * 256 + gc);
            bf16x8 b = *(const bf16x8*)(Ab + (size_t)row * 256 + gc);
            bf16x8 o;
#pragma unroll
            for (int j = 0; j < 8; j++)
                o[j] = (short)f2bf((bf2f(a[j]) + bf2f(b[j])) * inv);
            return o;
        }
        return *(const bf16x8*)(A + (size_t)row * K + gc);
    };

    bf16x8 pA = loadA(colAa);
    bf16x8 pB[8];
#pragma unroll
    for (int ci = 0; ci < 8; ci++)
        pB[ci] = *(const bf16x8*)(Bt + (size_t)rB[ci] * K + colB[ci]);

    for (int k0 = 0; k0 < K; k0 += 64) {
        __syncthreads();
        *(bf16x8*)((char*)As + flA) = pA;
#pragma unroll
        for (int ci = 0; ci < 8; ci++)
            *(bf16x8*)((char*)Bs + flB[ci]) = pB[ci];
        if (k0 + 64 < K) {
            pA = loadA(k0 + 64 + colAa);
#pragma unroll
            for (int ci = 0; ci < 8; ci++)
                pB[ci] = *(const bf16x8*)(Bt + (size_t)rB[ci] * K + k0 + 64 + colB[ci]);
        }
        __syncthreads();
#pragma unroll
        for (int kk = 0; kk < 2; kk++) {
            bf16x8 af[2], bfv[4];
#pragma unroll
            for (int i = 0; i < 2; i++)
                af[i] = *(const bf16x8*)&As[(i * 16 + c) * 64 + kk * 32 + quad * 8];
#pragma unroll
            for (int j = 0; j < 4; j++)
                bfv[j] = *(const bf16x8*)&Bs[(w * 64 + j * 16 + c) * 64 + kk * 32 + quad * 8];
#pragma unroll
            for (int i = 0; i < 2; i++)
#pragma unroll
                for (int j = 0; j < 4; j++)
                    acc[i][j] = __builtin_amdgcn_mfma_f32_16x16x32_bf16(
                        af[i], bfv[j], acc[i][j], 0, 0, 0);
        }
    }

    float bj[4];
#pragma unroll
    for (int j = 0; j < 4; j++) bj[j] = bias[w * 64 + j * 16 + c];
    float xv[2][4][4];
#pragma unroll
    for (int i = 0; i < 2; i++)
#pragma unroll
        for (int r = 0; r < 4; r++) {
            const int gr = row0 + i * 16 + quad * 4 + r;
#pragma unroll
            for (int j = 0; j < 4; j++) {
                const int gc = w * 64 + j * 16 + c;
                xv[i][j][r] = acc[i][j][r] + bj[j] + resid[(size_t)gr * 256 + gc];
            }
        }

    if (DOLN) {
        float sm[2][4], sp[2][4];
#pragma unroll
        for (int i = 0; i < 2; i++)
#pragma unroll
            for (int r = 0; r < 4; r++) {
                float s = 0.f, q = 0.f;
#pragma unroll
                for (int j = 0; j < 4; j++) { s += xv[i][j][r]; q += xv[i][j][r] * xv[i][j][r]; }
                sm[i][r] = s; sp[i][r] = q;
            }
#pragma unroll
        for (int off = 1; off < 16; off <<= 1)
#pragma unroll
            for (int i = 0; i < 2; i++)
#pragma unroll
                for (int r = 0; r < 4; r++) {
                    sm[i][r] += __shfl_xor(sm[i][r], off, 64);
                    sp[i][r] += __shfl_xor(sp[i][r], off, 64);
                }
        __syncthreads();
        if (c == 0) {
#pragma unroll
            for (int i = 0; i < 2; i++)
#pragma unroll
                for (int r = 0; r < 4; r++)
                    red[w][i * 16 + quad * 4 + r] = make_float2(sm[i][r], sp[i][r]);
        }
        __syncthreads();
#pragma unroll
        for (int i = 0; i < 2; i++)
#pragma unroll
            for (int r = 0; r < 4; r++) {
                const int row = i * 16 + quad * 4 + r;
                float2 t0 = red[0][row], t1 = red[1][row];
                float2 t2 = red[2][row], t3 = red[3][row];
                float S = (t0.x + t1.x) + (t2.x + t3.x);
                float Q = (t0.y + t1.y) + (t2.y + t3.y);
                float mu = S * (1.0f / 256.0f);
                float var = Q * (1.0f / 256.0f) - mu * mu;
                float rr = rsqrtf(var + 1e-5f);
                const int gr = row0 + row;
#pragma unroll
                for (int j = 0; j < 4; j++) {
                    const int gc = w * 64 + j * 16 + c;
                    float x = xv[i][j][r];
                    Xout[(size_t)gr * 256 + gc] = x;
                    Nout[(size_t)gr * 256 + gc] =
                        f2bf((x - mu) * rr * gamma[gc] + beta[gc]);
                }
            }
    } else {
#pragma unroll
        for (int i = 0; i < 2; i++)
#pragma unroll
            for (int r = 0; r < 4; r++) {
                const int gr = row0 + i * 16 + quad * 4 + r;
#pragma unroll
                for (int j = 0; j < 4; j++)
                    Xout[(size_t)gr * 256 + w * 64 + j * 16 + c] = xv[i][j][r];
            }
    }
}

// ---------------------------------------------------------------------------
// MFMA flash attention v7 (unchanged): exchange-free PV via virtual-k
// composite; l via ones-MFMA; 128q blocks; key-split x2; reg-prefetch;
// 128-key supertiles; raw v_exp.
// ---------------------------------------------------------------------------
__global__ __launch_bounds__(256) void attn_kernel(
    const u16* __restrict__ QKV, const u16* __restrict__ VT,
    u16* __restrict__ POa, u16* __restrict__ POb, float* __restrict__ Lp)
{
    const int h = blockIdx.y, b = blockIdx.z;
    const int half = blockIdx.x & 1;
    const int q0 = (blockIdx.x >> 1) * 128;
    const int tid = threadIdx.x, w = tid >> 6, lane = tid & 63;
    const int c = lane & 15, quad = lane >> 4;

    __shared__ u16 Kf[4096];
    __shared__ u16 Vf[4096];

    const u16* qp = QKV + (size_t)(b * T_SEQ + q0 + w * 32 + c) * QKV_N + h * 32 + quad * 8;
    bf16x8 aQ0 = *(const bf16x8*)qp;
    bf16x8 aQ1 = *(const bf16x8*)(qp + 16 * QKV_N);

    const bf16x8 bOnes = {0x3F80, 0x3F80, 0x3F80, 0x3F80,
                          0x3F80, 0x3F80, 0x3F80, 0x3F80};

    f32x4 O[2][2] = {};
    f32x4 Ol0 = {0.f, 0.f, 0.f, 0.f}, Ol1 = {0.f, 0.f, 0.f, 0.f};

    const u16* kgp = QKV + (size_t)(b * T_SEQ + w * 16 + c) * QKV_N + 256 + h * 32 + quad * 8;
    const u16* vgp = VT + ((size_t)h * 32 + (lane & 31)) * M_ROWS + b * T_SEQ
                     + (w * 2 + (lane >> 5)) * 8;
    u16* kfw = Kf + w * 512 + lane * 8;

    const int vd  = lane & 31, vdh = vd >> 4, vc = vd & 15, vhi = lane >> 5;
    const int vkh = w >> 1, vseg = w & 1;
    const int voff = ((((vkh * 2 + vdh) * 4 + 2 * vhi) * 16 + vc) * 8) + vseg * 4;

    const int kbeg = half * (T_SEQ / 2);
    const int kend = kbeg + T_SEQ / 2;

    bf16x8 gK0 = *(const bf16x8*)(kgp + (size_t)kbeg * QKV_N);
    bf16x8 gK1 = *(const bf16x8*)(kgp + (size_t)(kbeg + 64) * QKV_N);
    bf16x8 gV0 = *(const bf16x8*)(vgp + kbeg);
    bf16x8 gV1 = *(const bf16x8*)(vgp + kbeg + 64);

    for (int k0 = kbeg; k0 < kend; k0 += 128) {
        __syncthreads();
        *(bf16x8*)kfw          = gK0;
        *(bf16x8*)(kfw + 2048) = gK1;
        {
            bf16x4 l0v = __builtin_shufflevector(gV0, gV0, 0, 1, 2, 3);
            bf16x4 h0v = __builtin_shufflevector(gV0, gV0, 4, 5, 6, 7);
            bf16x4 l1v = __builtin_shufflevector(gV1, gV1, 0, 1, 2, 3);
            bf16x4 h1v = __builtin_shufflevector(gV1, gV1, 4, 5, 6, 7);
            *(bf16x4*)&Vf[voff]              = l0v;
            *(bf16x4*)&Vf[voff + 128]        = h0v;
            *(bf16x4*)&Vf[2048 + voff]       = l1v;
            *(bf16x4*)&Vf[2048 + voff + 128] = h1v;
        }
        if (k0 + 128 < kend) {
            gK0 = *(const bf16x8*)(kgp + (size_t)(k0 + 128) * QKV_N);
            gK1 = *(const bf16x8*)(kgp + (size_t)(k0 + 192) * QKV_N);
            gV0 = *(const bf16x8*)(vgp + k0 + 128);
            gV1 = *(const bf16x8*)(vgp + k0 + 192);
        }
        __syncthreads();

#pragma unroll
        for (int hf = 0; hf < 2; hf++) {
            const u16* Kb = Kf + hf * 2048;
            const u16* Vb = Vf + hf * 2048;

            unsigned pk0[4][2], pk1[4][2];
#pragma unroll
            for (int g = 0; g < 4; g++) {
                bf16x8 aK = *(const bf16x8*)&Kb[g * 512 + lane * 8];
                f32x4 S0 = __builtin_amdgcn_mfma_f32_16x16x32_bf16(
                    aK, aQ0, (f32x4){0.f, 0.f, 0.f, 0.f}, 0, 0, 0);
                f32x4 S1 = __builtin_amdgcn_mfma_f32_16x16x32_bf16(
                    aK, aQ1, (f32x4){0.f, 0.f, 0.f, 0.f}, 0, 0, 0);
                pk0[g][0] = pack2bf(__builtin_amdgcn_exp2f(S0[0]),
                                    __builtin_amdgcn_exp2f(S0[1]));
                pk0[g][1] = pack2bf(__builtin_amdgcn_exp2f(S0[2]),
                                    __builtin_amdgcn_exp2f(S0[3]));
                pk1[g][0] = pack2bf(__builtin_amdgcn_exp2f(S1[0]),
                                    __builtin_amdgcn_exp2f(S1[1]));
                pk1[g][1] = pack2bf(__builtin_amdgcn_exp2f(S1[2]),
                                    __builtin_amdgcn_exp2f(S1[3]));
            }

#pragma unroll
            for (int kh = 0; kh < 2; kh++) {
                bf16x8 aP0 = __builtin_bit_cast(bf16x8,
                    (u32x4){pk0[2 * kh][0], pk0[2 * kh][1],
                            pk0[2 * kh + 1][0], pk0[2 * kh + 1][1]});
                bf16x8 aP1 = __builtin_bit_cast(bf16x8,
                    (u32x4){pk1[2 * kh][0], pk1[2 * kh][1],
                            pk1[2 * kh + 1][0], pk1[2 * kh + 1][1]});
                Ol0 = __builtin_amdgcn_mfma_f32_16x16x32_bf16(aP0, bOnes, Ol0, 0, 0, 0);
                Ol1 = __builtin_amdgcn_mfma_f32_16x16x32_bf16(aP1, bOnes, Ol1, 0, 0, 0);
#pragma unroll
                for (int dh = 0; dh < 2; dh++) {
                    bf16x8 bV = *(const bf16x8*)&Vb[((kh * 2 + dh) * 64 + lane) * 8];
                    O[0][dh] = __builtin_amdgcn_mfma_f32_16x16x32_bf16(aP0, bV, O[0][dh], 0, 0, 0);
                    O[1][dh] = __builtin_amdgcn_mfma_f32_16x16x32_bf16(aP1, bV, O[1][dh], 0, 0, 0);
                }
            }
        }
    }

    u16* pb = (half ? POb : POa)
              + (size_t)(b * T_SEQ + q0 + w * 32) * 256 + h * 32;
    if (c == 0) {
        float* lb = Lp + (size_t)half * M_ROWS * 8
                    + (size_t)(b * T_SEQ + q0 + w * 32) * 8 + h;
#pragma unroll
        for (int r = 0; r < 4; r++) {
            lb[(size_t)(quad * 4 + r) * 8]      = Ol0[r];
            lb[(size_t)(16 + quad * 4 + r) * 8] = Ol1[r];
        }
    }
#pragma unroll
    for (int r = 0; r < 4; r++) {
        int src = quad * 4 + r;
        pb[(size_t)src * 256 + c]             = f2bf(O[0][0][r]);
        pb[(size_t)src * 256 + 16 + c]        = f2bf(O[0][1][r]);
        pb[(size_t)(16 + src) * 256 + c]      = f2bf(O[1][0][r]);
        pb[(size_t)(16 + src) * 256 + 16 + c] = f2bf(O[1][1][r]);
    }
}

// ---------------------------------------------------------------------------
extern "C" void kernel_launch(void* const* d_in, const int* in_sizes, int n_in,
                              void* d_out, int out_size, void* d_ws, size_t ws_size,
                              hipStream_t stream)
{
    const float* x     = (const float*)d_in[0];
    const float* ln1_s = (const float*)d_in[1];
    const float* ln1_b = (const float*)d_in[2];
    const float* wq    = (const float*)d_in[3];
    const float* bq    = (const float*)d_in[4];
    const float* wk    = (const float*)d_in[5];
    const float* bk    = (const float*)d_in[6];
    const float* wv    = (const float*)d_in[7];
    const float* bv    = (const float*)d_in[8];
    const float* wo    = (const float*)d_in[9];
    const float* bo    = (const float*)d_in[10];
    const float* ln2_s = (const float*)d_in[11];
    const float* ln2_b = (const float*)d_in[12];
    const float* w1    = (const float*)d_in[13];
    const float* b1    = (const float*)d_in[14];
    const float* w2    = (const float*)d_in[15];
    const float* b2    = (const float*)d_in[16];

    float* X = (float*)d_out;                   // fp32 residual stream

    u16* normed = (u16*)d_ws;                               // 8192*256
    u16* qkv    = normed + (size_t)M_ROWS * 256;            // 8192*768 (V third unused)
    u16* POa    = qkv + (size_t)M_ROWS * QKV_N;             // 8192*256
    u16* h1     = qkv;   // spans qkv+POa: 8192*1024
    u16* wqkv_t = POa + (size_t)M_ROWS * 256;               // 6*768*256
    u16* wo_t   = wqkv_t + (size_t)N_LAYERSC * QKV_N * 256; // 6*256*256
    u16* w1_t   = wo_t + (size_t)N_LAYERSC * 256 * 256;     // 6*1024*256
    u16* w2_t   = w1_t + (size_t)N_LAYERSC * D_FFC * 256;   // 6*256*1024
    float* qkvb = (float*)(w2_t + (size_t)N_LAYERSC * 256 * D_FFC); // 6*768 fp32
    u16* VTb    = (u16*)(qkvb + N_LAYERSC * QKV_N);         // 256*8192
    u16* POb    = VTb + (size_t)256 * M_ROWS;               // 8192*256
    float* Lp   = (float*)(POb + (size_t)M_ROWS * 256);     // 2*8192*8 fp32

    dim3 blk(256);

    // ---- ALL weight prep in one dispatch
    prep_all<<<dim3(4626), blk, 0, stream>>>(
        wq, wk, wv, wo, w1, w2, bq, bk, bv,
        wqkv_t, wo_t, w1_t, w2_t, qkvb);

    // ---- X = x and ln1(layer0) in one pass
    ln_copy<<<dim3(M_ROWS / 4), blk, 0, stream>>>(x, ln1_s, ln1_b, X, normed);

    dim3 g_qkv(QKV_N / 128, M_ROWS / 128);          // (6,64)
    dim3 g_ff(D_FFC / 128, M_ROWS / 128);           // (8,64)
    dim3 g_ln32(M_ROWS / 32);                       // 256 blocks
    dim3 g_attn(2 * T_SEQ / 128, N_HEADSC, B_SZ);   // (32,8,4) = 1024 blocks

    for (int l = 0; l < N_LAYERSC; l++) {
        mfma_gemm<3><<<g_qkv, blk, 0, stream>>>(
            normed, wqkv_t + (size_t)l * QKV_N * 256, qkvb + l * QKV_N,
            VTb, qkv, QKV_N, 256);
        attn_kernel<<<g_attn, blk, 0, stream>>>(qkv, VTb, POa, POb, Lp);
        // Wo + resid + ln2, with the key-half merge fused into A-staging
        gemm_ln<1, 1><<<g_ln32, blk, 0, stream>>>(
            POa, POb, Lp, wo_t + (size_t)l * 256 * 256, bo + l * 256, X,
            X, ln2_s + l * 256, ln2_b + l * 256, VTb, 256);
        mfma_gemm<2><<<g_ff, blk, 0, stream>>>(
            VTb, w1_t + (size_t)l * D_FFC * 256, b1 + l * D_FFC,
            nullptr, h1, D_FFC, 256);
        if (l + 1 < N_LAYERSC) {
            gemm_ln<1, 0><<<g_ln32, blk, 0, stream>>>(
                h1, nullptr, nullptr, w2_t + (size_t)l * 256 * D_FFC,
                b2 + l * 256, X, X, ln1_s + (l + 1) * 256,
                ln1_b + (l + 1) * 256, normed, D_FFC);
        } else {
            gemm_ln<0, 0><<<g_ln32, blk, 0, stream>>>(
                h1, nullptr, nullptr, w2_t + (size_t)l * 256 * D_FFC,
                b2 + l * 256, X, X, nullptr, nullptr, nullptr, D_FFC);
        }
    }
}